// Round 7
// baseline (860.959 us; speedup 1.0000x reference)
//
#include <hip/hip_runtime.h>
#include <cstdint>
#include <cstddef>

typedef unsigned short u16;
typedef __attribute__((ext_vector_type(8))) __bf16 bf16x8;   // MFMA A/B operand
typedef __attribute__((ext_vector_type(4))) float floatx4;   // MFMA C/D operand

// dims
#define T_DIM   512
#define B_SZ    8
#define ROWS    4096      // T*B
#define OBS_D   256
#define D_IN    2048
#define NHEAD   16
#define NSTATE  64
#define PDIM    128
#define NUNITS  256
#define NACT    64

__host__ __device__ __forceinline__ u16 f2bf(float f) {
    union { float f; uint32_t i; } v; v.f = f;
    uint32_t r = v.i + 0x7FFFu + ((v.i >> 16) & 1u);
    return (u16)(r >> 16);
}
__device__ __forceinline__ uint32_t pack_bf2(float lo, float hi) {
    return ((uint32_t)f2bf(hi) << 16) | (uint32_t)f2bf(lo);
}

// ---------------- fill (harness requires this symbol name) ----------------
__global__ __launch_bounds__(256) void ActorAgent_27625229647898_kernel(
        float* __restrict__ out, int n, float v) {
    for (int i = blockIdx.x * 256 + threadIdx.x; i < n; i += gridDim.x * 256)
        out[i] = v;
}

// ---------------- MFMA GEMM, fp32 I/O, bf16 compute, native (K,N) B ----------------
// C[M,N] = act(A[M,K] @ B[K,N] + bias). 256 thr (4 waves), 64x64 tile, K-step 32.
// Requires M%64==0, N%64==0, K%32==0.
template <int ACT>
__global__ __launch_bounds__(256) void gemm_kn(const float* __restrict__ A,
                                               const float* __restrict__ B,
                                               const float* __restrict__ bias,
                                               float* __restrict__ Cout,
                                               int M, int N, int K) {
    __shared__ __align__(16) u16 sA[64][40];  // [m][k], +8 pad
    __shared__ __align__(16) u16 sB[64][40];  // [n][k], +8 pad
    const int tid  = threadIdx.x;
    const int wave = tid >> 6, lane = tid & 63;
    const int quad = lane >> 4, lr = lane & 15;
    const int m0 = blockIdx.x * 64, n0 = blockIdx.y * 64;
    const int arow = tid >> 2, akoff = (tid & 3) * 8;   // A: 64 rows x 32 k, 8 fp32/thr
    const int bk = tid >> 3, bn = (tid & 7) * 8;        // B: 32 k x 64 n, 8 fp32/thr

    floatx4 acc[4];
#pragma unroll
    for (int i = 0; i < 4; i++)
#pragma unroll
        for (int j = 0; j < 4; j++) acc[i][j] = 0.f;

    const float* ap = A + (size_t)(m0 + arow) * K + akoff;
    const float* bp = B + (size_t)n0 + bn;

    for (int k0 = 0; k0 < K; k0 += 32) {
        float4 a0 = *(const float4*)(ap + k0);
        float4 a1 = *(const float4*)(ap + k0 + 4);
        const float* bq = bp + (size_t)(k0 + bk) * N;
        float4 b0 = *(const float4*)(bq);
        float4 b1 = *(const float4*)(bq + 4);
        __syncthreads();  // previous iteration's LDS readers done
        uint4 av;
        av.x = pack_bf2(a0.x, a0.y); av.y = pack_bf2(a0.z, a0.w);
        av.z = pack_bf2(a1.x, a1.y); av.w = pack_bf2(a1.z, a1.w);
        *(uint4*)&sA[arow][akoff] = av;
        sB[bn + 0][bk] = f2bf(b0.x); sB[bn + 1][bk] = f2bf(b0.y);
        sB[bn + 2][bk] = f2bf(b0.z); sB[bn + 3][bk] = f2bf(b0.w);
        sB[bn + 4][bk] = f2bf(b1.x); sB[bn + 5][bk] = f2bf(b1.y);
        sB[bn + 6][bk] = f2bf(b1.z); sB[bn + 7][bk] = f2bf(b1.w);
        __syncthreads();
        // A frag: A[m=lane&15][k=quad*8+j]; B frag: B[k=quad*8+j][n=lane&15]
        bf16x8 af = *(const bf16x8*)&sA[wave * 16 + lr][quad * 8];
#pragma unroll
        for (int nt = 0; nt < 4; nt++) {
            bf16x8 bf = *(const bf16x8*)&sB[nt * 16 + lr][quad * 8];
            acc[nt] = __builtin_amdgcn_mfma_f32_16x16x32_bf16(af, bf, acc[nt], 0, 0, 0);
        }
    }
    // C/D layout: col = lane&15, row = quad*4 + reg
#pragma unroll
    for (int nt = 0; nt < 4; nt++) {
        int col = n0 + nt * 16 + lr;
        float bvv = bias ? bias[col] : 0.f;
#pragma unroll
        for (int r = 0; r < 4; r++) {
            int row = m0 + wave * 16 + quad * 4 + r;
            float v = acc[nt][r] + bvv;
            if (ACT) v = fmaxf(v, 0.f);
            Cout[(size_t)row * N + col] = v;
        }
    }
}

// ---------------- dt projection + softplus + decay (fused, fp32) ----------------
__global__ __launch_bounds__(256) void dt_kernel(const float* __restrict__ xb,
                                                 const float* __restrict__ W_dt,
                                                 const float* __restrict__ dt_bias,
                                                 const float* __restrict__ A_log,
                                                 float* __restrict__ dtv,
                                                 float* __restrict__ decayv) {
    int row = blockIdx.x * 16 + (threadIdx.x >> 4);
    int h   = threadIdx.x & 15;
    const float* xp = xb + (size_t)row * D_IN;
    float acc = 0.f;
    for (int k = 0; k < D_IN; ++k)
        acc = fmaf(xp[k], W_dt[(size_t)k * NHEAD + h], acc);
    float z = acc + dt_bias[h];
    float sp = (z > 20.f) ? z : log1pf(expf(z));
    float a = expf(A_log[h]);
    dtv[row * NHEAD + h]    = sp;
    decayv[row * NHEAD + h] = expf(-a * sp);
}

// ---------------- sequential SSD scan — minimal fp32 version ----------------
// 256 blocks = (b, h, p-half). Thread owns p = ph*64 + (tid>>2), n-quarter
// (tid&3)*16 -> 16 state floats. Direct loads, two barriers/step.
__global__ __launch_bounds__(256) void ssd_scan(const float* __restrict__ xb,
                                                const float* __restrict__ Bm,
                                                const float* __restrict__ Cm,
                                                const float* __restrict__ dtv,
                                                const float* __restrict__ decayv,
                                                float* __restrict__ y) {
    int blk = blockIdx.x;
    int b  = blk >> 5;
    int h  = (blk >> 1) & 15;
    int ph = blk & 1;
    int tid = threadIdx.x;
    int pl = tid >> 2;
    int nq = (tid & 3) * 16;

    __shared__ float sX[64];
    __shared__ float sB[64];
    __shared__ float sC[64];
    __shared__ float sS[2];

    float state[16];
#pragma unroll
    for (int j = 0; j < 16; j++) state[j] = 0.f;

    const size_t xoff = (size_t)h * PDIM + (size_t)ph * 64;
    const size_t boff = (size_t)h * NSTATE;

    for (int t = 0; t < T_DIM; ++t) {
        int r = t * B_SZ + b;
        __syncthreads();  // protect previous step's LDS reads
        if (tid < 64)       sX[tid]       = xb[(size_t)r * D_IN + xoff + tid];
        else if (tid < 128) sB[tid - 64]  = Bm[(size_t)r * (NHEAD * NSTATE) + boff + (tid - 64)];
        else if (tid < 192) sC[tid - 128] = Cm[(size_t)r * (NHEAD * NSTATE) + boff + (tid - 128)];
        if (tid == 192) sS[0] = dtv[r * NHEAD + h];
        if (tid == 193) sS[1] = decayv[r * NHEAD + h];
        __syncthreads();
        float coef = sS[0] * sX[pl];
        float dec  = sS[1];
        float ysum = 0.f;
#pragma unroll
        for (int j = 0; j < 16; j++) {
            state[j] = fmaf(dec, state[j], coef * sB[nq + j]);
            ysum = fmaf(state[j], sC[nq + j], ysum);
        }
        ysum += __shfl_xor(ysum, 1);
        ysum += __shfl_xor(ysum, 2);
        if ((tid & 3) == 0)
            y[(size_t)r * D_IN + xoff + pl] = ysum;
    }
}

// ---------------- forensic diag ----------------
__global__ __launch_bounds__(256) void zero_sums(float* p) {
    if (threadIdx.x < 8 && blockIdx.x == 0) p[threadIdx.x] = 0.f;
}
__global__ __launch_bounds__(256) void sumabs_f32(const float* __restrict__ p, size_t n,
                                                  float* __restrict__ acc) {
    __shared__ float red[256];
    float s = 0.f;
    for (size_t i = (size_t)blockIdx.x * 256 + threadIdx.x; i < n; i += (size_t)gridDim.x * 256)
        s += fabsf(p[i]);
    red[threadIdx.x] = s; __syncthreads();
    for (int off = 128; off; off >>= 1) {
        if ((int)threadIdx.x < off) red[threadIdx.x] += red[threadIdx.x + off];
        __syncthreads();
    }
    if (threadIdx.x == 0) atomicAdd(acc, red[0]);
}
// flag=(stage+1)*100, +50 if NaN/inf; stages: 0 xb, 1 dtv, 2 decayv, 3 Bm, 4 Cm, 5 yb, 6 zb
__global__ void verdict(const float* __restrict__ sums, float* __restrict__ out) {
    if (threadIdx.x != 0 || blockIdx.x != 0) return;
    float flag = 0.f;
    for (int i = 0; i < 7; ++i) {
        float s = sums[i];
        bool bad = !isfinite(s);
        bool iszero = (s == 0.f);
        if (bad || iszero) { flag = (float)((i + 1) * 100 + (bad ? 50 : 0)); break; }
    }
    if (flag != 0.f)
        for (int i = 0; i < 8; ++i) out[i] = flag;
}

// ---------------- launch ----------------
extern "C" void kernel_launch(void* const* d_in, const int* in_sizes, int n_in,
                              void* d_out, int out_size, void* d_ws, size_t ws_size,
                              hipStream_t stream) {
    static const int exp_sizes[12] = {
        ROWS * OBS_D, OBS_D * D_IN, D_IN, NHEAD, NHEAD, D_IN * NHEAD,
        D_IN * NHEAD * NSTATE, D_IN * NHEAD * NSTATE, D_IN * NUNITS, NUNITS,
        NUNITS * NACT, NACT
    };
    bool spec_ok = (n_in == 12) && (out_size == ROWS * NACT);
    if (spec_ok)
        for (int i = 0; i < 12; ++i)
            if (in_sizes[i] != exp_sizes[i]) spec_ok = false;
    if (!spec_ok) {
        ActorAgent_27625229647898_kernel<<<dim3(128), 256, 0, stream>>>((float*)d_out, out_size, 800.f);
        return;
    }

    const float* obs     = (const float*)d_in[0];
    const float* W_in    = (const float*)d_in[1];
    const float* b_in    = (const float*)d_in[2];
    const float* A_log   = (const float*)d_in[3];
    const float* dt_bias = (const float*)d_in[4];
    const float* W_dt    = (const float*)d_in[5];
    const float* W_B     = (const float*)d_in[6];
    const float* W_C     = (const float*)d_in[7];
    const float* W_yo    = (const float*)d_in[8];
    const float* b_yo    = (const float*)d_in[9];
    const float* W_head  = (const float*)d_in[10];
    const float* b_head  = (const float*)d_in[11];

    char* ws = (char*)d_ws;
    size_t o = 0;
    float* xb     = (float*)(ws + o); o += (size_t)ROWS * D_IN * 4;            // 32 MB
    float* Bm     = (float*)(ws + o); o += (size_t)ROWS * NHEAD * NSTATE * 4;  // 16 MB
    float* Cm     = (float*)(ws + o); o += (size_t)ROWS * NHEAD * NSTATE * 4;  // 16 MB
    float* dtv    = (float*)(ws + o); o += (size_t)ROWS * NHEAD * 4;
    float* decayv = (float*)(ws + o); o += (size_t)ROWS * NHEAD * 4;
    float* yb     = (float*)(ws + o); o += (size_t)ROWS * D_IN * 4;            // 32 MB
    float* zb     = (float*)(ws + o); o += (size_t)ROWS * NUNITS * 4;          // 4 MB
    float* dsum   = (float*)(ws + o); o += 8 * 4;
    if (o > ws_size) {
        ActorAgent_27625229647898_kernel<<<dim3(128), 256, 0, stream>>>((float*)d_out, out_size, 900.f);
        return;
    }

    // canary fill of d_out (also keeps harness-required symbol referenced)
    ActorAgent_27625229647898_kernel<<<dim3(128), 256, 0, stream>>>((float*)d_out, out_size, 0.5f);

    // ---- pipeline ----
    gemm_kn<1><<<dim3(64, 32), 256, 0, stream>>>(obs, W_in, b_in, xb, ROWS, D_IN, OBS_D);
    dt_kernel<<<dim3(ROWS / 16), 256, 0, stream>>>(xb, W_dt, dt_bias, A_log, dtv, decayv);
    gemm_kn<0><<<dim3(64, 16), 256, 0, stream>>>(xb, W_B, (const float*)nullptr, Bm, ROWS, NHEAD * NSTATE, D_IN);
    gemm_kn<0><<<dim3(64, 16), 256, 0, stream>>>(xb, W_C, (const float*)nullptr, Cm, ROWS, NHEAD * NSTATE, D_IN);
    ssd_scan<<<dim3(256), 256, 0, stream>>>(xb, Bm, Cm, dtv, decayv, yb);
    gemm_kn<1><<<dim3(64, 4), 256, 0, stream>>>(yb, W_yo, b_yo, zb, ROWS, NUNITS, D_IN);
    gemm_kn<0><<<dim3(64, 1), 256, 0, stream>>>(zb, W_head, b_head, (float*)d_out, ROWS, NACT, NUNITS);

    // ---- forensic diag: full-buffer NaN/zero classification per stage ----
    zero_sums<<<dim3(1), 256, 0, stream>>>(dsum);
    sumabs_f32<<<dim3(256), 256, 0, stream>>>(xb,     (size_t)ROWS * D_IN,           dsum + 0);
    sumabs_f32<<<dim3(256), 256, 0, stream>>>(dtv,    (size_t)ROWS * NHEAD,          dsum + 1);
    sumabs_f32<<<dim3(256), 256, 0, stream>>>(decayv, (size_t)ROWS * NHEAD,          dsum + 2);
    sumabs_f32<<<dim3(256), 256, 0, stream>>>(Bm,     (size_t)ROWS * NHEAD * NSTATE, dsum + 3);
    sumabs_f32<<<dim3(256), 256, 0, stream>>>(Cm,     (size_t)ROWS * NHEAD * NSTATE, dsum + 4);
    sumabs_f32<<<dim3(256), 256, 0, stream>>>(yb,     (size_t)ROWS * D_IN,           dsum + 5);
    sumabs_f32<<<dim3(256), 256, 0, stream>>>(zb,     (size_t)ROWS * NUNITS,         dsum + 6);
    verdict<<<dim3(1), 1, 0, stream>>>(dsum, (float*)d_out);
}

// Round 8
// 606.694 us; speedup vs baseline: 1.4191x; 1.4191x over previous
//
#include <hip/hip_runtime.h>
#include <cstdint>
#include <cstddef>

typedef unsigned short u16;
typedef __attribute__((ext_vector_type(8))) __bf16 bf16x8;   // MFMA A/B operand
typedef __attribute__((ext_vector_type(4))) float floatx4;   // MFMA C/D operand

// dims
#define T_DIM   512
#define B_SZ    8
#define ROWS    4096      // T*B
#define OBS_D   256
#define D_IN    2048
#define NHEAD   16
#define NSTATE  64
#define PDIM    128
#define NUNITS  256
#define NACT    64
#define CHUNK   8         // scan time-steps per LDS stage

__host__ __device__ __forceinline__ u16 f2bf(float f) {
    union { float f; uint32_t i; } v; v.f = f;
    uint32_t r = v.i + 0x7FFFu + ((v.i >> 16) & 1u);
    return (u16)(r >> 16);
}
__device__ __forceinline__ uint32_t pack_bf2(float lo, float hi) {
    return ((uint32_t)f2bf(hi) << 16) | (uint32_t)f2bf(lo);
}

// ---------------- fill (harness requires this symbol name; also d_out canary) ----------------
__global__ __launch_bounds__(256) void ActorAgent_27625229647898_kernel(
        float* __restrict__ out, int n, float v) {
    for (int i = blockIdx.x * 256 + threadIdx.x; i < n; i += gridDim.x * 256)
        out[i] = v;
}

// ---------------- MFMA GEMM, fp32 I/O, bf16 compute, native (K,N) B ----------------
// C[M,N] = act(A[M,K] @ B[K,N] + bias). 256 thr (4 waves), 64x64 tile, K-step 32.
// Requires M%64==0, N%64==0, K%32==0.
template <int ACT>
__global__ __launch_bounds__(256) void gemm_kn(const float* __restrict__ A,
                                               const float* __restrict__ B,
                                               const float* __restrict__ bias,
                                               float* __restrict__ Cout,
                                               int M, int N, int K) {
    __shared__ __align__(16) u16 sA[64][40];  // [m][k], +8 pad
    __shared__ __align__(16) u16 sB[64][40];  // [n][k], +8 pad
    const int tid  = threadIdx.x;
    const int wave = tid >> 6, lane = tid & 63;
    const int quad = lane >> 4, lr = lane & 15;
    const int m0 = blockIdx.x * 64, n0 = blockIdx.y * 64;
    const int arow = tid >> 2, akoff = (tid & 3) * 8;   // A: 64 rows x 32 k, 8 fp32/thr
    const int bk = tid >> 3, bn = (tid & 7) * 8;        // B: 32 k x 64 n, 8 fp32/thr

    floatx4 acc[4];
#pragma unroll
    for (int i = 0; i < 4; i++)
#pragma unroll
        for (int j = 0; j < 4; j++) acc[i][j] = 0.f;

    const float* ap = A + (size_t)(m0 + arow) * K + akoff;
    const float* bp = B + (size_t)n0 + bn;

    for (int k0 = 0; k0 < K; k0 += 32) {
        float4 a0 = *(const float4*)(ap + k0);
        float4 a1 = *(const float4*)(ap + k0 + 4);
        const float* bq = bp + (size_t)(k0 + bk) * N;
        float4 b0 = *(const float4*)(bq);
        float4 b1 = *(const float4*)(bq + 4);
        __syncthreads();  // previous iteration's LDS readers done
        uint4 av;
        av.x = pack_bf2(a0.x, a0.y); av.y = pack_bf2(a0.z, a0.w);
        av.z = pack_bf2(a1.x, a1.y); av.w = pack_bf2(a1.z, a1.w);
        *(uint4*)&sA[arow][akoff] = av;
        sB[bn + 0][bk] = f2bf(b0.x); sB[bn + 1][bk] = f2bf(b0.y);
        sB[bn + 2][bk] = f2bf(b0.z); sB[bn + 3][bk] = f2bf(b0.w);
        sB[bn + 4][bk] = f2bf(b1.x); sB[bn + 5][bk] = f2bf(b1.y);
        sB[bn + 6][bk] = f2bf(b1.z); sB[bn + 7][bk] = f2bf(b1.w);
        __syncthreads();
        // A frag: A[m=lane&15][k=quad*8+j]; B frag: B[k=quad*8+j][n=lane&15]
        bf16x8 af = *(const bf16x8*)&sA[wave * 16 + lr][quad * 8];
#pragma unroll
        for (int nt = 0; nt < 4; nt++) {
            bf16x8 bf = *(const bf16x8*)&sB[nt * 16 + lr][quad * 8];
            acc[nt] = __builtin_amdgcn_mfma_f32_16x16x32_bf16(af, bf, acc[nt], 0, 0, 0);
        }
    }
    // C/D layout: col = lane&15, row = quad*4 + reg
#pragma unroll
    for (int nt = 0; nt < 4; nt++) {
        int col = n0 + nt * 16 + lr;
        float bvv = bias ? bias[col] : 0.f;
#pragma unroll
        for (int r = 0; r < 4; r++) {
            int row = m0 + wave * 16 + quad * 4 + r;
            float v = acc[nt][r] + bvv;
            if (ACT) v = fmaxf(v, 0.f);
            Cout[(size_t)row * N + col] = v;
        }
    }
}

// ---------------- merged B/C projection GEMM ----------------
// grid (64, 32): y<16 -> Bm = x @ W_B tile y; y>=16 -> Cm = x @ W_C tile y-16.
__global__ __launch_bounds__(256) void gemm_bc(const float* __restrict__ A,
                                               const float* __restrict__ WB,
                                               const float* __restrict__ WC,
                                               float* __restrict__ Bm,
                                               float* __restrict__ Cm,
                                               int M, int N, int K) {
    __shared__ __align__(16) u16 sA[64][40];
    __shared__ __align__(16) u16 sB[64][40];
    const int tid  = threadIdx.x;
    const int wave = tid >> 6, lane = tid & 63;
    const int quad = lane >> 4, lr = lane & 15;
    const int m0 = blockIdx.x * 64;
    const int isC = (blockIdx.y >= 16);
    const int n0 = (blockIdx.y & 15) * 64;
    const float* B = isC ? WC : WB;
    float* Cout = isC ? Cm : Bm;
    const int arow = tid >> 2, akoff = (tid & 3) * 8;
    const int bk = tid >> 3, bn = (tid & 7) * 8;

    floatx4 acc[4];
#pragma unroll
    for (int i = 0; i < 4; i++)
#pragma unroll
        for (int j = 0; j < 4; j++) acc[i][j] = 0.f;

    const float* ap = A + (size_t)(m0 + arow) * K + akoff;
    const float* bp = B + (size_t)n0 + bn;

    for (int k0 = 0; k0 < K; k0 += 32) {
        float4 a0 = *(const float4*)(ap + k0);
        float4 a1 = *(const float4*)(ap + k0 + 4);
        const float* bq = bp + (size_t)(k0 + bk) * N;
        float4 b0 = *(const float4*)(bq);
        float4 b1 = *(const float4*)(bq + 4);
        __syncthreads();
        uint4 av;
        av.x = pack_bf2(a0.x, a0.y); av.y = pack_bf2(a0.z, a0.w);
        av.z = pack_bf2(a1.x, a1.y); av.w = pack_bf2(a1.z, a1.w);
        *(uint4*)&sA[arow][akoff] = av;
        sB[bn + 0][bk] = f2bf(b0.x); sB[bn + 1][bk] = f2bf(b0.y);
        sB[bn + 2][bk] = f2bf(b0.z); sB[bn + 3][bk] = f2bf(b0.w);
        sB[bn + 4][bk] = f2bf(b1.x); sB[bn + 5][bk] = f2bf(b1.y);
        sB[bn + 6][bk] = f2bf(b1.z); sB[bn + 7][bk] = f2bf(b1.w);
        __syncthreads();
        bf16x8 af = *(const bf16x8*)&sA[wave * 16 + lr][quad * 8];
#pragma unroll
        for (int nt = 0; nt < 4; nt++) {
            bf16x8 bf = *(const bf16x8*)&sB[nt * 16 + lr][quad * 8];
            acc[nt] = __builtin_amdgcn_mfma_f32_16x16x32_bf16(af, bf, acc[nt], 0, 0, 0);
        }
    }
#pragma unroll
    for (int nt = 0; nt < 4; nt++) {
        int col = n0 + nt * 16 + lr;
#pragma unroll
        for (int r = 0; r < 4; r++) {
            int row = m0 + wave * 16 + quad * 4 + r;
            Cout[(size_t)row * N + col] = acc[nt][r];
        }
    }
}

// ---------------- dt projection + softplus + decay (fused, fp32) ----------------
__global__ __launch_bounds__(256) void dt_kernel(const float* __restrict__ xb,
                                                 const float* __restrict__ W_dt,
                                                 const float* __restrict__ dt_bias,
                                                 const float* __restrict__ A_log,
                                                 float* __restrict__ dtv,
                                                 float* __restrict__ decayv) {
    int row = blockIdx.x * 16 + (threadIdx.x >> 4);
    int h   = threadIdx.x & 15;
    const float* xp = xb + (size_t)row * D_IN;
    float acc = 0.f;
    for (int k = 0; k < D_IN; ++k)
        acc = fmaf(xp[k], W_dt[(size_t)k * NHEAD + h], acc);
    float z = acc + dt_bias[h];
    float sp = (z > 20.f) ? z : log1pf(expf(z));
    float a = expf(A_log[h]);
    dtv[row * NHEAD + h]    = sp;
    decayv[row * NHEAD + h] = expf(-a * sp);
}

// ---------------- sequential SSD scan — chunked LDS staging ----------------
// 512 blocks = b(8) x h(16) x p-quarter(4). Thread owns p = pq*32 + (tid>>3)
// and n-octant (tid&7)*8 -> 8 state floats. CHUNK=8 steps staged per barrier,
// double-buffered LDS, global loads for chunk c+1 issued before computing c.
__global__ __launch_bounds__(256) void ssd_scan(const float* __restrict__ xb,
                                                const float* __restrict__ Bm,
                                                const float* __restrict__ Cm,
                                                const float* __restrict__ dtv,
                                                const float* __restrict__ decayv,
                                                float* __restrict__ y) {
    const int blk = blockIdx.x;
    const int b  = blk >> 6;          // 0..7
    const int h  = (blk >> 2) & 15;   // 0..15
    const int pq = blk & 3;           // 0..3
    const int tid = threadIdx.x;
    const int pl  = tid >> 3;         // 0..31 local p
    const int oct = tid & 7;          // 0..7 n-octant

    __shared__ __align__(16) float sX[2][CHUNK][32];
    __shared__ __align__(16) float sB[2][CHUNK][64];
    __shared__ __align__(16) float sC[2][CHUNK][64];
    __shared__ float sS[2][CHUNK][2];  // [ss][0]=dt, [1]=decay

    float state[8];
#pragma unroll
    for (int j = 0; j < 8; j++) state[j] = 0.f;

    const size_t xcol = (size_t)h * PDIM + (size_t)pq * 32;
    const size_t bcol = (size_t)h * NSTATE;
    const int NB = NHEAD * NSTATE;  // 1024

    // staging roles: tid<32 -> x; 64..127 -> B; 128..191 -> C; 192..207 -> scalars
    float pre[CHUNK];
    auto loadchunk = [&](int c) {
        int t0 = c * CHUNK;
#pragma unroll
        for (int ss = 0; ss < CHUNK; ++ss) {
            int r = (t0 + ss) * B_SZ + b;
            if (tid < 32)                    pre[ss] = xb[(size_t)r * D_IN + xcol + tid];
            else if (tid >= 64 && tid < 128) pre[ss] = Bm[(size_t)r * NB + bcol + (tid - 64)];
            else if (tid >= 128 && tid < 192) pre[ss] = Cm[(size_t)r * NB + bcol + (tid - 128)];
        }
        if (tid >= 192 && tid < 192 + CHUNK * 2) {
            int ss = (tid - 192) >> 1;
            int r = (t0 + ss) * B_SZ + b;
            pre[0] = ((tid & 1) ? decayv : dtv)[r * NHEAD + h];
        }
    };
    auto writechunk = [&](int s) {
#pragma unroll
        for (int ss = 0; ss < CHUNK; ++ss) {
            if (tid < 32)                    sX[s][ss][tid] = pre[ss];
            else if (tid >= 64 && tid < 128) sB[s][ss][tid - 64] = pre[ss];
            else if (tid >= 128 && tid < 192) sC[s][ss][tid - 128] = pre[ss];
        }
        if (tid >= 192 && tid < 192 + CHUNK * 2)
            sS[s][(tid - 192) >> 1][tid & 1] = pre[0];
    };

    loadchunk(0);
    writechunk(0);
    __syncthreads();

    const int NCH = T_DIM / CHUNK;  // 64
    for (int c = 0; c < NCH; ++c) {
        int s = c & 1;
        if (c + 1 < NCH) loadchunk(c + 1);  // issue global loads early (MLP=8)
#pragma unroll
        for (int ss = 0; ss < CHUNK; ++ss) {
            float dt  = sS[s][ss][0];
            float dec = sS[s][ss][1];
            float coef = dt * sX[s][ss][pl];
            float4 b0 = *(const float4*)&sB[s][ss][oct * 8];
            float4 b1 = *(const float4*)&sB[s][ss][oct * 8 + 4];
            float4 c0 = *(const float4*)&sC[s][ss][oct * 8];
            float4 c1 = *(const float4*)&sC[s][ss][oct * 8 + 4];
            float ysum = 0.f;
            state[0] = fmaf(dec, state[0], coef * b0.x); ysum = fmaf(state[0], c0.x, ysum);
            state[1] = fmaf(dec, state[1], coef * b0.y); ysum = fmaf(state[1], c0.y, ysum);
            state[2] = fmaf(dec, state[2], coef * b0.z); ysum = fmaf(state[2], c0.z, ysum);
            state[3] = fmaf(dec, state[3], coef * b0.w); ysum = fmaf(state[3], c0.w, ysum);
            state[4] = fmaf(dec, state[4], coef * b1.x); ysum = fmaf(state[4], c1.x, ysum);
            state[5] = fmaf(dec, state[5], coef * b1.y); ysum = fmaf(state[5], c1.y, ysum);
            state[6] = fmaf(dec, state[6], coef * b1.z); ysum = fmaf(state[6], c1.z, ysum);
            state[7] = fmaf(dec, state[7], coef * b1.w); ysum = fmaf(state[7], c1.w, ysum);
            ysum += __shfl_xor(ysum, 1);
            ysum += __shfl_xor(ysum, 2);
            ysum += __shfl_xor(ysum, 4);
            if (oct == 0) {
                int r = (c * CHUNK + ss) * B_SZ + b;
                y[(size_t)r * D_IN + xcol + pl] = ysum;
            }
        }
        if (c + 1 < NCH) writechunk(s ^ 1);
        __syncthreads();
    }
}

// ---------------- launch ----------------
extern "C" void kernel_launch(void* const* d_in, const int* in_sizes, int n_in,
                              void* d_out, int out_size, void* d_ws, size_t ws_size,
                              hipStream_t stream) {
    const float* obs     = (const float*)d_in[0];
    const float* W_in    = (const float*)d_in[1];
    const float* b_in    = (const float*)d_in[2];
    const float* A_log   = (const float*)d_in[3];
    const float* dt_bias = (const float*)d_in[4];
    const float* W_dt    = (const float*)d_in[5];
    const float* W_B     = (const float*)d_in[6];
    const float* W_C     = (const float*)d_in[7];
    const float* W_yo    = (const float*)d_in[8];
    const float* b_yo    = (const float*)d_in[9];
    const float* W_head  = (const float*)d_in[10];
    const float* b_head  = (const float*)d_in[11];

    char* ws = (char*)d_ws;
    size_t o = 0;
    float* xb     = (float*)(ws + o); o += (size_t)ROWS * D_IN * 4;            // 32 MB
    float* Bm     = (float*)(ws + o); o += (size_t)ROWS * NHEAD * NSTATE * 4;  // 16 MB
    float* Cm     = (float*)(ws + o); o += (size_t)ROWS * NHEAD * NSTATE * 4;  // 16 MB
    float* dtv    = (float*)(ws + o); o += (size_t)ROWS * NHEAD * 4;
    float* decayv = (float*)(ws + o); o += (size_t)ROWS * NHEAD * 4;
    float* yb     = (float*)(ws + o); o += (size_t)ROWS * D_IN * 4;            // 32 MB
    float* zb     = (float*)(ws + o); o += (size_t)ROWS * NUNITS * 4;          // 4 MB

    // canary fill of d_out (keeps harness-required symbol launched; overwritten below)
    ActorAgent_27625229647898_kernel<<<dim3(128), 256, 0, stream>>>((float*)d_out, out_size, 0.5f);

    // ---- x = relu(obs @ W_in + b_in) ----
    gemm_kn<1><<<dim3(64, 32), 256, 0, stream>>>(obs, W_in, b_in, xb, ROWS, D_IN, OBS_D);
    // ---- dt = softplus(x @ W_dt + dt_bias); decay = exp(-exp(A_log)*dt) ----
    dt_kernel<<<dim3(ROWS / 16), 256, 0, stream>>>(xb, W_dt, dt_bias, A_log, dtv, decayv);
    // ---- B, C projections (merged) ----
    gemm_bc<<<dim3(64, 32), 256, 0, stream>>>(xb, W_B, W_C, Bm, Cm, ROWS, NHEAD * NSTATE, D_IN);
    // ---- sequential scan -> y ----
    ssd_scan<<<dim3(512), 256, 0, stream>>>(xb, Bm, Cm, dtv, decayv, yb);
    // ---- z = relu(y @ W_yo + b_yo) ----
    gemm_kn<1><<<dim3(64, 4), 256, 0, stream>>>(yb, W_yo, b_yo, zb, ROWS, NUNITS, D_IN);
    // ---- logits = z @ W_head + b_head -> d_out ----
    gemm_kn<0><<<dim3(64, 1), 256, 0, stream>>>(zb, W_head, b_head, (float*)d_out, ROWS, NACT, NUNITS);
}

// Round 9
// 483.086 us; speedup vs baseline: 1.7822x; 1.2559x over previous
//
#include <hip/hip_runtime.h>
#include <cstdint>
#include <cstddef>

typedef unsigned short u16;
typedef __attribute__((ext_vector_type(8))) __bf16 bf16x8;   // MFMA A/B operand
typedef __attribute__((ext_vector_type(4))) float floatx4;   // MFMA C/D operand

// dims
#define T_DIM   512
#define B_SZ    8
#define ROWS    4096      // T*B
#define OBS_D   256
#define D_IN    2048
#define NHEAD   16
#define NSTATE  64
#define PDIM    128
#define NUNITS  256
#define NACT    64
#define CHUNK   8         // scan time-steps per LDS stage
#define NSEG    4
#define SEGT    128       // T_DIM / NSEG
#define SLOT    (B_SZ * NHEAD * PDIM * NSTATE)   // 1048576 floats = 4 MB per seg-state

__host__ __device__ __forceinline__ u16 f2bf(float f) {
    union { float f; uint32_t i; } v; v.f = f;
    uint32_t r = v.i + 0x7FFFu + ((v.i >> 16) & 1u);
    return (u16)(r >> 16);
}
__device__ __forceinline__ uint32_t pack_bf2(float lo, float hi) {
    return ((uint32_t)f2bf(hi) << 16) | (uint32_t)f2bf(lo);
}

// ---------------- fill (harness requires this symbol name; d_out canary) ----------------
__global__ __launch_bounds__(256) void ActorAgent_27625229647898_kernel(
        float* __restrict__ out, int n, float v) {
    for (int i = blockIdx.x * 256 + threadIdx.x; i < n; i += gridDim.x * 256)
        out[i] = v;
}

// ---------------- MFMA GEMM, fp32 I/O, bf16 compute, native (K,N) B ----------------
// C[M,N] = act(A[M,K] @ B[K,N] + bias). 256 thr (4 waves), 64x64 tile, K-step 32.
// B staged via register transpose: thread=(n=tid&63, kg=tid>>6), 8 coalesced
// k-strided loads, one uint4 LDS write -> 2-way (free) bank pattern.
template <int ACT>
__global__ __launch_bounds__(256) void gemm_kn(const float* __restrict__ A,
                                               const float* __restrict__ B,
                                               const float* __restrict__ bias,
                                               float* __restrict__ Cout,
                                               int M, int N, int K) {
    __shared__ __align__(16) u16 sA[64][40];  // [m][k], stride 40 u16
    __shared__ __align__(16) u16 sB[64][40];  // [n][k]
    const int tid  = threadIdx.x;
    const int wave = tid >> 6, lane = tid & 63;
    const int quad = lane >> 4, lr = lane & 15;
    const int m0 = blockIdx.x * 64, n0 = blockIdx.y * 64;
    const int arow = tid >> 2, akoff = (tid & 3) * 8;   // A: 64 rows x 32 k
    const int bn_l = tid & 63, bkg = tid >> 6;          // B: 64 n x 4 k-octets

    floatx4 acc[4];
#pragma unroll
    for (int i = 0; i < 4; i++)
#pragma unroll
        for (int j = 0; j < 4; j++) acc[i][j] = 0.f;

    const float* ap = A + (size_t)(m0 + arow) * K + akoff;
    const float* bp = B + (size_t)(bkg * 8) * N + n0 + bn_l;

    for (int k0 = 0; k0 < K; k0 += 32) {
        float4 a0 = *(const float4*)(ap + k0);
        float4 a1 = *(const float4*)(ap + k0 + 4);
        const float* bq = bp + (size_t)k0 * N;
        float bv[8];
#pragma unroll
        for (int j = 0; j < 8; j++) bv[j] = bq[(size_t)j * N];
        __syncthreads();  // previous iteration's LDS readers done
        uint4 av;
        av.x = pack_bf2(a0.x, a0.y); av.y = pack_bf2(a0.z, a0.w);
        av.z = pack_bf2(a1.x, a1.y); av.w = pack_bf2(a1.z, a1.w);
        *(uint4*)&sA[arow][akoff] = av;
        uint4 bw;
        bw.x = pack_bf2(bv[0], bv[1]); bw.y = pack_bf2(bv[2], bv[3]);
        bw.z = pack_bf2(bv[4], bv[5]); bw.w = pack_bf2(bv[6], bv[7]);
        *(uint4*)&sB[bn_l][bkg * 8] = bw;
        __syncthreads();
        // A frag: A[m=lane&15][k=quad*8+j]; B frag: B[k=quad*8+j][n=lane&15]
        bf16x8 af = *(const bf16x8*)&sA[wave * 16 + lr][quad * 8];
#pragma unroll
        for (int nt = 0; nt < 4; nt++) {
            bf16x8 bf = *(const bf16x8*)&sB[nt * 16 + lr][quad * 8];
            acc[nt] = __builtin_amdgcn_mfma_f32_16x16x32_bf16(af, bf, acc[nt], 0, 0, 0);
        }
    }
    // C/D layout: col = lane&15, row = quad*4 + reg
#pragma unroll
    for (int nt = 0; nt < 4; nt++) {
        int col = n0 + nt * 16 + lr;
        float bvv = bias ? bias[col] : 0.f;
#pragma unroll
        for (int r = 0; r < 4; r++) {
            int row = m0 + wave * 16 + quad * 4 + r;
            float v = acc[nt][r] + bvv;
            if (ACT) v = fmaxf(v, 0.f);
            Cout[(size_t)row * N + col] = v;
        }
    }
}

// ---------------- merged B/C projection GEMM (same staging as gemm_kn) ----------------
__global__ __launch_bounds__(256) void gemm_bc(const float* __restrict__ A,
                                               const float* __restrict__ WB,
                                               const float* __restrict__ WC,
                                               float* __restrict__ Bm,
                                               float* __restrict__ Cm,
                                               int M, int N, int K) {
    __shared__ __align__(16) u16 sA[64][40];
    __shared__ __align__(16) u16 sB[64][40];
    const int tid  = threadIdx.x;
    const int wave = tid >> 6, lane = tid & 63;
    const int quad = lane >> 4, lr = lane & 15;
    const int m0 = blockIdx.x * 64;
    const int isC = (blockIdx.y >= 16);
    const int n0 = (blockIdx.y & 15) * 64;
    const float* B = isC ? WC : WB;
    float* Cout = isC ? Cm : Bm;
    const int arow = tid >> 2, akoff = (tid & 3) * 8;
    const int bn_l = tid & 63, bkg = tid >> 6;

    floatx4 acc[4];
#pragma unroll
    for (int i = 0; i < 4; i++)
#pragma unroll
        for (int j = 0; j < 4; j++) acc[i][j] = 0.f;

    const float* ap = A + (size_t)(m0 + arow) * K + akoff;
    const float* bp = B + (size_t)(bkg * 8) * N + n0 + bn_l;

    for (int k0 = 0; k0 < K; k0 += 32) {
        float4 a0 = *(const float4*)(ap + k0);
        float4 a1 = *(const float4*)(ap + k0 + 4);
        const float* bq = bp + (size_t)k0 * N;
        float bv[8];
#pragma unroll
        for (int j = 0; j < 8; j++) bv[j] = bq[(size_t)j * N];
        __syncthreads();
        uint4 av;
        av.x = pack_bf2(a0.x, a0.y); av.y = pack_bf2(a0.z, a0.w);
        av.z = pack_bf2(a1.x, a1.y); av.w = pack_bf2(a1.z, a1.w);
        *(uint4*)&sA[arow][akoff] = av;
        uint4 bw;
        bw.x = pack_bf2(bv[0], bv[1]); bw.y = pack_bf2(bv[2], bv[3]);
        bw.z = pack_bf2(bv[4], bv[5]); bw.w = pack_bf2(bv[6], bv[7]);
        *(uint4*)&sB[bn_l][bkg * 8] = bw;
        __syncthreads();
        bf16x8 af = *(const bf16x8*)&sA[wave * 16 + lr][quad * 8];
#pragma unroll
        for (int nt = 0; nt < 4; nt++) {
            bf16x8 bf = *(const bf16x8*)&sB[nt * 16 + lr][quad * 8];
            acc[nt] = __builtin_amdgcn_mfma_f32_16x16x32_bf16(af, bf, acc[nt], 0, 0, 0);
        }
    }
#pragma unroll
    for (int nt = 0; nt < 4; nt++) {
        int col = n0 + nt * 16 + lr;
#pragma unroll
        for (int r = 0; r < 4; r++) {
            int row = m0 + wave * 16 + quad * 4 + r;
            Cout[(size_t)row * N + col] = acc[nt][r];
        }
    }
}

// ---------------- dt projection + softplus + decay (fused, fp32) ----------------
__global__ __launch_bounds__(256) void dt_kernel(const float* __restrict__ xb,
                                                 const float* __restrict__ W_dt,
                                                 const float* __restrict__ dt_bias,
                                                 const float* __restrict__ A_log,
                                                 float* __restrict__ dtv,
                                                 float* __restrict__ decayv) {
    int row = blockIdx.x * 16 + (threadIdx.x >> 4);
    int h   = threadIdx.x & 15;
    const float* xp = xb + (size_t)row * D_IN;
    float acc = 0.f;
    for (int k = 0; k < D_IN; k += 4) {
        float4 xv = *(const float4*)(xp + k);
        acc = fmaf(xv.x, W_dt[(size_t)(k + 0) * NHEAD + h], acc);
        acc = fmaf(xv.y, W_dt[(size_t)(k + 1) * NHEAD + h], acc);
        acc = fmaf(xv.z, W_dt[(size_t)(k + 2) * NHEAD + h], acc);
        acc = fmaf(xv.w, W_dt[(size_t)(k + 3) * NHEAD + h], acc);
    }
    float z = acc + dt_bias[h];
    float sp = (z > 20.f) ? z : log1pf(expf(z));
    float a = expf(A_log[h]);
    dtv[row * NHEAD + h]    = sp;
    decayv[row * NHEAD + h] = expf(-a * sp);
}

// ---------------- segmented SSD scan ----------------
// Block = (seg, b, h, pq): blk>>9 = seg, (blk>>6)&7 = b, (blk>>2)&15 = h, blk&3 = pq.
// Thread owns p = pq*32 + (tid>>3), n-octant (tid&7)*8 -> 8 state floats.
// WRITE_Y: compute+store y (in-place over xb). HAS_INIT: seed state from
// Hbuf slot seg-1 (seg 0 -> zeros). WRITE_FINAL: store final state to slot seg.
template <int WRITE_Y, int HAS_INIT, int WRITE_FINAL>
__global__ __launch_bounds__(256) void ssd_scan_seg(const float* __restrict__ xb,
                                                    const float* __restrict__ Bm,
                                                    const float* __restrict__ Cm,
                                                    const float* __restrict__ dtv,
                                                    const float* __restrict__ decayv,
                                                    float* __restrict__ Hbuf,
                                                    float* __restrict__ y) {
    const int blk = blockIdx.x;
    const int seg = blk >> 9;
    const int b   = (blk >> 6) & 7;
    const int h   = (blk >> 2) & 15;
    const int pq  = blk & 3;
    const int tid = threadIdx.x;
    const int pl  = tid >> 3;         // 0..31 local p
    const int oct = tid & 7;          // 0..7 n-octant

    __shared__ __align__(16) float sX[2][CHUNK][32];
    __shared__ __align__(16) float sB[2][CHUNK][64];
    __shared__ __align__(16) float sC[2][CHUNK][64];
    __shared__ float sS[2][CHUNK][2];

    // per-thread state slice offset inside a slot
    const size_t hoff = (((size_t)b * NHEAD + h) * PDIM + pq * 32 + pl) * NSTATE + oct * 8;

    float state[8];
    if (HAS_INIT && seg > 0) {
        const float* src = Hbuf + (size_t)(seg - 1) * SLOT + hoff;
        float4 s0 = *(const float4*)(src);
        float4 s1 = *(const float4*)(src + 4);
        state[0] = s0.x; state[1] = s0.y; state[2] = s0.z; state[3] = s0.w;
        state[4] = s1.x; state[5] = s1.y; state[6] = s1.z; state[7] = s1.w;
    } else {
#pragma unroll
        for (int j = 0; j < 8; j++) state[j] = 0.f;
    }

    const size_t xcol = (size_t)h * PDIM + (size_t)pq * 32;
    const size_t bcol = (size_t)h * NSTATE;
    const int NB = NHEAD * NSTATE;
    const int tbase = seg * SEGT;

    float pre[CHUNK];
    auto loadchunk = [&](int c) {
        int t0 = tbase + c * CHUNK;
#pragma unroll
        for (int ss = 0; ss < CHUNK; ++ss) {
            int r = (t0 + ss) * B_SZ + b;
            if (tid < 32)                     pre[ss] = xb[(size_t)r * D_IN + xcol + tid];
            else if (tid >= 64 && tid < 128)  pre[ss] = Bm[(size_t)r * NB + bcol + (tid - 64)];
            else if (WRITE_Y && tid >= 128 && tid < 192) pre[ss] = Cm[(size_t)r * NB + bcol + (tid - 128)];
        }
        if (tid >= 192 && tid < 192 + CHUNK * 2) {
            int ss = (tid - 192) >> 1;
            int r = (t0 + ss) * B_SZ + b;
            pre[0] = ((tid & 1) ? decayv : dtv)[r * NHEAD + h];
        }
    };
    auto writechunk = [&](int s) {
#pragma unroll
        for (int ss = 0; ss < CHUNK; ++ss) {
            if (tid < 32)                     sX[s][ss][tid] = pre[ss];
            else if (tid >= 64 && tid < 128)  sB[s][ss][tid - 64] = pre[ss];
            else if (WRITE_Y && tid >= 128 && tid < 192) sC[s][ss][tid - 128] = pre[ss];
        }
        if (tid >= 192 && tid < 192 + CHUNK * 2)
            sS[s][(tid - 192) >> 1][tid & 1] = pre[0];
    };

    loadchunk(0);
    writechunk(0);
    __syncthreads();

    const int NCH = SEGT / CHUNK;  // 16
    for (int c = 0; c < NCH; ++c) {
        int s = c & 1;
        if (c + 1 < NCH) loadchunk(c + 1);
#pragma unroll
        for (int ss = 0; ss < CHUNK; ++ss) {
            float dt  = sS[s][ss][0];
            float dec = sS[s][ss][1];
            float coef = dt * sX[s][ss][pl];
            float4 b0 = *(const float4*)&sB[s][ss][oct * 8];
            float4 b1 = *(const float4*)&sB[s][ss][oct * 8 + 4];
            state[0] = fmaf(dec, state[0], coef * b0.x);
            state[1] = fmaf(dec, state[1], coef * b0.y);
            state[2] = fmaf(dec, state[2], coef * b0.z);
            state[3] = fmaf(dec, state[3], coef * b0.w);
            state[4] = fmaf(dec, state[4], coef * b1.x);
            state[5] = fmaf(dec, state[5], coef * b1.y);
            state[6] = fmaf(dec, state[6], coef * b1.z);
            state[7] = fmaf(dec, state[7], coef * b1.w);
            if (WRITE_Y) {
                float4 c0 = *(const float4*)&sC[s][ss][oct * 8];
                float4 c1 = *(const float4*)&sC[s][ss][oct * 8 + 4];
                float ysum = 0.f;
                ysum = fmaf(state[0], c0.x, ysum); ysum = fmaf(state[1], c0.y, ysum);
                ysum = fmaf(state[2], c0.z, ysum); ysum = fmaf(state[3], c0.w, ysum);
                ysum = fmaf(state[4], c1.x, ysum); ysum = fmaf(state[5], c1.y, ysum);
                ysum = fmaf(state[6], c1.z, ysum); ysum = fmaf(state[7], c1.w, ysum);
                ysum += __shfl_xor(ysum, 1);
                ysum += __shfl_xor(ysum, 2);
                ysum += __shfl_xor(ysum, 4);
                if (oct == 0) {
                    int r = (tbase + c * CHUNK + ss) * B_SZ + b;
                    y[(size_t)r * D_IN + xcol + pl] = ysum;
                }
            }
        }
        if (c + 1 < NCH) writechunk(s ^ 1);
        __syncthreads();
    }

    if (WRITE_FINAL) {
        float* dst = Hbuf + (size_t)seg * SLOT + hoff;
        float4 s0 = make_float4(state[0], state[1], state[2], state[3]);
        float4 s1 = make_float4(state[4], state[5], state[6], state[7]);
        *(float4*)(dst) = s0;
        *(float4*)(dst + 4) = s1;
    }
}

// ---------------- prefix combine: P_s = Hloc_s + (prod decay_s) * P_{s-1} ----------------
// Grid 512 = (b, h, echunk): blk>>6 = b, (blk>>2)&15 = h, blk&3 = ec.
// Slots 1..NSEG-2 updated in place (slot 0 already = P_0).
__global__ __launch_bounds__(256) void seg_prefix(float* __restrict__ Hbuf,
                                                  const float* __restrict__ decayv) {
    const int blk = blockIdx.x;
    const int b  = blk >> 6;
    const int h  = (blk >> 2) & 15;
    const int ec = blk & 3;
    const int tid = threadIdx.x;

    __shared__ float sA[NSEG];

    // per-segment decay products for s = 1..NSEG-2 (need A_1, A_2 for NSEG=4)
    if (tid < 64 * (NSEG - 2)) {
        int s = 1 + (tid >> 6);
        int i = tid & 63;
        int t = s * SEGT + i * 2;
        float p = decayv[(t * B_SZ + b) * NHEAD + h] *
                  decayv[((t + 1) * B_SZ + b) * NHEAD + h];
        p *= __shfl_xor(p, 1);
        p *= __shfl_xor(p, 2);
        p *= __shfl_xor(p, 4);
        p *= __shfl_xor(p, 8);
        p *= __shfl_xor(p, 16);
        p *= __shfl_xor(p, 32);
        if (i == 0) sA[s] = p;
    }
    __syncthreads();

    const size_t base = (((size_t)b * NHEAD + h) * PDIM * NSTATE) + (size_t)ec * 2048 + tid * 8;
    float4 P0 = *(const float4*)(Hbuf + base);
    float4 P1 = *(const float4*)(Hbuf + base + 4);
#pragma unroll
    for (int s = 1; s <= NSEG - 2; ++s) {
        float a = sA[s];
        float* slot = Hbuf + (size_t)s * SLOT + base;
        float4 h0 = *(const float4*)(slot);
        float4 h1 = *(const float4*)(slot + 4);
        P0.x = fmaf(a, P0.x, h0.x); P0.y = fmaf(a, P0.y, h0.y);
        P0.z = fmaf(a, P0.z, h0.z); P0.w = fmaf(a, P0.w, h0.w);
        P1.x = fmaf(a, P1.x, h1.x); P1.y = fmaf(a, P1.y, h1.y);
        P1.z = fmaf(a, P1.z, h1.z); P1.w = fmaf(a, P1.w, h1.w);
        *(float4*)(slot) = P0;
        *(float4*)(slot + 4) = P1;
    }
}

// ---------------- launch ----------------
extern "C" void kernel_launch(void* const* d_in, const int* in_sizes, int n_in,
                              void* d_out, int out_size, void* d_ws, size_t ws_size,
                              hipStream_t stream) {
    const float* obs     = (const float*)d_in[0];
    const float* W_in    = (const float*)d_in[1];
    const float* b_in    = (const float*)d_in[2];
    const float* A_log   = (const float*)d_in[3];
    const float* dt_bias = (const float*)d_in[4];
    const float* W_dt    = (const float*)d_in[5];
    const float* W_B     = (const float*)d_in[6];
    const float* W_C     = (const float*)d_in[7];
    const float* W_yo    = (const float*)d_in[8];
    const float* b_yo    = (const float*)d_in[9];
    const float* W_head  = (const float*)d_in[10];
    const float* b_head  = (const float*)d_in[11];

    char* ws = (char*)d_ws;
    size_t o = 0;
    float* xb     = (float*)(ws + o); o += (size_t)ROWS * D_IN * 4;            // 32 MB (x, then y in-place)
    float* Bm     = (float*)(ws + o); o += (size_t)ROWS * NHEAD * NSTATE * 4;  // 16 MB
    float* Cm     = (float*)(ws + o); o += (size_t)ROWS * NHEAD * NSTATE * 4;  // 16 MB
    float* dtv    = (float*)(ws + o); o += (size_t)ROWS * NHEAD * 4;           // 256 KB
    float* decayv = (float*)(ws + o); o += (size_t)ROWS * NHEAD * 4;           // 256 KB
    float* zb     = (float*)(ws + o); o += (size_t)ROWS * NUNITS * 4;          // 4 MB
    float* Hseg   = (float*)(ws + o); o += (size_t)(NSEG - 1) * SLOT * 4;      // 12 MB
    // total ~80.5 MB

    // canary fill of d_out (keeps harness-required symbol launched; overwritten below)
    ActorAgent_27625229647898_kernel<<<dim3(128), 256, 0, stream>>>((float*)d_out, out_size, 0.5f);

    // ---- x = relu(obs @ W_in + b_in) ----
    gemm_kn<1><<<dim3(64, 32), 256, 0, stream>>>(obs, W_in, b_in, xb, ROWS, D_IN, OBS_D);
    // ---- dt = softplus(x @ W_dt + dt_bias); decay = exp(-exp(A_log)*dt) ----
    dt_kernel<<<dim3(ROWS / 16), 256, 0, stream>>>(xb, W_dt, dt_bias, A_log, dtv, decayv);
    // ---- B, C projections (merged) ----
    gemm_bc<<<dim3(64, 32), 256, 0, stream>>>(xb, W_B, W_C, Bm, Cm, ROWS, NHEAD * NSTATE, D_IN);
    // ---- segmented scan: A) local final states for segs 0..NSEG-2 ----
    ssd_scan_seg<0, 0, 1><<<dim3((NSEG - 1) * 512), 256, 0, stream>>>(
        xb, Bm, Cm, dtv, decayv, Hseg, xb);
    //      B) prefix combine across segments ----
    seg_prefix<<<dim3(512), 256, 0, stream>>>(Hseg, decayv);
    //      C) full scan seeded per segment, y written in-place over xb ----
    ssd_scan_seg<1, 1, 0><<<dim3(NSEG * 512), 256, 0, stream>>>(
        xb, Bm, Cm, dtv, decayv, Hseg, xb);
    // ---- z = relu(y @ W_yo + b_yo) ----
    gemm_kn<1><<<dim3(64, 4), 256, 0, stream>>>(xb, W_yo, b_yo, zb, ROWS, NUNITS, D_IN);
    // ---- logits = z @ W_head + b_head -> d_out ----
    gemm_kn<0><<<dim3(64, 1), 256, 0, stream>>>(zb, W_head, b_head, (float*)d_out, ROWS, NACT, NUNITS);
}

// Round 10
// 450.166 us; speedup vs baseline: 1.9125x; 1.0731x over previous
//
#include <hip/hip_runtime.h>
#include <cstdint>
#include <cstddef>

typedef unsigned short u16;
typedef __attribute__((ext_vector_type(8))) __bf16 bf16x8;   // MFMA A/B operand
typedef __attribute__((ext_vector_type(4))) float floatx4;   // MFMA C/D operand

// dims
#define T_DIM   512
#define B_SZ    8
#define ROWS    4096      // T*B
#define OBS_D   256
#define D_IN    2048
#define NHEAD   16
#define NSTATE  64
#define PDIM    128
#define NUNITS  256
#define NACT    64
#define CHUNK   8         // scan time-steps per LDS stage
#define NSEG    4
#define SEGT    128       // T_DIM / NSEG
#define SLOT    (B_SZ * NHEAD * PDIM * NSTATE)   // 1048576 floats = 4 MB per seg-state

__host__ __device__ __forceinline__ float bf2f(u16 u) {
    union { uint32_t i; float f; } v; v.i = ((uint32_t)u) << 16; return v.f;
}
__host__ __device__ __forceinline__ u16 f2bf(float f) {
    union { float f; uint32_t i; } v; v.f = f;
    uint32_t r = v.i + 0x7FFFu + ((v.i >> 16) & 1u);
    return (u16)(r >> 16);
}

// ---------------- fill (harness requires this symbol name; d_out canary) ----------------
__global__ __launch_bounds__(256) void ActorAgent_27625229647898_kernel(
        float* __restrict__ out, int n, float v) {
    for (int i = blockIdx.x * 256 + threadIdx.x; i < n; i += gridDim.x * 256)
        out[i] = v;
}

// ---------------- fp32 -> bf16 elementwise ----------------
__global__ __launch_bounds__(256) void cvt_bf16(const float* __restrict__ in,
                                                u16* __restrict__ out, int n) {
    for (int i = blockIdx.x * 256 + threadIdx.x; i < n; i += gridDim.x * 256)
        out[i] = f2bf(in[i]);
}

// ---------------- fp32 (R,C) -> bf16 (C,R) transpose ----------------
// Requires R%32==0, C%32==0. grid (C/32, R/32), block 256.
__global__ __launch_bounds__(256) void tpose_bf16(const float* __restrict__ in,
                                                  u16* __restrict__ out, int R, int C) {
    __shared__ float t[32][33];
    int c0 = blockIdx.x * 32, r0 = blockIdx.y * 32;
    int tx = threadIdx.x & 31, ty = threadIdx.x >> 5;
#pragma unroll
    for (int i = 0; i < 32; i += 8)
        t[ty + i][tx] = in[(size_t)(r0 + ty + i) * C + c0 + tx];
    __syncthreads();
#pragma unroll
    for (int i = 0; i < 32; i += 8)
        out[(size_t)(c0 + ty + i) * R + r0 + tx] = f2bf(t[tx][ty + i]);
}

// ---------------- bt128: 128x128-tile bf16 MFMA GEMM, B^T (N,K) layout ----------------
// C[M,N] = act(A @ BT^T + bias). A (M,K) bf16, BT (N,K) bf16. 256 thr = 4 waves
// in 2x2; each wave owns 64x64 = 4x4 MFMA tiles. K-step 32. M%128==N%128==0, K%32==0.
template <int ACT, int OUT_BF16, int HAS_BIAS>
__global__ __launch_bounds__(256) void gemm_bt128(const u16* __restrict__ A,
                                                  const u16* __restrict__ BT,
                                                  const float* __restrict__ bias,
                                                  void* __restrict__ Cout,
                                                  int M, int N, int K) {
    __shared__ __align__(16) u16 sA[128][40];  // [m][k], +8 pad (2-way free)
    __shared__ __align__(16) u16 sB[128][40];  // [n][k]
    const int tid  = threadIdx.x;
    const int wave = tid >> 6, lane = tid & 63;
    const int quad = lane >> 4, lr = lane & 15;
    const int wm = wave & 1, wn = wave >> 1;
    const int m0 = blockIdx.x * 128, n0 = blockIdx.y * 128;
    const int srow = tid >> 1, skoff = (tid & 1) * 16;  // 128 rows x 32 k, 16 el/thr

    floatx4 acc[4][4];
#pragma unroll
    for (int i = 0; i < 4; i++)
#pragma unroll
        for (int j = 0; j < 4; j++)
#pragma unroll
            for (int r = 0; r < 4; r++) acc[i][j][r] = 0.f;

    const u16* ap = A + (size_t)(m0 + srow) * K + skoff;
    const u16* bp = BT + (size_t)(n0 + srow) * K + skoff;

    for (int k0 = 0; k0 < K; k0 += 32) {
        uint4 a0 = *(const uint4*)(ap + k0);
        uint4 a1 = *(const uint4*)(ap + k0 + 8);
        uint4 b0 = *(const uint4*)(bp + k0);
        uint4 b1 = *(const uint4*)(bp + k0 + 8);
        __syncthreads();  // previous iteration's LDS readers done
        *(uint4*)&sA[srow][skoff] = a0;
        *(uint4*)&sA[srow][skoff + 8] = a1;
        *(uint4*)&sB[srow][skoff] = b0;
        *(uint4*)&sB[srow][skoff + 8] = b1;
        __syncthreads();
        bf16x8 af[4], bfr[4];
#pragma unroll
        for (int i = 0; i < 4; i++)
            af[i] = *(const bf16x8*)&sA[wm * 64 + i * 16 + lr][quad * 8];
#pragma unroll
        for (int j = 0; j < 4; j++)
            bfr[j] = *(const bf16x8*)&sB[wn * 64 + j * 16 + lr][quad * 8];
#pragma unroll
        for (int i = 0; i < 4; i++)
#pragma unroll
            for (int j = 0; j < 4; j++)
                acc[i][j] = __builtin_amdgcn_mfma_f32_16x16x32_bf16(af[i], bfr[j], acc[i][j], 0, 0, 0);
    }
    // C/D layout: col = lane&15, row = quad*4 + reg
#pragma unroll
    for (int j = 0; j < 4; j++) {
        int col = n0 + wn * 64 + j * 16 + lr;
        float bvv = HAS_BIAS ? bias[col] : 0.f;
#pragma unroll
        for (int i = 0; i < 4; i++) {
#pragma unroll
            for (int r = 0; r < 4; r++) {
                int row = m0 + wm * 64 + i * 16 + quad * 4 + r;
                float v = acc[i][j][r] + bvv;
                if (ACT) v = fmaxf(v, 0.f);
                if (OUT_BF16) ((u16*)Cout)[(size_t)row * N + col] = f2bf(v);
                else          ((float*)Cout)[(size_t)row * N + col] = v;
            }
        }
    }
}

// ---------------- bt64: 64x64-tile bf16 MFMA GEMM, B^T layout ----------------
template <int ACT, int OUT_BF16>
__global__ __launch_bounds__(256) void gemm_bt64(const u16* __restrict__ A,
                                                 const u16* __restrict__ BT,
                                                 const float* __restrict__ bias,
                                                 void* __restrict__ Cout,
                                                 int M, int N, int K) {
    __shared__ __align__(16) u16 sA[64][40];
    __shared__ __align__(16) u16 sB[64][40];
    const int tid  = threadIdx.x;
    const int wave = tid >> 6, lane = tid & 63;
    const int quad = lane >> 4, lr = lane & 15;
    const int m0 = blockIdx.x * 64, n0 = blockIdx.y * 64;
    const int arow = tid >> 2, akoff = (tid & 3) * 8;

    floatx4 acc[4];
#pragma unroll
    for (int i = 0; i < 4; i++)
#pragma unroll
        for (int j = 0; j < 4; j++) acc[i][j] = 0.f;

    const u16* ap = A + (size_t)(m0 + arow) * K + akoff;
    const u16* bp = BT + (size_t)(n0 + arow) * K + akoff;

    for (int k0 = 0; k0 < K; k0 += 32) {
        uint4 av = *(const uint4*)(ap + k0);
        uint4 bv = *(const uint4*)(bp + k0);
        __syncthreads();
        *(uint4*)&sA[arow][akoff] = av;
        *(uint4*)&sB[arow][akoff] = bv;
        __syncthreads();
        bf16x8 af = *(const bf16x8*)&sA[wave * 16 + lr][quad * 8];
#pragma unroll
        for (int nt = 0; nt < 4; nt++) {
            bf16x8 bf = *(const bf16x8*)&sB[nt * 16 + lr][quad * 8];
            acc[nt] = __builtin_amdgcn_mfma_f32_16x16x32_bf16(af, bf, acc[nt], 0, 0, 0);
        }
    }
#pragma unroll
    for (int nt = 0; nt < 4; nt++) {
        int col = n0 + nt * 16 + lr;
        float bvv = bias ? bias[col] : 0.f;
#pragma unroll
        for (int r = 0; r < 4; r++) {
            int row = m0 + wave * 16 + quad * 4 + r;
            float v = acc[nt][r] + bvv;
            if (ACT) v = fmaxf(v, 0.f);
            if (OUT_BF16) ((u16*)Cout)[(size_t)row * N + col] = f2bf(v);
            else          ((float*)Cout)[(size_t)row * N + col] = v;
        }
    }
}

// ---------------- dt: one row per block, LDS-staged x, 16h x 16strip partials ----------------
__global__ __launch_bounds__(256) void dt_kernel(const u16* __restrict__ xb,
                                                 const u16* __restrict__ Wdtb,
                                                 const float* __restrict__ dt_bias,
                                                 const float* __restrict__ A_log,
                                                 float* __restrict__ dtv,
                                                 float* __restrict__ decayv) {
    const int row = blockIdx.x;
    __shared__ __align__(16) u16 xr[D_IN];  // 4 KB
    __shared__ float part[256];
    const int tid = threadIdx.x;
    *(uint4*)&xr[tid * 8] = *(const uint4*)(xb + (size_t)row * D_IN + tid * 8);
    __syncthreads();
    const int h = tid & 15, ks = tid >> 4;
    float acc = 0.f;
    const int kb = ks * 128;
    for (int k = 0; k < 128; ++k)
        acc = fmaf(bf2f(xr[kb + k]), bf2f(Wdtb[(size_t)(kb + k) * NHEAD + h]), acc);
    part[tid] = acc;
    __syncthreads();
    if (tid < 16) {
        float s = 0.f;
        for (int k2 = 0; k2 < 16; ++k2) s += part[k2 * 16 + tid];
        float z = s + dt_bias[tid];
        float sp = (z > 20.f) ? z : log1pf(expf(z));
        float a = expf(A_log[tid]);
        dtv[row * NHEAD + tid]    = sp;
        decayv[row * NHEAD + tid] = expf(-a * sp);
    }
}

// ---------------- segmented SSD scan (bf16 x/B/C, fp32 state/LDS) ----------------
// Block = (seg, b, h, pq). Thread owns p = pq*32 + (tid>>3), n-octant (tid&7)*8.
// BCm combined: B at col h*64, C at col 1024 + h*64. y written bf16 in-place to xb.
template <int WRITE_Y, int HAS_INIT, int WRITE_FINAL>
__global__ __launch_bounds__(256) void ssd_scan_seg(const u16* __restrict__ xw,
                                                    const u16* __restrict__ BCm,
                                                    const float* __restrict__ dtv,
                                                    const float* __restrict__ decayv,
                                                    float* __restrict__ Hbuf,
                                                    u16* __restrict__ y) {
    const int blk = blockIdx.x;
    const int seg = blk >> 9;
    const int b   = (blk >> 6) & 7;
    const int h   = (blk >> 2) & 15;
    const int pq  = blk & 3;
    const int tid = threadIdx.x;
    const int pl  = tid >> 3;
    const int oct = tid & 7;

    __shared__ __align__(16) float sX[2][CHUNK][32];
    __shared__ __align__(16) float sB[2][CHUNK][64];
    __shared__ __align__(16) float sC[2][CHUNK][64];
    __shared__ float sS[2][CHUNK][2];

    const size_t hoff = (((size_t)b * NHEAD + h) * PDIM + pq * 32 + pl) * NSTATE + oct * 8;

    float state[8];
    if (HAS_INIT && seg > 0) {
        const float* src = Hbuf + (size_t)(seg - 1) * SLOT + hoff;
        float4 s0 = *(const float4*)(src);
        float4 s1 = *(const float4*)(src + 4);
        state[0] = s0.x; state[1] = s0.y; state[2] = s0.z; state[3] = s0.w;
        state[4] = s1.x; state[5] = s1.y; state[6] = s1.z; state[7] = s1.w;
    } else {
#pragma unroll
        for (int j = 0; j < 8; j++) state[j] = 0.f;
    }

    const size_t xcol = (size_t)h * PDIM + (size_t)pq * 32;
    const size_t bcol = (size_t)h * NSTATE;         // B cols
    const size_t ccol = 1024 + (size_t)h * NSTATE;  // C cols
    const int tbase = seg * SEGT;

    float pre[CHUNK];
    auto loadchunk = [&](int c) {
        int t0 = tbase + c * CHUNK;
#pragma unroll
        for (int ss = 0; ss < CHUNK; ++ss) {
            int r = (t0 + ss) * B_SZ + b;
            if (tid < 32)                     pre[ss] = bf2f(xw[(size_t)r * D_IN + xcol + tid]);
            else if (tid >= 64 && tid < 128)  pre[ss] = bf2f(BCm[(size_t)r * D_IN + bcol + (tid - 64)]);
            else if (WRITE_Y && tid >= 128 && tid < 192) pre[ss] = bf2f(BCm[(size_t)r * D_IN + ccol + (tid - 128)]);
        }
        if (tid >= 192 && tid < 192 + CHUNK * 2) {
            int ss = (tid - 192) >> 1;
            int r = (t0 + ss) * B_SZ + b;
            pre[0] = ((tid & 1) ? decayv : dtv)[r * NHEAD + h];
        }
    };
    auto writechunk = [&](int s) {
#pragma unroll
        for (int ss = 0; ss < CHUNK; ++ss) {
            if (tid < 32)                     sX[s][ss][tid] = pre[ss];
            else if (tid >= 64 && tid < 128)  sB[s][ss][tid - 64] = pre[ss];
            else if (WRITE_Y && tid >= 128 && tid < 192) sC[s][ss][tid - 128] = pre[ss];
        }
        if (tid >= 192 && tid < 192 + CHUNK * 2)
            sS[s][(tid - 192) >> 1][tid & 1] = pre[0];
    };

    loadchunk(0);
    writechunk(0);
    __syncthreads();

    const int NCH = SEGT / CHUNK;  // 16
    for (int c = 0; c < NCH; ++c) {
        int s = c & 1;
        if (c + 1 < NCH) loadchunk(c + 1);
#pragma unroll
        for (int ss = 0; ss < CHUNK; ++ss) {
            float dt  = sS[s][ss][0];
            float dec = sS[s][ss][1];
            float coef = dt * sX[s][ss][pl];
            float4 b0 = *(const float4*)&sB[s][ss][oct * 8];
            float4 b1 = *(const float4*)&sB[s][ss][oct * 8 + 4];
            state[0] = fmaf(dec, state[0], coef * b0.x);
            state[1] = fmaf(dec, state[1], coef * b0.y);
            state[2] = fmaf(dec, state[2], coef * b0.z);
            state[3] = fmaf(dec, state[3], coef * b0.w);
            state[4] = fmaf(dec, state[4], coef * b1.x);
            state[5] = fmaf(dec, state[5], coef * b1.y);
            state[6] = fmaf(dec, state[6], coef * b1.z);
            state[7] = fmaf(dec, state[7], coef * b1.w);
            if (WRITE_Y) {
                float4 c0 = *(const float4*)&sC[s][ss][oct * 8];
                float4 c1 = *(const float4*)&sC[s][ss][oct * 8 + 4];
                float ysum = 0.f;
                ysum = fmaf(state[0], c0.x, ysum); ysum = fmaf(state[1], c0.y, ysum);
                ysum = fmaf(state[2], c0.z, ysum); ysum = fmaf(state[3], c0.w, ysum);
                ysum = fmaf(state[4], c1.x, ysum); ysum = fmaf(state[5], c1.y, ysum);
                ysum = fmaf(state[6], c1.z, ysum); ysum = fmaf(state[7], c1.w, ysum);
                ysum += __shfl_xor(ysum, 1);
                ysum += __shfl_xor(ysum, 2);
                ysum += __shfl_xor(ysum, 4);
                if (oct == 0) {
                    int r = (tbase + c * CHUNK + ss) * B_SZ + b;
                    y[(size_t)r * D_IN + xcol + pl] = f2bf(ysum);
                }
            }
        }
        if (c + 1 < NCH) writechunk(s ^ 1);
        __syncthreads();
    }

    if (WRITE_FINAL) {
        float* dst = Hbuf + (size_t)seg * SLOT + hoff;
        *(float4*)(dst)     = make_float4(state[0], state[1], state[2], state[3]);
        *(float4*)(dst + 4) = make_float4(state[4], state[5], state[6], state[7]);
    }
}

// ---------------- prefix combine: P_s = Hloc_s + (prod decay_s) * P_{s-1} ----------------
__global__ __launch_bounds__(256) void seg_prefix(float* __restrict__ Hbuf,
                                                  const float* __restrict__ decayv) {
    const int blk = blockIdx.x;
    const int b  = blk >> 6;
    const int h  = (blk >> 2) & 15;
    const int ec = blk & 3;
    const int tid = threadIdx.x;

    __shared__ float sA[NSEG];

    if (tid < 64 * (NSEG - 2)) {
        int s = 1 + (tid >> 6);
        int i = tid & 63;
        int t = s * SEGT + i * 2;
        float p = decayv[(t * B_SZ + b) * NHEAD + h] *
                  decayv[((t + 1) * B_SZ + b) * NHEAD + h];
        p *= __shfl_xor(p, 1);
        p *= __shfl_xor(p, 2);
        p *= __shfl_xor(p, 4);
        p *= __shfl_xor(p, 8);
        p *= __shfl_xor(p, 16);
        p *= __shfl_xor(p, 32);
        if (i == 0) sA[s] = p;
    }
    __syncthreads();

    const size_t base = (((size_t)b * NHEAD + h) * PDIM * NSTATE) + (size_t)ec * 2048 + tid * 8;
    float4 P0 = *(const float4*)(Hbuf + base);
    float4 P1 = *(const float4*)(Hbuf + base + 4);
#pragma unroll
    for (int s = 1; s <= NSEG - 2; ++s) {
        float a = sA[s];
        float* slot = Hbuf + (size_t)s * SLOT + base;
        float4 h0 = *(const float4*)(slot);
        float4 h1 = *(const float4*)(slot + 4);
        P0.x = fmaf(a, P0.x, h0.x); P0.y = fmaf(a, P0.y, h0.y);
        P0.z = fmaf(a, P0.z, h0.z); P0.w = fmaf(a, P0.w, h0.w);
        P1.x = fmaf(a, P1.x, h1.x); P1.y = fmaf(a, P1.y, h1.y);
        P1.z = fmaf(a, P1.z, h1.z); P1.w = fmaf(a, P1.w, h1.w);
        *(float4*)(slot) = P0;
        *(float4*)(slot + 4) = P1;
    }
}

// ---------------- launch ----------------
extern "C" void kernel_launch(void* const* d_in, const int* in_sizes, int n_in,
                              void* d_out, int out_size, void* d_ws, size_t ws_size,
                              hipStream_t stream) {
    const float* obs     = (const float*)d_in[0];
    const float* W_in    = (const float*)d_in[1];
    const float* b_in    = (const float*)d_in[2];
    const float* A_log   = (const float*)d_in[3];
    const float* dt_bias = (const float*)d_in[4];
    const float* W_dt    = (const float*)d_in[5];
    const float* W_B     = (const float*)d_in[6];
    const float* W_C     = (const float*)d_in[7];
    const float* W_yo    = (const float*)d_in[8];
    const float* b_yo    = (const float*)d_in[9];
    const float* W_head  = (const float*)d_in[10];
    const float* b_head  = (const float*)d_in[11];

    char* ws = (char*)d_ws;
    size_t o = 0;
    u16*   xb     = (u16*)(ws + o);   o += (size_t)ROWS * D_IN * 2;            // 16 MB (x, then y in-place)
    u16*   BCm    = (u16*)(ws + o);   o += (size_t)ROWS * D_IN * 2;            // 16 MB (B | C)
    float* dtv    = (float*)(ws + o); o += (size_t)ROWS * NHEAD * 4;           // 256 KB
    float* decayv = (float*)(ws + o); o += (size_t)ROWS * NHEAD * 4;           // 256 KB
    u16*   zb     = (u16*)(ws + o);   o += (size_t)ROWS * NUNITS * 2;          // 2 MB
    float* Hseg   = (float*)(ws + o); o += (size_t)(NSEG - 1) * SLOT * 4;      // 12 MB
    u16*   obsb   = (u16*)(ws + o);   o += (size_t)ROWS * OBS_D * 2;           // 2 MB
    u16*   WinT   = (u16*)(ws + o);   o += (size_t)D_IN * OBS_D * 2;           // 1 MB
    u16*   WBCT   = (u16*)(ws + o);   o += (size_t)D_IN * D_IN * 2;            // 8 MB
    u16*   WyoT   = (u16*)(ws + o);   o += (size_t)NUNITS * D_IN * 2;          // 1 MB
    u16*   WheadT = (u16*)(ws + o);   o += (size_t)NACT * NUNITS * 2;          // 32 KB
    u16*   Wdtb   = (u16*)(ws + o);   o += (size_t)D_IN * NHEAD * 2;           // 64 KB
    // total ~58.6 MB

    // canary fill of d_out (keeps harness-required symbol launched; overwritten below)
    ActorAgent_27625229647898_kernel<<<dim3(128), 256, 0, stream>>>((float*)d_out, out_size, 0.5f);

    // ---- one-time converts / transposes to bf16 ----
    cvt_bf16<<<dim3(512), 256, 0, stream>>>(obs, obsb, ROWS * OBS_D);
    cvt_bf16<<<dim3(32), 256, 0, stream>>>(W_dt, Wdtb, D_IN * NHEAD);
    tpose_bf16<<<dim3(64, 8),  256, 0, stream>>>(W_in,   WinT,   OBS_D, D_IN);
    tpose_bf16<<<dim3(32, 64), 256, 0, stream>>>(W_B,    WBCT,                    D_IN, NHEAD * NSTATE);
    tpose_bf16<<<dim3(32, 64), 256, 0, stream>>>(W_C,    WBCT + (size_t)1024 * D_IN, D_IN, NHEAD * NSTATE);
    tpose_bf16<<<dim3(8, 64),  256, 0, stream>>>(W_yo,   WyoT,   D_IN, NUNITS);
    tpose_bf16<<<dim3(2, 8),   256, 0, stream>>>(W_head, WheadT, NUNITS, NACT);

    // ---- x = relu(obs @ W_in + b_in) -> bf16 ----
    gemm_bt128<1, 1, 1><<<dim3(32, 16), 256, 0, stream>>>(obsb, WinT, b_in, xb, ROWS, D_IN, OBS_D);
    // ---- dt = softplus(x @ W_dt + dt_bias); decay = exp(-exp(A_log)*dt) ----
    dt_kernel<<<dim3(ROWS), 256, 0, stream>>>(xb, Wdtb, dt_bias, A_log, dtv, decayv);
    // ---- B|C projection (single 4096x2048x2048 GEMM) -> bf16 ----
    gemm_bt128<0, 1, 0><<<dim3(32, 16), 256, 0, stream>>>(xb, WBCT, (const float*)nullptr, BCm, ROWS, D_IN, D_IN);
    // ---- segmented scan: A) local final states ----
    ssd_scan_seg<0, 0, 1><<<dim3((NSEG - 1) * 512), 256, 0, stream>>>(
        xb, BCm, dtv, decayv, Hseg, xb);
    //      B) prefix combine ----
    seg_prefix<<<dim3(512), 256, 0, stream>>>(Hseg, decayv);
    //      C) full scan seeded, y bf16 in-place over xb ----
    ssd_scan_seg<1, 1, 0><<<dim3(NSEG * 512), 256, 0, stream>>>(
        xb, BCm, dtv, decayv, Hseg, xb);
    // ---- z = relu(y @ W_yo + b_yo) -> bf16 ----
    gemm_bt64<1, 1><<<dim3(64, 4), 256, 0, stream>>>(xb, WyoT, b_yo, zb, ROWS, NUNITS, D_IN);
    // ---- logits = z @ W_head + b_head -> d_out (fp32) ----
    gemm_bt64<0, 0><<<dim3(64, 1), 256, 0, stream>>>(zb, WheadT, b_head, (float*)d_out, ROWS, NACT, NUNITS);
}

// Round 11
// 371.263 us; speedup vs baseline: 2.3190x; 1.2125x over previous
//
#include <hip/hip_runtime.h>
#include <cstdint>
#include <cstddef>

typedef unsigned short u16;
typedef __attribute__((ext_vector_type(8))) __bf16 bf16x8;   // MFMA A/B operand
typedef __attribute__((ext_vector_type(4))) float floatx4;   // MFMA C/D operand

// dims
#define T_DIM   512
#define B_SZ    8
#define ROWS    4096      // T*B
#define OBS_D   256
#define D_IN    2048
#define NHEAD   16
#define NSTATE  64
#define PDIM    128
#define NUNITS  256
#define NACT    64
#define CHUNK   8         // scan time-steps per LDS stage
#define NSEG    4
#define SEGT    128       // T_DIM / NSEG
#define SLOT    (B_SZ * NHEAD * PDIM * NSTATE)   // 1048576 floats = 4 MB per seg-state

__host__ __device__ __forceinline__ float bf2f(u16 u) {
    union { uint32_t i; float f; } v; v.i = ((uint32_t)u) << 16; return v.f;
}
__host__ __device__ __forceinline__ u16 f2bf(float f) {
    union { float f; uint32_t i; } v; v.f = f;
    uint32_t r = v.i + 0x7FFFu + ((v.i >> 16) & 1u);
    return (u16)(r >> 16);
}

// ---------------- fill (harness requires this symbol name; d_out canary) ----------------
__global__ __launch_bounds__(256) void ActorAgent_27625229647898_kernel(
        float* __restrict__ out, int n, float v) {
    for (int i = blockIdx.x * 256 + threadIdx.x; i < n; i += gridDim.x * 256)
        out[i] = v;
}

// ---------------- fp32 -> bf16 elementwise ----------------
__global__ __launch_bounds__(256) void cvt_bf16(const float* __restrict__ in,
                                                u16* __restrict__ out, int n) {
    for (int i = blockIdx.x * 256 + threadIdx.x; i < n; i += gridDim.x * 256)
        out[i] = f2bf(in[i]);
}

// ---------------- fp32 (R,C) -> bf16 (C,R) transpose ----------------
__global__ __launch_bounds__(256) void tpose_bf16(const float* __restrict__ in,
                                                  u16* __restrict__ out, int R, int C) {
    __shared__ float t[32][33];
    int c0 = blockIdx.x * 32, r0 = blockIdx.y * 32;
    int tx = threadIdx.x & 31, ty = threadIdx.x >> 5;
#pragma unroll
    for (int i = 0; i < 32; i += 8)
        t[ty + i][tx] = in[(size_t)(r0 + ty + i) * C + c0 + tx];
    __syncthreads();
#pragma unroll
    for (int i = 0; i < 32; i += 8)
        out[(size_t)(c0 + ty + i) * R + r0 + tx] = f2bf(t[tx][ty + i]);
}

// ---------------- bt128: 128x128-tile bf16 MFMA GEMM, B^T (N,K) layout ----------------
template <int ACT, int OUT_BF16, int HAS_BIAS>
__global__ __launch_bounds__(256) void gemm_bt128(const u16* __restrict__ A,
                                                  const u16* __restrict__ BT,
                                                  const float* __restrict__ bias,
                                                  void* __restrict__ Cout,
                                                  int M, int N, int K) {
    __shared__ __align__(16) u16 sA[128][40];
    __shared__ __align__(16) u16 sB[128][40];
    const int tid  = threadIdx.x;
    const int wave = tid >> 6, lane = tid & 63;
    const int quad = lane >> 4, lr = lane & 15;
    const int wm = wave & 1, wn = wave >> 1;
    const int m0 = blockIdx.x * 128, n0 = blockIdx.y * 128;
    const int srow = tid >> 1, skoff = (tid & 1) * 16;

    floatx4 acc[4][4];
#pragma unroll
    for (int i = 0; i < 4; i++)
#pragma unroll
        for (int j = 0; j < 4; j++)
#pragma unroll
            for (int r = 0; r < 4; r++) acc[i][j][r] = 0.f;

    const u16* ap = A + (size_t)(m0 + srow) * K + skoff;
    const u16* bp = BT + (size_t)(n0 + srow) * K + skoff;

    for (int k0 = 0; k0 < K; k0 += 32) {
        uint4 a0 = *(const uint4*)(ap + k0);
        uint4 a1 = *(const uint4*)(ap + k0 + 8);
        uint4 b0 = *(const uint4*)(bp + k0);
        uint4 b1 = *(const uint4*)(bp + k0 + 8);
        __syncthreads();
        *(uint4*)&sA[srow][skoff] = a0;
        *(uint4*)&sA[srow][skoff + 8] = a1;
        *(uint4*)&sB[srow][skoff] = b0;
        *(uint4*)&sB[srow][skoff + 8] = b1;
        __syncthreads();
        bf16x8 af[4], bfr[4];
#pragma unroll
        for (int i = 0; i < 4; i++)
            af[i] = *(const bf16x8*)&sA[wm * 64 + i * 16 + lr][quad * 8];
#pragma unroll
        for (int j = 0; j < 4; j++)
            bfr[j] = *(const bf16x8*)&sB[wn * 64 + j * 16 + lr][quad * 8];
#pragma unroll
        for (int i = 0; i < 4; i++)
#pragma unroll
            for (int j = 0; j < 4; j++)
                acc[i][j] = __builtin_amdgcn_mfma_f32_16x16x32_bf16(af[i], bfr[j], acc[i][j], 0, 0, 0);
    }
#pragma unroll
    for (int j = 0; j < 4; j++) {
        int col = n0 + wn * 64 + j * 16 + lr;
        float bvv = HAS_BIAS ? bias[col] : 0.f;
#pragma unroll
        for (int i = 0; i < 4; i++) {
#pragma unroll
            for (int r = 0; r < 4; r++) {
                int row = m0 + wm * 64 + i * 16 + quad * 4 + r;
                float v = acc[i][j][r] + bvv;
                if (ACT) v = fmaxf(v, 0.f);
                if (OUT_BF16) ((u16*)Cout)[(size_t)row * N + col] = f2bf(v);
                else          ((float*)Cout)[(size_t)row * N + col] = v;
            }
        }
    }
}

// ---------------- bt64: 64x64-tile bf16 MFMA GEMM, B^T layout ----------------
template <int ACT, int OUT_BF16>
__global__ __launch_bounds__(256) void gemm_bt64(const u16* __restrict__ A,
                                                 const u16* __restrict__ BT,
                                                 const float* __restrict__ bias,
                                                 void* __restrict__ Cout,
                                                 int M, int N, int K) {
    __shared__ __align__(16) u16 sA[64][40];
    __shared__ __align__(16) u16 sB[64][40];
    const int tid  = threadIdx.x;
    const int wave = tid >> 6, lane = tid & 63;
    const int quad = lane >> 4, lr = lane & 15;
    const int m0 = blockIdx.x * 64, n0 = blockIdx.y * 64;
    const int arow = tid >> 2, akoff = (tid & 3) * 8;

    floatx4 acc[4];
#pragma unroll
    for (int i = 0; i < 4; i++)
#pragma unroll
        for (int j = 0; j < 4; j++) acc[i][j] = 0.f;

    const u16* ap = A + (size_t)(m0 + arow) * K + akoff;
    const u16* bp = BT + (size_t)(n0 + arow) * K + akoff;

    for (int k0 = 0; k0 < K; k0 += 32) {
        uint4 av = *(const uint4*)(ap + k0);
        uint4 bv = *(const uint4*)(bp + k0);
        __syncthreads();
        *(uint4*)&sA[arow][akoff] = av;
        *(uint4*)&sB[arow][akoff] = bv;
        __syncthreads();
        bf16x8 af = *(const bf16x8*)&sA[wave * 16 + lr][quad * 8];
#pragma unroll
        for (int nt = 0; nt < 4; nt++) {
            bf16x8 bf = *(const bf16x8*)&sB[nt * 16 + lr][quad * 8];
            acc[nt] = __builtin_amdgcn_mfma_f32_16x16x32_bf16(af, bf, acc[nt], 0, 0, 0);
        }
    }
#pragma unroll
    for (int nt = 0; nt < 4; nt++) {
        int col = n0 + nt * 16 + lr;
        float bvv = bias ? bias[col] : 0.f;
#pragma unroll
        for (int r = 0; r < 4; r++) {
            int row = m0 + wave * 16 + quad * 4 + r;
            float v = acc[nt][r] + bvv;
            if (ACT) v = fmaxf(v, 0.f);
            if (OUT_BF16) ((u16*)Cout)[(size_t)row * N + col] = f2bf(v);
            else          ((float*)Cout)[(size_t)row * N + col] = v;
        }
    }
}

// ---------------- dt: one row per block ----------------
__global__ __launch_bounds__(256) void dt_kernel(const u16* __restrict__ xb,
                                                 const u16* __restrict__ Wdtb,
                                                 const float* __restrict__ dt_bias,
                                                 const float* __restrict__ A_log,
                                                 float* __restrict__ dtv,
                                                 float* __restrict__ decayv) {
    const int row = blockIdx.x;
    __shared__ __align__(16) u16 xr[D_IN];
    __shared__ float part[256];
    const int tid = threadIdx.x;
    *(uint4*)&xr[tid * 8] = *(const uint4*)(xb + (size_t)row * D_IN + tid * 8);
    __syncthreads();
    const int h = tid & 15, ks = tid >> 4;
    float acc = 0.f;
    const int kb = ks * 128;
    for (int k = 0; k < 128; ++k)
        acc = fmaf(bf2f(xr[kb + k]), bf2f(Wdtb[(size_t)(kb + k) * NHEAD + h]), acc);
    part[tid] = acc;
    __syncthreads();
    if (tid < 16) {
        float s = 0.f;
        for (int k2 = 0; k2 < 16; ++k2) s += part[k2 * 16 + tid];
        float z = s + dt_bias[tid];
        float sp = (z > 20.f) ? z : log1pf(expf(z));
        float a = expf(A_log[tid]);
        dtv[row * NHEAD + tid]    = sp;
        decayv[row * NHEAD + tid] = expf(-a * sp);
    }
}

// ---------------- seg_state: segment-final states as weighted outer-product sum ----------------
// H_s[p,n] = sum_t (dt_t * prod_{t'>t} dec_t') * x_t[p] * B_t[n], t in segment s.
// Block = (seg, b, h): blk>>7 = seg, (blk>>4)&7 = b, blk&15 = h. 384 blocks.
// Thread owns 4 p x 8 n = 32 accumulators: pgrp = tid>>3 (p = pgrp*4..+4), oct = tid&7.
__global__ __launch_bounds__(256) void seg_state(const u16* __restrict__ xw,
                                                 const u16* __restrict__ BCm,
                                                 const float* __restrict__ dtv,
                                                 const float* __restrict__ decayv,
                                                 float* __restrict__ Hbuf) {
    const int blk = blockIdx.x;
    const int seg = blk >> 7;
    const int b   = (blk >> 4) & 7;
    const int h   = blk & 15;
    const int tid = threadIdx.x;
    const int pgrp = tid >> 3;   // 0..31 -> p = pgrp*4
    const int oct  = tid & 7;    // n = oct*8

    __shared__ __align__(16) u16 sx[SEGT][PDIM];    // 32 KB [t][p]
    __shared__ __align__(16) u16 sbm[SEGT][NSTATE]; // 16 KB [t][n]
    __shared__ float sw[SEGT];
    __shared__ float sdt[SEGT];
    __shared__ float sdec[SEGT];
    __shared__ float sP[32];

    const int t0 = seg * SEGT;

    // ---- stage x: 128 t x 128 p bf16, 8 uint4/thread ----
#pragma unroll
    for (int k = 0; k < 8; ++k) {
        int idx = tid + k * 256;           // 0..2047
        int t = idx >> 4, c = (idx & 15) * 8;
        int r = (t0 + t) * B_SZ + b;
        *(uint4*)&sx[t][c] = *(const uint4*)(xw + (size_t)r * D_IN + h * PDIM + c);
    }
    // ---- stage B: 128 t x 64 n bf16, 4 uint4/thread ----
#pragma unroll
    for (int k = 0; k < 4; ++k) {
        int idx = tid + k * 256;           // 0..1023
        int t = idx >> 3, c = (idx & 7) * 8;
        int r = (t0 + t) * B_SZ + b;
        *(uint4*)&sbm[t][c] = *(const uint4*)(BCm + (size_t)r * D_IN + h * NSTATE + c);
    }
    // ---- stage dt / dec ----
    if (tid < SEGT)            sdt[tid] = dtv[((t0 + tid) * B_SZ + b) * NHEAD + h];
    else if (tid < 2 * SEGT)   sdec[tid - SEGT] = decayv[((t0 + tid - SEGT) * B_SZ + b) * NHEAD + h];
    __syncthreads();

    // ---- weights: w_t = dt_t * suffix-prod(dec) ; 3-phase block scan ----
    if (tid < 32) {
        float p = 1.f;
        for (int i = 3; i >= 0; --i) {
            int t = tid * 4 + i;
            sw[t] = sdt[t] * p;
            p *= sdec[t];
        }
        sP[tid] = p;
    }
    __syncthreads();
    if (tid == 0) {
        float suf = 1.f;
        for (int q = 31; q >= 0; --q) { float tmp = sP[q]; sP[q] = suf; suf *= tmp; }
    }
    __syncthreads();
    if (tid < 32) {
        float m = sP[tid];
        for (int i = 0; i < 4; ++i) sw[tid * 4 + i] *= m;
    }
    __syncthreads();

    // ---- accumulate ----
    float acc[4][8];
#pragma unroll
    for (int i = 0; i < 4; i++)
#pragma unroll
        for (int j = 0; j < 8; j++) acc[i][j] = 0.f;

    for (int t = 0; t < SEGT; ++t) {
        float w = sw[t];
        const u16* xp = &sx[t][pgrp * 4];
        const u16* bp = &sbm[t][oct * 8];
        float xv[4], bv[8];
#pragma unroll
        for (int i = 0; i < 4; i++) xv[i] = w * bf2f(xp[i]);
#pragma unroll
        for (int j = 0; j < 8; j++) bv[j] = bf2f(bp[j]);
#pragma unroll
        for (int i = 0; i < 4; i++)
#pragma unroll
            for (int j = 0; j < 8; j++)
                acc[i][j] = fmaf(xv[i], bv[j], acc[i][j]);
    }

    // ---- store H[b][h][p][n] in slot seg ----
    float* base = Hbuf + (size_t)seg * SLOT +
                  (((size_t)b * NHEAD + h) * PDIM + pgrp * 4) * NSTATE + oct * 8;
#pragma unroll
    for (int i = 0; i < 4; i++) {
        *(float4*)(base + (size_t)i * NSTATE)     = make_float4(acc[i][0], acc[i][1], acc[i][2], acc[i][3]);
        *(float4*)(base + (size_t)i * NSTATE + 4) = make_float4(acc[i][4], acc[i][5], acc[i][6], acc[i][7]);
    }
}

// ---------------- segmented SSD scan, pass C (bf16 x/B/C, fp32 state/LDS) ----------------
template <int WRITE_Y, int HAS_INIT, int WRITE_FINAL>
__global__ __launch_bounds__(256) void ssd_scan_seg(const u16* __restrict__ xw,
                                                    const u16* __restrict__ BCm,
                                                    const float* __restrict__ dtv,
                                                    const float* __restrict__ decayv,
                                                    float* __restrict__ Hbuf,
                                                    u16* __restrict__ y) {
    const int blk = blockIdx.x;
    const int seg = blk >> 9;
    const int b   = (blk >> 6) & 7;
    const int h   = (blk >> 2) & 15;
    const int pq  = blk & 3;
    const int tid = threadIdx.x;
    const int pl  = tid >> 3;
    const int oct = tid & 7;

    __shared__ __align__(16) float sX[2][CHUNK][32];
    __shared__ __align__(16) float sB[2][CHUNK][64];
    __shared__ __align__(16) float sC[2][CHUNK][64];
    __shared__ float sS[2][CHUNK][2];

    const size_t hoff = (((size_t)b * NHEAD + h) * PDIM + pq * 32 + pl) * NSTATE + oct * 8;

    float state[8];
    if (HAS_INIT && seg > 0) {
        const float* src = Hbuf + (size_t)(seg - 1) * SLOT + hoff;
        float4 s0 = *(const float4*)(src);
        float4 s1 = *(const float4*)(src + 4);
        state[0] = s0.x; state[1] = s0.y; state[2] = s0.z; state[3] = s0.w;
        state[4] = s1.x; state[5] = s1.y; state[6] = s1.z; state[7] = s1.w;
    } else {
#pragma unroll
        for (int j = 0; j < 8; j++) state[j] = 0.f;
    }

    const size_t xcol = (size_t)h * PDIM + (size_t)pq * 32;
    const size_t bcol = (size_t)h * NSTATE;
    const size_t ccol = 1024 + (size_t)h * NSTATE;
    const int tbase = seg * SEGT;

    float pre[CHUNK];
    auto loadchunk = [&](int c) {
        int t0 = tbase + c * CHUNK;
#pragma unroll
        for (int ss = 0; ss < CHUNK; ++ss) {
            int r = (t0 + ss) * B_SZ + b;
            if (tid < 32)                     pre[ss] = bf2f(xw[(size_t)r * D_IN + xcol + tid]);
            else if (tid >= 64 && tid < 128)  pre[ss] = bf2f(BCm[(size_t)r * D_IN + bcol + (tid - 64)]);
            else if (WRITE_Y && tid >= 128 && tid < 192) pre[ss] = bf2f(BCm[(size_t)r * D_IN + ccol + (tid - 128)]);
        }
        if (tid >= 192 && tid < 192 + CHUNK * 2) {
            int ss = (tid - 192) >> 1;
            int r = (t0 + ss) * B_SZ + b;
            pre[0] = ((tid & 1) ? decayv : dtv)[r * NHEAD + h];
        }
    };
    auto writechunk = [&](int s) {
#pragma unroll
        for (int ss = 0; ss < CHUNK; ++ss) {
            if (tid < 32)                     sX[s][ss][tid] = pre[ss];
            else if (tid >= 64 && tid < 128)  sB[s][ss][tid - 64] = pre[ss];
            else if (WRITE_Y && tid >= 128 && tid < 192) sC[s][ss][tid - 128] = pre[ss];
        }
        if (tid >= 192 && tid < 192 + CHUNK * 2)
            sS[s][(tid - 192) >> 1][tid & 1] = pre[0];
    };

    loadchunk(0);
    writechunk(0);
    __syncthreads();

    const int NCH = SEGT / CHUNK;
    for (int c = 0; c < NCH; ++c) {
        int s = c & 1;
        if (c + 1 < NCH) loadchunk(c + 1);
#pragma unroll
        for (int ss = 0; ss < CHUNK; ++ss) {
            float dt  = sS[s][ss][0];
            float dec = sS[s][ss][1];
            float coef = dt * sX[s][ss][pl];
            float4 b0 = *(const float4*)&sB[s][ss][oct * 8];
            float4 b1 = *(const float4*)&sB[s][ss][oct * 8 + 4];
            state[0] = fmaf(dec, state[0], coef * b0.x);
            state[1] = fmaf(dec, state[1], coef * b0.y);
            state[2] = fmaf(dec, state[2], coef * b0.z);
            state[3] = fmaf(dec, state[3], coef * b0.w);
            state[4] = fmaf(dec, state[4], coef * b1.x);
            state[5] = fmaf(dec, state[5], coef * b1.y);
            state[6] = fmaf(dec, state[6], coef * b1.z);
            state[7] = fmaf(dec, state[7], coef * b1.w);
            if (WRITE_Y) {
                float4 c0 = *(const float4*)&sC[s][ss][oct * 8];
                float4 c1 = *(const float4*)&sC[s][ss][oct * 8 + 4];
                float ysum = 0.f;
                ysum = fmaf(state[0], c0.x, ysum); ysum = fmaf(state[1], c0.y, ysum);
                ysum = fmaf(state[2], c0.z, ysum); ysum = fmaf(state[3], c0.w, ysum);
                ysum = fmaf(state[4], c1.x, ysum); ysum = fmaf(state[5], c1.y, ysum);
                ysum = fmaf(state[6], c1.z, ysum); ysum = fmaf(state[7], c1.w, ysum);
                ysum += __shfl_xor(ysum, 1);
                ysum += __shfl_xor(ysum, 2);
                ysum += __shfl_xor(ysum, 4);
                if (oct == 0) {
                    int r = (tbase + c * CHUNK + ss) * B_SZ + b;
                    y[(size_t)r * D_IN + xcol + pl] = f2bf(ysum);
                }
            }
        }
        if (c + 1 < NCH) writechunk(s ^ 1);
        __syncthreads();
    }

    if (WRITE_FINAL) {
        float* dst = Hbuf + (size_t)seg * SLOT + hoff;
        *(float4*)(dst)     = make_float4(state[0], state[1], state[2], state[3]);
        *(float4*)(dst + 4) = make_float4(state[4], state[5], state[6], state[7]);
    }
}

// ---------------- prefix combine: P_s = Hloc_s + (prod decay_s) * P_{s-1} ----------------
__global__ __launch_bounds__(256) void seg_prefix(float* __restrict__ Hbuf,
                                                  const float* __restrict__ decayv) {
    const int blk = blockIdx.x;
    const int b  = blk >> 6;
    const int h  = (blk >> 2) & 15;
    const int ec = blk & 3;
    const int tid = threadIdx.x;

    __shared__ float sA[NSEG];

    if (tid < 64 * (NSEG - 2)) {
        int s = 1 + (tid >> 6);
        int i = tid & 63;
        int t = s * SEGT + i * 2;
        float p = decayv[(t * B_SZ + b) * NHEAD + h] *
                  decayv[((t + 1) * B_SZ + b) * NHEAD + h];
        p *= __shfl_xor(p, 1);
        p *= __shfl_xor(p, 2);
        p *= __shfl_xor(p, 4);
        p *= __shfl_xor(p, 8);
        p *= __shfl_xor(p, 16);
        p *= __shfl_xor(p, 32);
        if (i == 0) sA[s] = p;
    }
    __syncthreads();

    const size_t base = (((size_t)b * NHEAD + h) * PDIM * NSTATE) + (size_t)ec * 2048 + tid * 8;
    float4 P0 = *(const float4*)(Hbuf + base);
    float4 P1 = *(const float4*)(Hbuf + base + 4);
#pragma unroll
    for (int s = 1; s <= NSEG - 2; ++s) {
        float a = sA[s];
        float* slot = Hbuf + (size_t)s * SLOT + base;
        float4 h0 = *(const float4*)(slot);
        float4 h1 = *(const float4*)(slot + 4);
        P0.x = fmaf(a, P0.x, h0.x); P0.y = fmaf(a, P0.y, h0.y);
        P0.z = fmaf(a, P0.z, h0.z); P0.w = fmaf(a, P0.w, h0.w);
        P1.x = fmaf(a, P1.x, h1.x); P1.y = fmaf(a, P1.y, h1.y);
        P1.z = fmaf(a, P1.z, h1.z); P1.w = fmaf(a, P1.w, h1.w);
        *(float4*)(slot) = P0;
        *(float4*)(slot + 4) = P1;
    }
}

// ---------------- launch ----------------
extern "C" void kernel_launch(void* const* d_in, const int* in_sizes, int n_in,
                              void* d_out, int out_size, void* d_ws, size_t ws_size,
                              hipStream_t stream) {
    const float* obs     = (const float*)d_in[0];
    const float* W_in    = (const float*)d_in[1];
    const float* b_in    = (const float*)d_in[2];
    const float* A_log   = (const float*)d_in[3];
    const float* dt_bias = (const float*)d_in[4];
    const float* W_dt    = (const float*)d_in[5];
    const float* W_B     = (const float*)d_in[6];
    const float* W_C     = (const float*)d_in[7];
    const float* W_yo    = (const float*)d_in[8];
    const float* b_yo    = (const float*)d_in[9];
    const float* W_head  = (const float*)d_in[10];
    const float* b_head  = (const float*)d_in[11];

    char* ws = (char*)d_ws;
    size_t o = 0;
    u16*   xb     = (u16*)(ws + o);   o += (size_t)ROWS * D_IN * 2;            // 16 MB (x, then y in-place)
    u16*   BCm    = (u16*)(ws + o);   o += (size_t)ROWS * D_IN * 2;            // 16 MB (B | C)
    float* dtv    = (float*)(ws + o); o += (size_t)ROWS * NHEAD * 4;
    float* decayv = (float*)(ws + o); o += (size_t)ROWS * NHEAD * 4;
    u16*   zb     = (u16*)(ws + o);   o += (size_t)ROWS * NUNITS * 2;          // 2 MB
    float* Hseg   = (float*)(ws + o); o += (size_t)(NSEG - 1) * SLOT * 4;      // 12 MB
    u16*   obsb   = (u16*)(ws + o);   o += (size_t)ROWS * OBS_D * 2;           // 2 MB
    u16*   WinT   = (u16*)(ws + o);   o += (size_t)D_IN * OBS_D * 2;           // 1 MB
    u16*   WBCT   = (u16*)(ws + o);   o += (size_t)D_IN * D_IN * 2;            // 8 MB
    u16*   WyoT   = (u16*)(ws + o);   o += (size_t)NUNITS * D_IN * 2;          // 1 MB
    u16*   WheadT = (u16*)(ws + o);   o += (size_t)NACT * NUNITS * 2;
    u16*   Wdtb   = (u16*)(ws + o);   o += (size_t)D_IN * NHEAD * 2;

    // canary fill of d_out (keeps harness-required symbol launched; overwritten below)
    ActorAgent_27625229647898_kernel<<<dim3(128), 256, 0, stream>>>((float*)d_out, out_size, 0.5f);

    // ---- one-time converts / transposes to bf16 ----
    cvt_bf16<<<dim3(512), 256, 0, stream>>>(obs, obsb, ROWS * OBS_D);
    cvt_bf16<<<dim3(32), 256, 0, stream>>>(W_dt, Wdtb, D_IN * NHEAD);
    tpose_bf16<<<dim3(64, 8),  256, 0, stream>>>(W_in,   WinT,   OBS_D, D_IN);
    tpose_bf16<<<dim3(32, 64), 256, 0, stream>>>(W_B,    WBCT,                       D_IN, NHEAD * NSTATE);
    tpose_bf16<<<dim3(32, 64), 256, 0, stream>>>(W_C,    WBCT + (size_t)1024 * D_IN, D_IN, NHEAD * NSTATE);
    tpose_bf16<<<dim3(8, 64),  256, 0, stream>>>(W_yo,   WyoT,   D_IN, NUNITS);
    tpose_bf16<<<dim3(2, 8),   256, 0, stream>>>(W_head, WheadT, NUNITS, NACT);

    // ---- x = relu(obs @ W_in + b_in) -> bf16 ----
    gemm_bt128<1, 1, 1><<<dim3(32, 16), 256, 0, stream>>>(obsb, WinT, b_in, xb, ROWS, D_IN, OBS_D);
    // ---- dt/decay ----
    dt_kernel<<<dim3(ROWS), 256, 0, stream>>>(xb, Wdtb, dt_bias, A_log, dtv, decayv);
    // ---- B|C projection ----
    gemm_bt128<0, 1, 0><<<dim3(32, 16), 256, 0, stream>>>(xb, WBCT, (const float*)nullptr, BCm, ROWS, D_IN, D_IN);
    // ---- scan A) segment-final states via weighted outer-product sums ----
    seg_state<<<dim3((NSEG - 1) * 128), 256, 0, stream>>>(xb, BCm, dtv, decayv, Hseg);
    //      B) prefix combine ----
    seg_prefix<<<dim3(512), 256, 0, stream>>>(Hseg, decayv);
    //      C) full scan seeded, y bf16 in-place over xb ----
    ssd_scan_seg<1, 1, 0><<<dim3(NSEG * 512), 256, 0, stream>>>(
        xb, BCm, dtv, decayv, Hseg, xb);
    // ---- z = relu(y @ W_yo + b_yo) -> bf16 ----
    gemm_bt64<1, 1><<<dim3(64, 4), 256, 0, stream>>>(xb, WyoT, b_yo, zb, ROWS, NUNITS, D_IN);
    // ---- logits = z @ W_head + b_head -> d_out (fp32) ----
    gemm_bt64<0, 0><<<dim3(64, 1), 256, 0, stream>>>(zb, WheadT, b_head, (float*)d_out, ROWS, NACT, NUNITS);
}

// Round 12
// 282.814 us; speedup vs baseline: 3.0443x; 1.3127x over previous
//
#include <hip/hip_runtime.h>
#include <cstdint>
#include <cstddef>

typedef unsigned short u16;
typedef __attribute__((ext_vector_type(8))) __bf16 bf16x8;   // MFMA A/B operand
typedef __attribute__((ext_vector_type(4))) float floatx4;   // MFMA C/D operand

// dims
#define T_DIM   512
#define B_SZ    8
#define ROWS    4096      // T*B
#define OBS_D   256
#define D_IN    2048
#define NHEAD   16
#define NSTATE  64
#define PDIM    128
#define NUNITS  256
#define NACT    64
#define NSEG    4
#define SEGT    128       // T_DIM / NSEG
#define SLOT    (B_SZ * NHEAD * PDIM * NSTATE)   // 1048576 floats = 4 MB per seg-state

__host__ __device__ __forceinline__ float bf2f(u16 u) {
    union { uint32_t i; float f; } v; v.i = ((uint32_t)u) << 16; return v.f;
}
__host__ __device__ __forceinline__ u16 f2bf(float f) {
    union { float f; uint32_t i; } v; v.f = f;
    uint32_t r = v.i + 0x7FFFu + ((v.i >> 16) & 1u);
    return (u16)(r >> 16);
}

// ---------------- fill (harness requires this symbol name; d_out canary) ----------------
__global__ __launch_bounds__(256) void ActorAgent_27625229647898_kernel(
        float* __restrict__ out, int n, float v) {
    for (int i = blockIdx.x * 256 + threadIdx.x; i < n; i += gridDim.x * 256)
        out[i] = v;
}

// ---------------- fp32 -> bf16 elementwise ----------------
__global__ __launch_bounds__(256) void cvt_bf16(const float* __restrict__ in,
                                                u16* __restrict__ out, int n) {
    for (int i = blockIdx.x * 256 + threadIdx.x; i < n; i += gridDim.x * 256)
        out[i] = f2bf(in[i]);
}

// ---------------- fp32 (R,C) -> bf16 (C,R) transpose ----------------
__global__ __launch_bounds__(256) void tpose_bf16(const float* __restrict__ in,
                                                  u16* __restrict__ out, int R, int C) {
    __shared__ float t[32][33];
    int c0 = blockIdx.x * 32, r0 = blockIdx.y * 32;
    int tx = threadIdx.x & 31, ty = threadIdx.x >> 5;
#pragma unroll
    for (int i = 0; i < 32; i += 8)
        t[ty + i][tx] = in[(size_t)(r0 + ty + i) * C + c0 + tx];
    __syncthreads();
#pragma unroll
    for (int i = 0; i < 32; i += 8)
        out[(size_t)(c0 + ty + i) * R + r0 + tx] = f2bf(t[tx][ty + i]);
}

// ---------------- bt128: 128x128-tile bf16 MFMA GEMM, B^T (N,K) layout ----------------
template <int ACT, int OUT_BF16, int HAS_BIAS>
__global__ __launch_bounds__(256) void gemm_bt128(const u16* __restrict__ A,
                                                  const u16* __restrict__ BT,
                                                  const float* __restrict__ bias,
                                                  void* __restrict__ Cout,
                                                  int M, int N, int K) {
    __shared__ __align__(16) u16 sA[128][40];
    __shared__ __align__(16) u16 sB[128][40];
    const int tid  = threadIdx.x;
    const int wave = tid >> 6, lane = tid & 63;
    const int quad = lane >> 4, lr = lane & 15;
    const int wm = wave & 1, wn = wave >> 1;
    const int m0 = blockIdx.x * 128, n0 = blockIdx.y * 128;
    const int srow = tid >> 1, skoff = (tid & 1) * 16;

    floatx4 acc[4][4];
#pragma unroll
    for (int i = 0; i < 4; i++)
#pragma unroll
        for (int j = 0; j < 4; j++)
#pragma unroll
            for (int r = 0; r < 4; r++) acc[i][j][r] = 0.f;

    const u16* ap = A + (size_t)(m0 + srow) * K + skoff;
    const u16* bp = BT + (size_t)(n0 + srow) * K + skoff;

    for (int k0 = 0; k0 < K; k0 += 32) {
        uint4 a0 = *(const uint4*)(ap + k0);
        uint4 a1 = *(const uint4*)(ap + k0 + 8);
        uint4 b0 = *(const uint4*)(bp + k0);
        uint4 b1 = *(const uint4*)(bp + k0 + 8);
        __syncthreads();
        *(uint4*)&sA[srow][skoff] = a0;
        *(uint4*)&sA[srow][skoff + 8] = a1;
        *(uint4*)&sB[srow][skoff] = b0;
        *(uint4*)&sB[srow][skoff + 8] = b1;
        __syncthreads();
        bf16x8 af[4], bfr[4];
#pragma unroll
        for (int i = 0; i < 4; i++)
            af[i] = *(const bf16x8*)&sA[wm * 64 + i * 16 + lr][quad * 8];
#pragma unroll
        for (int j = 0; j < 4; j++)
            bfr[j] = *(const bf16x8*)&sB[wn * 64 + j * 16 + lr][quad * 8];
#pragma unroll
        for (int i = 0; i < 4; i++)
#pragma unroll
            for (int j = 0; j < 4; j++)
                acc[i][j] = __builtin_amdgcn_mfma_f32_16x16x32_bf16(af[i], bfr[j], acc[i][j], 0, 0, 0);
    }
#pragma unroll
    for (int j = 0; j < 4; j++) {
        int col = n0 + wn * 64 + j * 16 + lr;
        float bvv = HAS_BIAS ? bias[col] : 0.f;
#pragma unroll
        for (int i = 0; i < 4; i++) {
#pragma unroll
            for (int r = 0; r < 4; r++) {
                int row = m0 + wm * 64 + i * 16 + quad * 4 + r;
                float v = acc[i][j][r] + bvv;
                if (ACT) v = fmaxf(v, 0.f);
                if (OUT_BF16) ((u16*)Cout)[(size_t)row * N + col] = f2bf(v);
                else          ((float*)Cout)[(size_t)row * N + col] = v;
            }
        }
    }
}

// ---------------- bt64: 64x64-tile bf16 MFMA GEMM, B^T layout ----------------
template <int ACT, int OUT_BF16>
__global__ __launch_bounds__(256) void gemm_bt64(const u16* __restrict__ A,
                                                 const u16* __restrict__ BT,
                                                 const float* __restrict__ bias,
                                                 void* __restrict__ Cout,
                                                 int M, int N, int K) {
    __shared__ __align__(16) u16 sA[64][40];
    __shared__ __align__(16) u16 sB[64][40];
    const int tid  = threadIdx.x;
    const int wave = tid >> 6, lane = tid & 63;
    const int quad = lane >> 4, lr = lane & 15;
    const int m0 = blockIdx.x * 64, n0 = blockIdx.y * 64;
    const int arow = tid >> 2, akoff = (tid & 3) * 8;

    floatx4 acc[4];
#pragma unroll
    for (int i = 0; i < 4; i++)
#pragma unroll
        for (int j = 0; j < 4; j++) acc[i][j] = 0.f;

    const u16* ap = A + (size_t)(m0 + arow) * K + akoff;
    const u16* bp = BT + (size_t)(n0 + arow) * K + akoff;

    for (int k0 = 0; k0 < K; k0 += 32) {
        uint4 av = *(const uint4*)(ap + k0);
        uint4 bv = *(const uint4*)(bp + k0);
        __syncthreads();
        *(uint4*)&sA[arow][akoff] = av;
        *(uint4*)&sB[arow][akoff] = bv;
        __syncthreads();
        bf16x8 af = *(const bf16x8*)&sA[wave * 16 + lr][quad * 8];
#pragma unroll
        for (int nt = 0; nt < 4; nt++) {
            bf16x8 bf = *(const bf16x8*)&sB[nt * 16 + lr][quad * 8];
            acc[nt] = __builtin_amdgcn_mfma_f32_16x16x32_bf16(af, bf, acc[nt], 0, 0, 0);
        }
    }
#pragma unroll
    for (int nt = 0; nt < 4; nt++) {
        int col = n0 + nt * 16 + lr;
        float bvv = bias ? bias[col] : 0.f;
#pragma unroll
        for (int r = 0; r < 4; r++) {
            int row = m0 + wave * 16 + quad * 4 + r;
            float v = acc[nt][r] + bvv;
            if (ACT) v = fmaxf(v, 0.f);
            if (OUT_BF16) ((u16*)Cout)[(size_t)row * N + col] = f2bf(v);
            else          ((float*)Cout)[(size_t)row * N + col] = v;
        }
    }
}

// ---------------- dt: one row per block ----------------
__global__ __launch_bounds__(256) void dt_kernel(const u16* __restrict__ xb,
                                                 const u16* __restrict__ Wdtb,
                                                 const float* __restrict__ dt_bias,
                                                 const float* __restrict__ A_log,
                                                 float* __restrict__ dtv,
                                                 float* __restrict__ decayv) {
    const int row = blockIdx.x;
    __shared__ __align__(16) u16 xr[D_IN];
    __shared__ float part[256];
    const int tid = threadIdx.x;
    *(uint4*)&xr[tid * 8] = *(const uint4*)(xb + (size_t)row * D_IN + tid * 8);
    __syncthreads();
    const int h = tid & 15, ks = tid >> 4;
    float acc = 0.f;
    const int kb = ks * 128;
    for (int k = 0; k < 128; ++k)
        acc = fmaf(bf2f(xr[kb + k]), bf2f(Wdtb[(size_t)(kb + k) * NHEAD + h]), acc);
    part[tid] = acc;
    __syncthreads();
    if (tid < 16) {
        float s = 0.f;
        for (int k2 = 0; k2 < 16; ++k2) s += part[k2 * 16 + tid];
        float z = s + dt_bias[tid];
        float sp = (z > 20.f) ? z : log1pf(expf(z));
        float a = expf(A_log[tid]);
        dtv[row * NHEAD + tid]    = sp;
        decayv[row * NHEAD + tid] = expf(-a * sp);
    }
}

// ---------------- seg_state: segment-final states as weighted outer-product sum ----------------
__global__ __launch_bounds__(256) void seg_state(const u16* __restrict__ xw,
                                                 const u16* __restrict__ BCm,
                                                 const float* __restrict__ dtv,
                                                 const float* __restrict__ decayv,
                                                 float* __restrict__ Hbuf) {
    const int blk = blockIdx.x;
    const int seg = blk >> 7;
    const int b   = (blk >> 4) & 7;
    const int h   = blk & 15;
    const int tid = threadIdx.x;
    const int pgrp = tid >> 3;
    const int oct  = tid & 7;

    __shared__ __align__(16) u16 sx[SEGT][PDIM];
    __shared__ __align__(16) u16 sbm[SEGT][NSTATE];
    __shared__ float sw[SEGT];
    __shared__ float sdt[SEGT];
    __shared__ float sdec[SEGT];
    __shared__ float sP[32];

    const int t0 = seg * SEGT;

#pragma unroll
    for (int k = 0; k < 8; ++k) {
        int idx = tid + k * 256;
        int t = idx >> 4, c = (idx & 15) * 8;
        int r = (t0 + t) * B_SZ + b;
        *(uint4*)&sx[t][c] = *(const uint4*)(xw + (size_t)r * D_IN + h * PDIM + c);
    }
#pragma unroll
    for (int k = 0; k < 4; ++k) {
        int idx = tid + k * 256;
        int t = idx >> 3, c = (idx & 7) * 8;
        int r = (t0 + t) * B_SZ + b;
        *(uint4*)&sbm[t][c] = *(const uint4*)(BCm + (size_t)r * D_IN + h * NSTATE + c);
    }
    if (tid < SEGT)            sdt[tid] = dtv[((t0 + tid) * B_SZ + b) * NHEAD + h];
    else if (tid < 2 * SEGT)   sdec[tid - SEGT] = decayv[((t0 + tid - SEGT) * B_SZ + b) * NHEAD + h];
    __syncthreads();

    if (tid < 32) {
        float p = 1.f;
        for (int i = 3; i >= 0; --i) {
            int t = tid * 4 + i;
            sw[t] = sdt[t] * p;
            p *= sdec[t];
        }
        sP[tid] = p;
    }
    __syncthreads();
    if (tid == 0) {
        float suf = 1.f;
        for (int q = 31; q >= 0; --q) { float tmp = sP[q]; sP[q] = suf; suf *= tmp; }
    }
    __syncthreads();
    if (tid < 32) {
        float m = sP[tid];
        for (int i = 0; i < 4; ++i) sw[tid * 4 + i] *= m;
    }
    __syncthreads();

    float acc[4][8];
#pragma unroll
    for (int i = 0; i < 4; i++)
#pragma unroll
        for (int j = 0; j < 8; j++) acc[i][j] = 0.f;

    for (int t = 0; t < SEGT; ++t) {
        float w = sw[t];
        const u16* xp = &sx[t][pgrp * 4];
        const u16* bp = &sbm[t][oct * 8];
        float xv[4], bv[8];
#pragma unroll
        for (int i = 0; i < 4; i++) xv[i] = w * bf2f(xp[i]);
#pragma unroll
        for (int j = 0; j < 8; j++) bv[j] = bf2f(bp[j]);
#pragma unroll
        for (int i = 0; i < 4; i++)
#pragma unroll
            for (int j = 0; j < 8; j++)
                acc[i][j] = fmaf(xv[i], bv[j], acc[i][j]);
    }

    float* base = Hbuf + (size_t)seg * SLOT +
                  (((size_t)b * NHEAD + h) * PDIM + pgrp * 4) * NSTATE + oct * 8;
#pragma unroll
    for (int i = 0; i < 4; i++) {
        *(float4*)(base + (size_t)i * NSTATE)     = make_float4(acc[i][0], acc[i][1], acc[i][2], acc[i][3]);
        *(float4*)(base + (size_t)i * NSTATE + 4) = make_float4(acc[i][4], acc[i][5], acc[i][6], acc[i][7]);
    }
}

// ---------------- prefix combine: P_s = Hloc_s + (prod decay_s) * P_{s-1} ----------------
__global__ __launch_bounds__(256) void seg_prefix(float* __restrict__ Hbuf,
                                                  const float* __restrict__ decayv) {
    const int blk = blockIdx.x;
    const int b  = blk >> 6;
    const int h  = (blk >> 2) & 15;
    const int ec = blk & 3;
    const int tid = threadIdx.x;

    __shared__ float sA[NSEG];

    if (tid < 64 * (NSEG - 2)) {
        int s = 1 + (tid >> 6);
        int i = tid & 63;
        int t = s * SEGT + i * 2;
        float p = decayv[(t * B_SZ + b) * NHEAD + h] *
                  decayv[((t + 1) * B_SZ + b) * NHEAD + h];
        p *= __shfl_xor(p, 1);
        p *= __shfl_xor(p, 2);
        p *= __shfl_xor(p, 4);
        p *= __shfl_xor(p, 8);
        p *= __shfl_xor(p, 16);
        p *= __shfl_xor(p, 32);
        if (i == 0) sA[s] = p;
    }
    __syncthreads();

    const size_t base = (((size_t)b * NHEAD + h) * PDIM * NSTATE) + (size_t)ec * 2048 + tid * 8;
    float4 P0 = *(const float4*)(Hbuf + base);
    float4 P1 = *(const float4*)(Hbuf + base + 4);
#pragma unroll
    for (int s = 1; s <= NSEG - 2; ++s) {
        float a = sA[s];
        float* slot = Hbuf + (size_t)s * SLOT + base;
        float4 h0 = *(const float4*)(slot);
        float4 h1 = *(const float4*)(slot + 4);
        P0.x = fmaf(a, P0.x, h0.x); P0.y = fmaf(a, P0.y, h0.y);
        P0.z = fmaf(a, P0.z, h0.z); P0.w = fmaf(a, P0.w, h0.w);
        P1.x = fmaf(a, P1.x, h1.x); P1.y = fmaf(a, P1.y, h1.y);
        P1.z = fmaf(a, P1.z, h1.z); P1.w = fmaf(a, P1.w, h1.w);
        *(float4*)(slot) = P0;
        *(float4*)(slot + 4) = P1;
    }
}

// ---------------- chunk_S: S'[t][t'] = mask(t,t') * (C_t . B_t') ----------------
// One block per (seg,b,h). S2 = B @ C^T via MFMA (M=t'=128, N=t=128, K=64),
// masked with dt[t']*exp(L[t]-L[t']) (t'<=t), stored bf16 row-major [t][t'].
// Also writes L (segment-local cumsum of log decay) to Lg.
__global__ __launch_bounds__(256) void chunk_S(const u16* __restrict__ BCm,
                                               const float* __restrict__ dtv,
                                               const float* __restrict__ decayv,
                                               u16* __restrict__ Sg,
                                               float* __restrict__ Lg) {
    __shared__ __align__(16) u16 smem[128 * 72 * 2];  // 36 KB: B|C, reused for S'
    __shared__ float sdt[SEGT];
    __shared__ float sL[SEGT];
    __shared__ float stmp[32];
    const int blk = blockIdx.x;
    const int seg = blk >> 7, b = (blk >> 4) & 7, h = blk & 15;
    const int tid = threadIdx.x;
    const int wave = tid >> 6, lane = tid & 63;
    const int quad = lane >> 4, lr = lane & 15;
    const int wm = wave & 1, wn = wave >> 1;
    const int t0 = seg * SEGT;

#pragma unroll
    for (int it = 0; it < 4; ++it) {
        int idx = tid + it * 256;
        int t = idx >> 3, c = (idx & 7) * 8;
        int r = (t0 + t) * B_SZ + b;
        *(uint4*)&smem[t * 72 + c]            = *(const uint4*)(BCm + (size_t)r * D_IN + h * NSTATE + c);
        *(uint4*)&smem[128 * 72 + t * 72 + c] = *(const uint4*)(BCm + (size_t)r * D_IN + 1024 + h * NSTATE + c);
    }
    if (tid < SEGT) sdt[tid] = dtv[((t0 + tid) * B_SZ + b) * NHEAD + h];
    else if (tid < 2 * SEGT) {
        int t = tid - SEGT;
        sL[t] = __logf(fmaxf(decayv[((t0 + t) * B_SZ + b) * NHEAD + h], 1e-30f));
    }
    __syncthreads();
    // inclusive prefix-sum of log-decays
    if (tid < 32) {
        float s = 0.f, v[4];
#pragma unroll
        for (int i = 0; i < 4; ++i) { s += sL[tid * 4 + i]; v[i] = s; }
        stmp[tid] = s;
#pragma unroll
        for (int i = 0; i < 4; ++i) sL[tid * 4 + i] = v[i];
    }
    __syncthreads();
    if (tid == 0) {
        float run = 0.f;
        for (int q = 0; q < 32; ++q) { float c2 = stmp[q]; stmp[q] = run; run += c2; }
    }
    __syncthreads();
    if (tid < 32) {
        float off = stmp[tid];
#pragma unroll
        for (int i = 0; i < 4; ++i) sL[tid * 4 + i] += off;
    }
    __syncthreads();

    // S2[t'][t] = sum_n B[t'][n] * C[t][n]
    floatx4 acc[4][4];
#pragma unroll
    for (int i = 0; i < 4; i++)
#pragma unroll
        for (int j = 0; j < 4; j++)
#pragma unroll
            for (int r = 0; r < 4; r++) acc[i][j][r] = 0.f;
#pragma unroll
    for (int k0 = 0; k0 < 64; k0 += 32) {
        bf16x8 af[4], bfr[4];
#pragma unroll
        for (int i = 0; i < 4; i++)
            af[i] = *(const bf16x8*)&smem[(wm * 64 + i * 16 + lr) * 72 + k0 + quad * 8];
#pragma unroll
        for (int j = 0; j < 4; j++)
            bfr[j] = *(const bf16x8*)&smem[128 * 72 + (wn * 64 + j * 16 + lr) * 72 + k0 + quad * 8];
#pragma unroll
        for (int i = 0; i < 4; i++)
#pragma unroll
            for (int j = 0; j < 4; j++)
                acc[i][j] = __builtin_amdgcn_mfma_f32_16x16x32_bf16(af[i], bfr[j], acc[i][j], 0, 0, 0);
    }
    __syncthreads();  // B/C reads done; smem becomes S' [t][t'] stride 136

    // masked transform + transposed write: row = t' = wm*64+i*16+quad*4+r, col = t = wn*64+j*16+lr
#pragma unroll
    for (int j = 0; j < 4; j++) {
        int tt = wn * 64 + j * 16 + lr;
        float Lt = sL[tt];
#pragma unroll
        for (int i = 0; i < 4; i++) {
#pragma unroll
            for (int r = 0; r < 4; r++) {
                int tp = wm * 64 + i * 16 + quad * 4 + r;
                float v = 0.f;
                if (tp <= tt) v = acc[i][j][r] * sdt[tp] * __expf(Lt - sL[tp]);
                smem[tt * 136 + tp] = f2bf(v);
            }
        }
    }
    __syncthreads();
    // coalesced store S' rows to global
#pragma unroll
    for (int it = 0; it < 8; ++it) {
        int idx = tid + it * 256;
        int t = idx >> 4, c = (idx & 15) * 8;
        *(uint4*)(Sg + (size_t)blk * 16384 + t * 128 + c) = *(const uint4*)&smem[t * 136 + c];
    }
    if (tid < SEGT) Lg[blk * SEGT + tid] = sL[tid];
}

// ---------------- chunk_Y: Y = Csc @ Hp^T + S' @ X^T, written bf16 in-place over xb ----------------
// One block per (seg,b,h). Csc[t][n] = C[t][n]*exp(L[t]); Hp[p][n] = prefix state (slot seg-1).
__global__ __launch_bounds__(256) void chunk_Y(const u16* __restrict__ Sg,
                                               const float* __restrict__ Lg,
                                               const u16* __restrict__ BCm,
                                               const float* __restrict__ Hseg,
                                               u16* __restrict__ xb) {
    __shared__ __align__(16) u16 sCs[128][72];
    __shared__ __align__(16) u16 sHp[128][72];
    __shared__ __align__(16) u16 sA[128][40];
    __shared__ __align__(16) u16 sXT[128][40];
    const int blk = blockIdx.x;
    const int seg = blk >> 7, b = (blk >> 4) & 7, h = blk & 15;
    const int tid = threadIdx.x;
    const int wave = tid >> 6, lane = tid & 63;
    const int quad = lane >> 4, lr = lane & 15;
    const int wm = wave & 1, wn = wave >> 1;
    const int t0 = seg * SEGT;

    // stage Csc [t][n] and Hp [p][n]
#pragma unroll
    for (int it = 0; it < 4; ++it) {
        int idx = tid + it * 256;
        int t = idx >> 3, c = (idx & 7) * 8;
        int r = (t0 + t) * B_SZ + b;
        float el = __expf(Lg[blk * SEGT + t]);
        uint4 cv = *(const uint4*)(BCm + (size_t)r * D_IN + 1024 + h * NSTATE + c);
        const u16* cw = (const u16*)&cv;
        u16 pk[8];
#pragma unroll
        for (int j2 = 0; j2 < 8; ++j2) pk[j2] = f2bf(el * bf2f(cw[j2]));
        *(uint4*)&sCs[t][c] = *(const uint4*)pk;
        u16 hp[8];
        if (seg > 0) {
            const float* hsrc = Hseg + (size_t)(seg - 1) * SLOT +
                                (((size_t)b * NHEAD + h) * PDIM + t) * NSTATE + c;
#pragma unroll
            for (int j2 = 0; j2 < 8; ++j2) hp[j2] = f2bf(hsrc[j2]);
        } else {
#pragma unroll
            for (int j2 = 0; j2 < 8; ++j2) hp[j2] = 0;
        }
        *(uint4*)&sHp[t][c] = *(const uint4*)hp;
    }
    __syncthreads();

    floatx4 acc[4][4];
#pragma unroll
    for (int i = 0; i < 4; i++)
#pragma unroll
        for (int j = 0; j < 4; j++)
#pragma unroll
            for (int r = 0; r < 4; r++) acc[i][j][r] = 0.f;

    // phase 1: Y += Csc @ Hp^T (K = 64)
#pragma unroll
    for (int k0 = 0; k0 < 64; k0 += 32) {
        bf16x8 af[4], bfr[4];
#pragma unroll
        for (int i = 0; i < 4; i++)
            af[i] = *(const bf16x8*)&sCs[wm * 64 + i * 16 + lr][k0 + quad * 8];
#pragma unroll
        for (int j = 0; j < 4; j++)
            bfr[j] = *(const bf16x8*)&sHp[wn * 64 + j * 16 + lr][k0 + quad * 8];
#pragma unroll
        for (int i = 0; i < 4; i++)
#pragma unroll
            for (int j = 0; j < 4; j++)
                acc[i][j] = __builtin_amdgcn_mfma_f32_16x16x32_bf16(af[i], bfr[j], acc[i][j], 0, 0, 0);
    }

    // phase 2: Y += S' @ X^T (K = 128, 4 k-tiles of 32)
    const int srow = tid >> 1, skoff = (tid & 1) * 16;
    const int px = tid & 127, koh = (tid >> 7) * 16;
    for (int kc = 0; kc < 128; kc += 32) {
        uint4 s0 = *(const uint4*)(Sg + (size_t)blk * 16384 + srow * 128 + kc + skoff);
        uint4 s1 = *(const uint4*)(Sg + (size_t)blk * 16384 + srow * 128 + kc + skoff + 8);
        u16 xv[16];
#pragma unroll
        for (int j2 = 0; j2 < 16; ++j2) {
            int tp = kc + koh + j2;
            xv[j2] = xb[(size_t)((t0 + tp) * B_SZ + b) * D_IN + h * PDIM + px];
        }
        __syncthreads();  // previous iteration's frag reads done
        *(uint4*)&sA[srow][skoff]     = s0;
        *(uint4*)&sA[srow][skoff + 8] = s1;
        *(uint4*)&sXT[px][koh]     = *(const uint4*)&xv[0];
        *(uint4*)&sXT[px][koh + 8] = *(const uint4*)&xv[8];
        __syncthreads();
        bf16x8 af[4], bfr[4];
#pragma unroll
        for (int i = 0; i < 4; i++)
            af[i] = *(const bf16x8*)&sA[wm * 64 + i * 16 + lr][quad * 8];
#pragma unroll
        for (int j = 0; j < 4; j++)
            bfr[j] = *(const bf16x8*)&sXT[wn * 64 + j * 16 + lr][quad * 8];
#pragma unroll
        for (int i = 0; i < 4; i++)
#pragma unroll
            for (int j = 0; j < 4; j++)
                acc[i][j] = __builtin_amdgcn_mfma_f32_16x16x32_bf16(af[i], bfr[j], acc[i][j], 0, 0, 0);
    }

    // epilogue: Y[t][p] -> xb (all X reads completed before last barrier)
#pragma unroll
    for (int j = 0; j < 4; j++) {
        int p = wn * 64 + j * 16 + lr;
#pragma unroll
        for (int i = 0; i < 4; i++) {
#pragma unroll
            for (int r = 0; r < 4; r++) {
                int t = wm * 64 + i * 16 + quad * 4 + r;
                xb[(size_t)((t0 + t) * B_SZ + b) * D_IN + h * PDIM + p] = f2bf(acc[i][j][r]);
            }
        }
    }
}

// ---------------- launch ----------------
extern "C" void kernel_launch(void* const* d_in, const int* in_sizes, int n_in,
                              void* d_out, int out_size, void* d_ws, size_t ws_size,
                              hipStream_t stream) {
    const float* obs     = (const float*)d_in[0];
    const float* W_in    = (const float*)d_in[1];
    const float* b_in    = (const float*)d_in[2];
    const float* A_log   = (const float*)d_in[3];
    const float* dt_bias = (const float*)d_in[4];
    const float* W_dt    = (const float*)d_in[5];
    const float* W_B     = (const float*)d_in[6];
    const float* W_C     = (const float*)d_in[7];
    const float* W_yo    = (const float*)d_in[8];
    const float* b_yo    = (const float*)d_in[9];
    const float* W_head  = (const float*)d_in[10];
    const float* b_head  = (const float*)d_in[11];

    char* ws = (char*)d_ws;
    size_t o = 0;
    u16*   xb     = (u16*)(ws + o);   o += (size_t)ROWS * D_IN * 2;            // 16 MB (x, then y in-place)
    u16*   BCm    = (u16*)(ws + o);   o += (size_t)ROWS * D_IN * 2;            // 16 MB (B | C)
    float* dtv    = (float*)(ws + o); o += (size_t)ROWS * NHEAD * 4;
    float* decayv = (float*)(ws + o); o += (size_t)ROWS * NHEAD * 4;
    u16*   zb     = (u16*)(ws + o);   o += (size_t)ROWS * NUNITS * 2;          // 2 MB
    float* Hseg   = (float*)(ws + o); o += (size_t)(NSEG - 1) * SLOT * 4;      // 12 MB
    u16*   Sg     = (u16*)(ws + o);   o += (size_t)NSEG * 128 * SEGT * SEGT * 2; // 16.8 MB
    float* Lg     = (float*)(ws + o); o += (size_t)NSEG * 128 * SEGT * 4;      // 256 KB
    u16*   obsb   = (u16*)(ws + o);   o += (size_t)ROWS * OBS_D * 2;           // 2 MB
    u16*   WinT   = (u16*)(ws + o);   o += (size_t)D_IN * OBS_D * 2;           // 1 MB
    u16*   WBCT   = (u16*)(ws + o);   o += (size_t)D_IN * D_IN * 2;            // 8 MB
    u16*   WyoT   = (u16*)(ws + o);   o += (size_t)NUNITS * D_IN * 2;          // 1 MB
    u16*   WheadT = (u16*)(ws + o);   o += (size_t)NACT * NUNITS * 2;
    u16*   Wdtb   = (u16*)(ws + o);   o += (size_t)D_IN * NHEAD * 2;

    // canary fill of d_out (keeps harness-required symbol launched; overwritten below)
    ActorAgent_27625229647898_kernel<<<dim3(128), 256, 0, stream>>>((float*)d_out, out_size, 0.5f);

    // ---- one-time converts / transposes to bf16 ----
    cvt_bf16<<<dim3(512), 256, 0, stream>>>(obs, obsb, ROWS * OBS_D);
    cvt_bf16<<<dim3(32), 256, 0, stream>>>(W_dt, Wdtb, D_IN * NHEAD);
    tpose_bf16<<<dim3(64, 8),  256, 0, stream>>>(W_in,   WinT,   OBS_D, D_IN);
    tpose_bf16<<<dim3(32, 64), 256, 0, stream>>>(W_B,    WBCT,                       D_IN, NHEAD * NSTATE);
    tpose_bf16<<<dim3(32, 64), 256, 0, stream>>>(W_C,    WBCT + (size_t)1024 * D_IN, D_IN, NHEAD * NSTATE);
    tpose_bf16<<<dim3(8, 64),  256, 0, stream>>>(W_yo,   WyoT,   D_IN, NUNITS);
    tpose_bf16<<<dim3(2, 8),   256, 0, stream>>>(W_head, WheadT, NUNITS, NACT);

    // ---- x = relu(obs @ W_in + b_in) -> bf16 ----
    gemm_bt128<1, 1, 1><<<dim3(32, 16), 256, 0, stream>>>(obsb, WinT, b_in, xb, ROWS, D_IN, OBS_D);
    // ---- dt/decay ----
    dt_kernel<<<dim3(ROWS), 256, 0, stream>>>(xb, Wdtb, dt_bias, A_log, dtv, decayv);
    // ---- B|C projection ----
    gemm_bt128<0, 1, 0><<<dim3(32, 16), 256, 0, stream>>>(xb, WBCT, (const float*)nullptr, BCm, ROWS, D_IN, D_IN);
    // ---- scan: A) segment-local final states ----
    seg_state<<<dim3((NSEG - 1) * 128), 256, 0, stream>>>(xb, BCm, dtv, decayv, Hseg);
    //          B) prefix combine ----
    seg_prefix<<<dim3(512), 256, 0, stream>>>(Hseg, decayv);
    //          C1) masked score matrices ----
    chunk_S<<<dim3(NSEG * 128), 256, 0, stream>>>(BCm, dtv, decayv, Sg, Lg);
    //          C2) Y = Csc@Hp^T + S'@X^T, in-place over xb ----
    chunk_Y<<<dim3(NSEG * 128), 256, 0, stream>>>(Sg, Lg, BCm, Hseg, xb);
    // ---- z = relu(y @ W_yo + b_yo) -> bf16 ----
    gemm_bt64<1, 1><<<dim3(64, 4), 256, 0, stream>>>(xb, WyoT, b_yo, zb, ROWS, NUNITS, D_IN);
    // ---- logits = z @ W_head + b_head -> d_out (fp32) ----
    gemm_bt64<0, 0><<<dim3(64, 1), 256, 0, stream>>>(zb, WheadT, b_head, (float*)d_out, ROWS, NACT, NUNITS);
}

// Round 13
// 256.596 us; speedup vs baseline: 3.3553x; 1.1022x over previous
//
#include <hip/hip_runtime.h>
#include <cstdint>
#include <cstddef>

typedef unsigned short u16;
typedef __attribute__((ext_vector_type(8))) __bf16 bf16x8;   // MFMA A/B operand
typedef __attribute__((ext_vector_type(4))) float floatx4;   // MFMA C/D operand

// dims
#define T_DIM   512
#define B_SZ    8
#define ROWS    4096      // T*B
#define OBS_D   256
#define D_IN    2048
#define NHEAD   16
#define NSTATE  64
#define PDIM    128
#define NUNITS  256
#define NACT    64
#define NSEG    4
#define SEGT    128       // T_DIM / NSEG
#define SLOT    (B_SZ * NHEAD * PDIM * NSTATE)   // 1048576 elems per seg-state slot

__host__ __device__ __forceinline__ float bf2f(u16 u) {
    union { uint32_t i; float f; } v; v.i = ((uint32_t)u) << 16; return v.f;
}
__host__ __device__ __forceinline__ u16 f2bf(float f) {
    union { float f; uint32_t i; } v; v.f = f;
    uint32_t r = v.i + 0x7FFFu + ((v.i >> 16) & 1u);
    return (u16)(r >> 16);
}

// async 16B/lane global->LDS (m97 pattern). lds ptr must be wave-uniform.
__device__ __forceinline__ void glds16(const u16* g, u16* l) {
    __builtin_amdgcn_global_load_lds(
        (__attribute__((address_space(1))) void*)g,
        (__attribute__((address_space(3))) void*)l, 16, 0, 0);
}

// ---------------- fill (harness requires this symbol name; d_out canary) ----------------
__global__ __launch_bounds__(256) void ActorAgent_27625229647898_kernel(
        float* __restrict__ out, int n, float v) {
    for (int i = blockIdx.x * 256 + threadIdx.x; i < n; i += gridDim.x * 256)
        out[i] = v;
}

// ---------------- prep: all weight converts + transposes in ONE launch ----------------
// blocks [0,160): flat cvt obs (1048576) then W_dt (32768)
// blocks [160, ...): 32x32 transpose tiles for W_in / W_B / W_C / W_yo / W_head
__global__ __launch_bounds__(256) void prep(const float* __restrict__ obs,
                                            const float* __restrict__ W_dt,
                                            const float* __restrict__ W_in,
                                            const float* __restrict__ W_B,
                                            const float* __restrict__ W_C,
                                            const float* __restrict__ W_yo,
                                            const float* __restrict__ W_head,
                                            u16* __restrict__ obsb, u16* __restrict__ Wdtb,
                                            u16* __restrict__ WinT, u16* __restrict__ WBCT,
                                            u16* __restrict__ WyoT, u16* __restrict__ WheadT) {
    int bid = blockIdx.x;
    if (bid < 160) {
        const int NOBS = ROWS * OBS_D;             // 1048576
        const int NDT  = D_IN * NHEAD;             // 32768
        for (int i = bid * 256 + threadIdx.x; i < NOBS + NDT; i += 160 * 256) {
            if (i < NOBS) obsb[i] = f2bf(obs[i]);
            else          Wdtb[i - NOBS] = f2bf(W_dt[i - NOBS]);
        }
        return;
    }
    bid -= 160;
    const float* src; u16* dst; int R, C, bx, by;
    if (bid < 512)       { src = W_in;   dst = WinT;   R = 256;  C = 2048; bx = bid & 63; by = bid >> 6; }
    else if (bid < 2560) { int i = bid - 512;  src = W_B;  dst = WBCT; R = 2048; C = 1024; bx = i & 31; by = i >> 5; }
    else if (bid < 4608) { int i = bid - 2560; src = W_C;  dst = WBCT + (size_t)1024 * 2048; R = 2048; C = 1024; bx = i & 31; by = i >> 5; }
    else if (bid < 5120) { int i = bid - 4608; src = W_yo; dst = WyoT; R = 2048; C = 256;  bx = i & 7;  by = i >> 3; }
    else                 { int i = bid - 5120; src = W_head; dst = WheadT; R = 256; C = 64; bx = i & 1; by = i >> 1; }
    __shared__ float t[32][33];
    int c0 = bx * 32, r0 = by * 32;
    int tx = threadIdx.x & 31, ty = threadIdx.x >> 5;
#pragma unroll
    for (int i = 0; i < 32; i += 8)
        t[ty + i][tx] = src[(size_t)(r0 + ty + i) * C + c0 + tx];
    __syncthreads();
#pragma unroll
    for (int i = 0; i < 32; i += 8)
        dst[(size_t)(c0 + ty + i) * R + r0 + tx] = f2bf(t[tx][ty + i]);
}

// ---------------- bt128: 128x128 bf16 MFMA GEMM, B^T (N,K), global_load_lds staging ----------------
// m97-style: unpadded [row][32] LDS, 4 glds16/thread/iter, 2 barriers/iter.
template <int ACT, int OUT_BF16, int HAS_BIAS>
__global__ __launch_bounds__(256) void gemm_bt128(const u16* __restrict__ A,
                                                  const u16* __restrict__ BT,
                                                  const float* __restrict__ bias,
                                                  void* __restrict__ Cout,
                                                  int M, int N, int K) {
    __shared__ __align__(16) u16 sA[128 * 32];
    __shared__ __align__(16) u16 sB[128 * 32];
    const int tid  = threadIdx.x;
    const int wave = tid >> 6, lane = tid & 63;
    const int quad = lane >> 4, lr = lane & 15;
    const int wm = wave & 1, wn = wave >> 1;
    const int m0 = blockIdx.x * 128, n0 = blockIdx.y * 128;
    const int r0 = wave * 32 + (lane >> 2);   // staged row per lane
    const int kel = (lane & 3) * 8;           // k offset (u16) per lane

    floatx4 acc[4][4];
#pragma unroll
    for (int i = 0; i < 4; i++)
#pragma unroll
        for (int j = 0; j < 4; j++)
#pragma unroll
            for (int r = 0; r < 4; r++) acc[i][j][r] = 0.f;

    const u16* apg = A + (size_t)(m0 + r0) * K + kel;
    const u16* bpg = BT + (size_t)(n0 + r0) * K + kel;
    u16* lA0 = &sA[(wave * 32) * 32];
    u16* lA1 = &sA[(wave * 32 + 16) * 32];
    u16* lB0 = &sB[(wave * 32) * 32];
    u16* lB1 = &sB[(wave * 32 + 16) * 32];

    for (int k0 = 0; k0 < K; k0 += 32) {
        __syncthreads();   // previous iteration's LDS readers done
        glds16(apg + k0, lA0);
        glds16(apg + (size_t)16 * K + k0, lA1);
        glds16(bpg + k0, lB0);
        glds16(bpg + (size_t)16 * K + k0, lB1);
        __syncthreads();   // drains vmcnt before barrier -> LDS data visible
        bf16x8 af[4], bfr[4];
#pragma unroll
        for (int i = 0; i < 4; i++)
            af[i] = *(const bf16x8*)&sA[(wm * 64 + i * 16 + lr) * 32 + quad * 8];
#pragma unroll
        for (int j = 0; j < 4; j++)
            bfr[j] = *(const bf16x8*)&sB[(wn * 64 + j * 16 + lr) * 32 + quad * 8];
#pragma unroll
        for (int i = 0; i < 4; i++)
#pragma unroll
            for (int j = 0; j < 4; j++)
                acc[i][j] = __builtin_amdgcn_mfma_f32_16x16x32_bf16(af[i], bfr[j], acc[i][j], 0, 0, 0);
    }
    // C/D layout: col = lane&15, row = quad*4 + reg
#pragma unroll
    for (int j = 0; j < 4; j++) {
        int col = n0 + wn * 64 + j * 16 + lr;
        float bvv = HAS_BIAS ? bias[col] : 0.f;
#pragma unroll
        for (int i = 0; i < 4; i++) {
#pragma unroll
            for (int r = 0; r < 4; r++) {
                int row = m0 + wm * 64 + i * 16 + quad * 4 + r;
                float v = acc[i][j][r] + bvv;
                if (ACT) v = fmaxf(v, 0.f);
                if (OUT_BF16) ((u16*)Cout)[(size_t)row * N + col] = f2bf(v);
                else          ((float*)Cout)[(size_t)row * N + col] = v;
            }
        }
    }
}

// ---------------- bt64: 64x64 bf16 MFMA GEMM, B^T layout, glds staging ----------------
template <int ACT, int OUT_BF16>
__global__ __launch_bounds__(256) void gemm_bt64(const u16* __restrict__ A,
                                                 const u16* __restrict__ BT,
                                                 const float* __restrict__ bias,
                                                 void* __restrict__ Cout,
                                                 int M, int N, int K) {
    __shared__ __align__(16) u16 sA[64 * 32];
    __shared__ __align__(16) u16 sB[64 * 32];
    const int tid  = threadIdx.x;
    const int wave = tid >> 6, lane = tid & 63;
    const int quad = lane >> 4, lr = lane & 15;
    const int m0 = blockIdx.x * 64, n0 = blockIdx.y * 64;
    const int r0 = wave * 16 + (lane >> 2);
    const int kel = (lane & 3) * 8;

    floatx4 acc[4];
#pragma unroll
    for (int i = 0; i < 4; i++)
#pragma unroll
        for (int j = 0; j < 4; j++) acc[i][j] = 0.f;

    const u16* apg = A + (size_t)(m0 + r0) * K + kel;
    const u16* bpg = BT + (size_t)(n0 + r0) * K + kel;
    u16* lA = &sA[(wave * 16) * 32];
    u16* lB = &sB[(wave * 16) * 32];

    for (int k0 = 0; k0 < K; k0 += 32) {
        __syncthreads();
        glds16(apg + k0, lA);
        glds16(bpg + k0, lB);
        __syncthreads();
        bf16x8 af = *(const bf16x8*)&sA[(wave * 16 + lr) * 32 + quad * 8];
#pragma unroll
        for (int nt = 0; nt < 4; nt++) {
            bf16x8 bf = *(const bf16x8*)&sB[(nt * 16 + lr) * 32 + quad * 8];
            acc[nt] = __builtin_amdgcn_mfma_f32_16x16x32_bf16(af, bf, acc[nt], 0, 0, 0);
        }
    }
#pragma unroll
    for (int nt = 0; nt < 4; nt++) {
        int col = n0 + nt * 16 + lr;
        float bvv = bias ? bias[col] : 0.f;
#pragma unroll
        for (int r = 0; r < 4; r++) {
            int row = m0 + wave * 16 + quad * 4 + r;
            float v = acc[nt][r] + bvv;
            if (ACT) v = fmaxf(v, 0.f);
            if (OUT_BF16) ((u16*)Cout)[(size_t)row * N + col] = f2bf(v);
            else          ((float*)Cout)[(size_t)row * N + col] = v;
        }
    }
}

// ---------------- dt: one row per block ----------------
__global__ __launch_bounds__(256) void dt_kernel(const u16* __restrict__ xb,
                                                 const u16* __restrict__ Wdtb,
                                                 const float* __restrict__ dt_bias,
                                                 const float* __restrict__ A_log,
                                                 float* __restrict__ dtv,
                                                 float* __restrict__ decayv) {
    const int row = blockIdx.x;
    __shared__ __align__(16) u16 xr[D_IN];
    __shared__ float part[256];
    const int tid = threadIdx.x;
    *(uint4*)&xr[tid * 8] = *(const uint4*)(xb + (size_t)row * D_IN + tid * 8);
    __syncthreads();
    const int h = tid & 15, ks = tid >> 4;
    float acc = 0.f;
    const int kb = ks * 128;
    for (int k = 0; k < 128; ++k)
        acc = fmaf(bf2f(xr[kb + k]), bf2f(Wdtb[(size_t)(kb + k) * NHEAD + h]), acc);
    part[tid] = acc;
    __syncthreads();
    if (tid < 16) {
        float s = 0.f;
        for (int k2 = 0; k2 < 16; ++k2) s += part[k2 * 16 + tid];
        float z = s + dt_bias[tid];
        float sp = (z > 20.f) ? z : log1pf(expf(z));
        float a = expf(A_log[tid]);
        dtv[row * NHEAD + tid]    = sp;
        decayv[row * NHEAD + tid] = expf(-a * sp);
    }
}

// ---------------- seg_state: segment-final states as weighted outer-product sum ----------------
__global__ __launch_bounds__(256) void seg_state(const u16* __restrict__ xw,
                                                 const u16* __restrict__ BCm,
                                                 const float* __restrict__ dtv,
                                                 const float* __restrict__ decayv,
                                                 float* __restrict__ Hbuf) {
    const int blk = blockIdx.x;
    const int seg = blk >> 7;
    const int b   = (blk >> 4) & 7;
    const int h   = blk & 15;
    const int tid = threadIdx.x;
    const int pgrp = tid >> 3;
    const int oct  = tid & 7;

    __shared__ __align__(16) u16 sx[SEGT][PDIM];
    __shared__ __align__(16) u16 sbm[SEGT][NSTATE];
    __shared__ float sw[SEGT];
    __shared__ float sdt[SEGT];
    __shared__ float sdec[SEGT];
    __shared__ float sP[32];

    const int t0 = seg * SEGT;

#pragma unroll
    for (int k = 0; k < 8; ++k) {
        int idx = tid + k * 256;
        int t = idx >> 4, c = (idx & 15) * 8;
        int r = (t0 + t) * B_SZ + b;
        *(uint4*)&sx[t][c] = *(const uint4*)(xw + (size_t)r * D_IN + h * PDIM + c);
    }
#pragma unroll
    for (int k = 0; k < 4; ++k) {
        int idx = tid + k * 256;
        int t = idx >> 3, c = (idx & 7) * 8;
        int r = (t0 + t) * B_SZ + b;
        *(uint4*)&sbm[t][c] = *(const uint4*)(BCm + (size_t)r * D_IN + h * NSTATE + c);
    }
    if (tid < SEGT)            sdt[tid] = dtv[((t0 + tid) * B_SZ + b) * NHEAD + h];
    else if (tid < 2 * SEGT)   sdec[tid - SEGT] = decayv[((t0 + tid - SEGT) * B_SZ + b) * NHEAD + h];
    __syncthreads();

    if (tid < 32) {
        float p = 1.f;
        for (int i = 3; i >= 0; --i) {
            int t = tid * 4 + i;
            sw[t] = sdt[t] * p;
            p *= sdec[t];
        }
        sP[tid] = p;
    }
    __syncthreads();
    if (tid == 0) {
        float suf = 1.f;
        for (int q = 31; q >= 0; --q) { float tmp = sP[q]; sP[q] = suf; suf *= tmp; }
    }
    __syncthreads();
    if (tid < 32) {
        float m = sP[tid];
        for (int i = 0; i < 4; ++i) sw[tid * 4 + i] *= m;
    }
    __syncthreads();

    float acc[4][8];
#pragma unroll
    for (int i = 0; i < 4; i++)
#pragma unroll
        for (int j = 0; j < 8; j++) acc[i][j] = 0.f;

    for (int t = 0; t < SEGT; ++t) {
        float w = sw[t];
        const u16* xp = &sx[t][pgrp * 4];
        const u16* bp = &sbm[t][oct * 8];
        float xv[4], bv[8];
#pragma unroll
        for (int i = 0; i < 4; i++) xv[i] = w * bf2f(xp[i]);
#pragma unroll
        for (int j = 0; j < 8; j++) bv[j] = bf2f(bp[j]);
#pragma unroll
        for (int i = 0; i < 4; i++)
#pragma unroll
            for (int j = 0; j < 8; j++)
                acc[i][j] = fmaf(xv[i], bv[j], acc[i][j]);
    }

    float* base = Hbuf + (size_t)seg * SLOT +
                  (((size_t)b * NHEAD + h) * PDIM + pgrp * 4) * NSTATE + oct * 8;
#pragma unroll
    for (int i = 0; i < 4; i++) {
        *(float4*)(base + (size_t)i * NSTATE)     = make_float4(acc[i][0], acc[i][1], acc[i][2], acc[i][3]);
        *(float4*)(base + (size_t)i * NSTATE + 4) = make_float4(acc[i][4], acc[i][5], acc[i][6], acc[i][7]);
    }
}

// ---------------- prefix combine -> bf16 prefix states Hbf ----------------
// P_s = Hloc_s + (prod decay_s) * P_{s-1}; emits bf16 slots 0..NSEG-2 (consumed by chunk_scan).
__global__ __launch_bounds__(256) void seg_prefix(const float* __restrict__ Hbuf,
                                                  const float* __restrict__ decayv,
                                                  u16* __restrict__ Hbf) {
    const int blk = blockIdx.x;
    const int b  = blk >> 6;
    const int h  = (blk >> 2) & 15;
    const int ec = blk & 3;
    const int tid = threadIdx.x;

    __shared__ float sA[NSEG];

    if (tid < 64 * (NSEG - 2)) {
        int s = 1 + (tid >> 6);
        int i = tid & 63;
        int t = s * SEGT + i * 2;
        float p = decayv[(t * B_SZ + b) * NHEAD + h] *
                  decayv[((t + 1) * B_SZ + b) * NHEAD + h];
        p *= __shfl_xor(p, 1);
        p *= __shfl_xor(p, 2);
        p *= __shfl_xor(p, 4);
        p *= __shfl_xor(p, 8);
        p *= __shfl_xor(p, 16);
        p *= __shfl_xor(p, 32);
        if (i == 0) sA[s] = p;
    }
    __syncthreads();

    const size_t base = (((size_t)b * NHEAD + h) * PDIM * NSTATE) + (size_t)ec * 2048 + tid * 8;
    float4 P0 = *(const float4*)(Hbuf + base);
    float4 P1 = *(const float4*)(Hbuf + base + 4);
    u16 pk[8];
    pk[0] = f2bf(P0.x); pk[1] = f2bf(P0.y); pk[2] = f2bf(P0.z); pk[3] = f2bf(P0.w);
    pk[4] = f2bf(P1.x); pk[5] = f2bf(P1.y); pk[6] = f2bf(P1.z); pk[7] = f2bf(P1.w);
    *(uint4*)(Hbf + base) = *(const uint4*)pk;
#pragma unroll
    for (int s = 1; s <= NSEG - 2; ++s) {
        float a = sA[s];
        const float* slot = Hbuf + (size_t)s * SLOT + base;
        float4 h0 = *(const float4*)(slot);
        float4 h1 = *(const float4*)(slot + 4);
        P0.x = fmaf(a, P0.x, h0.x); P0.y = fmaf(a, P0.y, h0.y);
        P0.z = fmaf(a, P0.z, h0.z); P0.w = fmaf(a, P0.w, h0.w);
        P1.x = fmaf(a, P1.x, h1.x); P1.y = fmaf(a, P1.y, h1.y);
        P1.z = fmaf(a, P1.z, h1.z); P1.w = fmaf(a, P1.w, h1.w);
        pk[0] = f2bf(P0.x); pk[1] = f2bf(P0.y); pk[2] = f2bf(P0.z); pk[3] = f2bf(P0.w);
        pk[4] = f2bf(P1.x); pk[5] = f2bf(P1.y); pk[6] = f2bf(P1.z); pk[7] = f2bf(P1.w);
        *(uint4*)(Hbf + (size_t)s * SLOT + base) = *(const uint4*)pk;
    }
}

// ---------------- chunk_scan: fused S' build + Y = exp(L).C@Hp^T + S'@X^T ----------------
// One block per (seg,b,h); S' kept in LDS (no global round-trip). y bf16 in-place over xb.
__global__ __launch_bounds__(256) void chunk_scan(const u16* __restrict__ BCm,
                                                  const float* __restrict__ dtv,
                                                  const float* __restrict__ decayv,
                                                  const u16* __restrict__ Hbf,
                                                  u16* __restrict__ xb) {
    __shared__ __align__(16) u16 sB_[128][68];   // B [t'][n]
    __shared__ __align__(16) u16 sC_[128][68];   // C [t][n]
    __shared__ __align__(16) u16 sS[128][132];   // S' [t][t']
    __shared__ __align__(16) u16 sXT[128][36];   // X^T [p][k-tile]
    __shared__ float sdt[SEGT], sL[SEGT], sEL[SEGT], stmp[32];

    const int blk = blockIdx.x;
    const int seg = blk >> 7, b = (blk >> 4) & 7, h = blk & 15;
    const int tid = threadIdx.x;
    const int wave = tid >> 6, lane = tid & 63;
    const int quad = lane >> 4, lr = lane & 15;
    const int wm = wave & 1, wn = wave >> 1;
    const int t0 = seg * SEGT;

    // ---- stage B, C, dt, log-decay ----
#pragma unroll
    for (int it = 0; it < 4; ++it) {
        int idx = tid + it * 256;
        int t = idx >> 3, c = (idx & 7) * 8;
        int r = (t0 + t) * B_SZ + b;
        *(uint4*)&sB_[t][c] = *(const uint4*)(BCm + (size_t)r * D_IN + h * NSTATE + c);
        *(uint4*)&sC_[t][c] = *(const uint4*)(BCm + (size_t)r * D_IN + 1024 + h * NSTATE + c);
    }
    if (tid < SEGT) sdt[tid] = dtv[((t0 + tid) * B_SZ + b) * NHEAD + h];
    else if (tid < 2 * SEGT) {
        int t = tid - SEGT;
        sL[t] = __logf(fmaxf(decayv[((t0 + t) * B_SZ + b) * NHEAD + h], 1e-30f));
    }
    __syncthreads();
    // ---- inclusive prefix-sum of log-decays ----
    if (tid < 32) {
        float s = 0.f, v[4];
#pragma unroll
        for (int i = 0; i < 4; ++i) { s += sL[tid * 4 + i]; v[i] = s; }
        stmp[tid] = s;
#pragma unroll
        for (int i = 0; i < 4; ++i) sL[tid * 4 + i] = v[i];
    }
    __syncthreads();
    if (tid == 0) {
        float run = 0.f;
        for (int q = 0; q < 32; ++q) { float c2 = stmp[q]; stmp[q] = run; run += c2; }
    }
    __syncthreads();
    if (tid < 32) {
        float off = stmp[tid];
#pragma unroll
        for (int i = 0; i < 4; ++i) sL[tid * 4 + i] += off;
    }
    __syncthreads();
    if (tid < SEGT) sEL[tid] = __expf(sL[tid]);

    // ---- S2 = B @ C^T (M=t', N=t, K=64) ----
    floatx4 accS[4][4];
#pragma unroll
    for (int i = 0; i < 4; i++)
#pragma unroll
        for (int j = 0; j < 4; j++)
#pragma unroll
            for (int r = 0; r < 4; r++) accS[i][j][r] = 0.f;
#pragma unroll
    for (int k0 = 0; k0 < 64; k0 += 32) {
        bf16x8 af[4], bfr[4];
#pragma unroll
        for (int i = 0; i < 4; i++)
            af[i] = *(const bf16x8*)&sB_[wm * 64 + i * 16 + lr][k0 + quad * 8];
#pragma unroll
        for (int j = 0; j < 4; j++)
            bfr[j] = *(const bf16x8*)&sC_[wn * 64 + j * 16 + lr][k0 + quad * 8];
#pragma unroll
        for (int i = 0; i < 4; i++)
#pragma unroll
            for (int j = 0; j < 4; j++)
                accS[i][j] = __builtin_amdgcn_mfma_f32_16x16x32_bf16(af[i], bfr[j], accS[i][j], 0, 0, 0);
    }
    // ---- masked transform, transposed write into sS[t][t'] ----
#pragma unroll
    for (int j = 0; j < 4; j++) {
        int tt = wn * 64 + j * 16 + lr;
        float Lt = sL[tt];
#pragma unroll
        for (int i = 0; i < 4; i++) {
#pragma unroll
            for (int r = 0; r < 4; r++) {
                int tp = wm * 64 + i * 16 + quad * 4 + r;
                float v = 0.f;
                if (tp <= tt) v = accS[i][j][r] * sdt[tp] * __expf(Lt - sL[tp]);
                sS[tt][tp] = f2bf(v);
            }
        }
    }

    // ---- phase 1: Y = C @ Hp^T, rows scaled by exp(L[t]) ----
    floatx4 acc[4][4];
#pragma unroll
    for (int i = 0; i < 4; i++)
#pragma unroll
        for (int j = 0; j < 4; j++)
#pragma unroll
            for (int r = 0; r < 4; r++) acc[i][j][r] = 0.f;
    __syncthreads();  // sS + sEL visible to all
    if (seg > 0) {
        const u16* hbase = Hbf + (size_t)(seg - 1) * SLOT + (((size_t)b * NHEAD + h) * PDIM) * NSTATE;
#pragma unroll
        for (int k0 = 0; k0 < 64; k0 += 32) {
            bf16x8 af[4], bfr[4];
#pragma unroll
            for (int i = 0; i < 4; i++)
                af[i] = *(const bf16x8*)&sC_[wm * 64 + i * 16 + lr][k0 + quad * 8];
#pragma unroll
            for (int j = 0; j < 4; j++)
                bfr[j] = *(const bf16x8*)(hbase + (size_t)(wn * 64 + j * 16 + lr) * NSTATE + k0 + quad * 8);
#pragma unroll
            for (int i = 0; i < 4; i++)
#pragma unroll
                for (int j = 0; j < 4; j++)
                    acc[i][j] = __builtin_amdgcn_mfma_f32_16x16x32_bf16(af[i], bfr[j], acc[i][j], 0, 0, 0);
        }
#pragma unroll
        for (int i = 0; i < 4; i++) {
#pragma unroll
            for (int r = 0; r < 4; r++) {
                float el = sEL[wm * 64 + i * 16 + quad * 4 + r];
#pragma unroll
                for (int j = 0; j < 4; j++) acc[i][j][r] *= el;
            }
        }
    }

    // ---- phase 2: Y += S' @ X^T (K = 128, 4 k-tiles) ----
    const int px = tid & 127, koh = (tid >> 7) * 16;
    for (int kc = 0; kc < 128; kc += 32) {
        u16 xv[16];
#pragma unroll
        for (int j2 = 0; j2 < 16; ++j2) {
            int tp = kc + koh + j2;
            xv[j2] = xb[(size_t)((t0 + tp) * B_SZ + b) * D_IN + h * PDIM + px];
        }
        __syncthreads();  // previous k-tile's sXT reads done
        *(uint4*)&sXT[px][koh]     = *(const uint4*)&xv[0];
        *(uint4*)&sXT[px][koh + 8] = *(const uint4*)&xv[8];
        __syncthreads();
        bf16x8 af[4], bfr[4];
#pragma unroll
        for (int i = 0; i < 4; i++)
            af[i] = *(const bf16x8*)&sS[wm * 64 + i * 16 + lr][kc + quad * 8];
#pragma unroll
        for (int j = 0; j < 4; j++)
            bfr[j] = *(const bf16x8*)&sXT[wn * 64 + j * 16 + lr][quad * 8];
#pragma unroll
        for (int i = 0; i < 4; i++)
#pragma unroll
            for (int j = 0; j < 4; j++)
                acc[i][j] = __builtin_amdgcn_mfma_f32_16x16x32_bf16(af[i], bfr[j], acc[i][j], 0, 0, 0);
    }

    // ---- epilogue: Y[t][p] -> xb (all X reads completed before last barrier) ----
#pragma unroll
    for (int j = 0; j < 4; j++) {
        int p = wn * 64 + j * 16 + lr;
#pragma unroll
        for (int i = 0; i < 4; i++) {
#pragma unroll
            for (int r = 0; r < 4; r++) {
                int t = wm * 64 + i * 16 + quad * 4 + r;
                xb[(size_t)((t0 + t) * B_SZ + b) * D_IN + h * PDIM + p] = f2bf(acc[i][j][r]);
            }
        }
    }
}

// ---------------- launch ----------------
extern "C" void kernel_launch(void* const* d_in, const int* in_sizes, int n_in,
                              void* d_out, int out_size, void* d_ws, size_t ws_size,
                              hipStream_t stream) {
    const float* obs     = (const float*)d_in[0];
    const float* W_in    = (const float*)d_in[1];
    const float* b_in    = (const float*)d_in[2];
    const float* A_log   = (const float*)d_in[3];
    const float* dt_bias = (const float*)d_in[4];
    const float* W_dt    = (const float*)d_in[5];
    const float* W_B     = (const float*)d_in[6];
    const float* W_C     = (const float*)d_in[7];
    const float* W_yo    = (const float*)d_in[8];
    const float* b_yo    = (const float*)d_in[9];
    const float* W_head  = (const float*)d_in[10];
    const float* b_head  = (const float*)d_in[11];

    char* ws = (char*)d_ws;
    size_t o = 0;
    u16*   xb     = (u16*)(ws + o);   o += (size_t)ROWS * D_IN * 2;            // 16 MB (x, then y in-place)
    u16*   BCm    = (u16*)(ws + o);   o += (size_t)ROWS * D_IN * 2;            // 16 MB (B | C)
    float* dtv    = (float*)(ws + o); o += (size_t)ROWS * NHEAD * 4;
    float* decayv = (float*)(ws + o); o += (size_t)ROWS * NHEAD * 4;
    u16*   zb     = (u16*)(ws + o);   o += (size_t)ROWS * NUNITS * 2;          // 2 MB
    float* Hseg   = (float*)(ws + o); o += (size_t)(NSEG - 1) * SLOT * 4;      // 12 MB
    u16*   Hbf    = (u16*)(ws + o);   o += (size_t)(NSEG - 1) * SLOT * 2;      // 6 MB
    u16*   obsb   = (u16*)(ws + o);   o += (size_t)ROWS * OBS_D * 2;           // 2 MB
    u16*   WinT   = (u16*)(ws + o);   o += (size_t)D_IN * OBS_D * 2;           // 1 MB
    u16*   WBCT   = (u16*)(ws + o);   o += (size_t)D_IN * D_IN * 2;            // 8 MB
    u16*   WyoT   = (u16*)(ws + o);   o += (size_t)NUNITS * D_IN * 2;          // 1 MB
    u16*   WheadT = (u16*)(ws + o);   o += (size_t)NACT * NUNITS * 2;
    u16*   Wdtb   = (u16*)(ws + o);   o += (size_t)D_IN * NHEAD * 2;

    // canary fill of d_out (keeps harness-required symbol launched; overwritten below)
    ActorAgent_27625229647898_kernel<<<dim3(128), 256, 0, stream>>>((float*)d_out, out_size, 0.5f);

    // ---- all weight prep in one launch ----
    prep<<<dim3(160 + 5136), 256, 0, stream>>>(obs, W_dt, W_in, W_B, W_C, W_yo, W_head,
                                               obsb, Wdtb, WinT, WBCT, WyoT, WheadT);

    // ---- x = relu(obs @ W_in + b_in) -> bf16 ----
    gemm_bt128<1, 1, 1><<<dim3(32, 16), 256, 0, stream>>>(obsb, WinT, b_in, xb, ROWS, D_IN, OBS_D);
    // ---- dt/decay ----
    dt_kernel<<<dim3(ROWS), 256, 0, stream>>>(xb, Wdtb, dt_bias, A_log, dtv, decayv);
    // ---- B|C projection ----
    gemm_bt128<0, 1, 0><<<dim3(32, 16), 256, 0, stream>>>(xb, WBCT, (const float*)nullptr, BCm, ROWS, D_IN, D_IN);
    // ---- scan: A) segment-local final states ----
    seg_state<<<dim3((NSEG - 1) * 128), 256, 0, stream>>>(xb, BCm, dtv, decayv, Hseg);
    //          B) prefix combine -> bf16 ----
    seg_prefix<<<dim3(512), 256, 0, stream>>>(Hseg, decayv, Hbf);
    //          C) fused S' + Y, in-place over xb ----
    chunk_scan<<<dim3(NSEG * 128), 256, 0, stream>>>(BCm, dtv, decayv, Hbf, xb);
    // ---- z = relu(y @ W_yo + b_yo) -> bf16 ----
    gemm_bt64<1, 1><<<dim3(64, 4), 256, 0, stream>>>(xb, WyoT, b_yo, zb, ROWS, NUNITS, D_IN);
    // ---- logits = z @ W_head + b_head -> d_out (fp32) ----
    gemm_bt64<0, 0><<<dim3(64, 1), 256, 0, stream>>>(zb, WheadT, b_head, (float*)d_out, ROWS, NACT, NUNITS);
}

// Round 14
// 254.408 us; speedup vs baseline: 3.3842x; 1.0086x over previous
//
#include <hip/hip_runtime.h>
#include <cstdint>
#include <cstddef>

typedef unsigned short u16;
typedef __attribute__((ext_vector_type(8))) __bf16 bf16x8;   // MFMA A/B operand
typedef __attribute__((ext_vector_type(4))) float floatx4;   // MFMA C/D operand

// dims
#define T_DIM   512
#define B_SZ    8
#define ROWS    4096      // T*B
#define OBS_D   256
#define D_IN    2048
#define NHEAD   16
#define NSTATE  64
#define PDIM    128
#define NUNITS  256
#define NACT    64
#define NSEG    4
#define SEGT    128       // T_DIM / NSEG
#define SLOT    (B_SZ * NHEAD * PDIM * NSTATE)   // 1048576 elems per seg-state slot

__host__ __device__ __forceinline__ float bf2f(u16 u) {
    union { uint32_t i; float f; } v; v.i = ((uint32_t)u) << 16; return v.f;
}
__host__ __device__ __forceinline__ u16 f2bf(float f) {
    union { float f; uint32_t i; } v; v.f = f;
    uint32_t r = v.i + 0x7FFFu + ((v.i >> 16) & 1u);
    return (u16)(r >> 16);
}

// async 16B/lane global->LDS (m97 pattern). lds ptr must be wave-uniform.
__device__ __forceinline__ void glds16(const u16* g, u16* l) {
    __builtin_amdgcn_global_load_lds(
        (__attribute__((address_space(1))) void*)g,
        (__attribute__((address_space(3))) void*)l, 16, 0, 0);
}

// ---------------- harness-required symbol (zero-work launch keeps it referenced) ----------------
__global__ __launch_bounds__(256) void ActorAgent_27625229647898_kernel(
        float* __restrict__ out, int n, float v) {
    for (int i = blockIdx.x * 256 + threadIdx.x; i < n; i += gridDim.x * 256)
        out[i] = v;
}

// ---------------- prep: all weight converts + transposes in ONE launch ----------------
__global__ __launch_bounds__(256) void prep(const float* __restrict__ obs,
                                            const float* __restrict__ W_dt,
                                            const float* __restrict__ W_in,
                                            const float* __restrict__ W_B,
                                            const float* __restrict__ W_C,
                                            const float* __restrict__ W_yo,
                                            const float* __restrict__ W_head,
                                            u16* __restrict__ obsb, u16* __restrict__ Wdtb,
                                            u16* __restrict__ WinT, u16* __restrict__ WBCT,
                                            u16* __restrict__ WyoT, u16* __restrict__ WheadT) {
    int bid = blockIdx.x;
    if (bid < 160) {
        const int NOBS = ROWS * OBS_D;             // 1048576
        const int NDT  = D_IN * NHEAD;             // 32768
        for (int i = bid * 256 + threadIdx.x; i < NOBS + NDT; i += 160 * 256) {
            if (i < NOBS) obsb[i] = f2bf(obs[i]);
            else          Wdtb[i - NOBS] = f2bf(W_dt[i - NOBS]);
        }
        return;
    }
    bid -= 160;
    const float* src; u16* dst; int R, C, bx, by;
    if (bid < 512)       { src = W_in;   dst = WinT;   R = 256;  C = 2048; bx = bid & 63; by = bid >> 6; }
    else if (bid < 2560) { int i = bid - 512;  src = W_B;  dst = WBCT; R = 2048; C = 1024; bx = i & 31; by = i >> 5; }
    else if (bid < 4608) { int i = bid - 2560; src = W_C;  dst = WBCT + (size_t)1024 * 2048; R = 2048; C = 1024; bx = i & 31; by = i >> 5; }
    else if (bid < 5120) { int i = bid - 4608; src = W_yo; dst = WyoT; R = 2048; C = 256;  bx = i & 7;  by = i >> 3; }
    else                 { int i = bid - 5120; src = W_head; dst = WheadT; R = 256; C = 64; bx = i & 1; by = i >> 1; }
    __shared__ float t[32][33];
    int c0 = bx * 32, r0 = by * 32;
    int tx = threadIdx.x & 31, ty = threadIdx.x >> 5;
#pragma unroll
    for (int i = 0; i < 32; i += 8)
        t[ty + i][tx] = src[(size_t)(r0 + ty + i) * C + c0 + tx];
    __syncthreads();
#pragma unroll
    for (int i = 0; i < 32; i += 8)
        dst[(size_t)(c0 + ty + i) * R + r0 + tx] = f2bf(t[tx][ty + i]);
}

// ---------------- bt128: 128x128 bf16 MFMA GEMM, B^T (N,K), BK=64 glds staging ----------------
// Unpadded [row][64] LDS; 8 glds16/iter; 2 barriers per 64-deep K-slab (32 MFMA/wave).
template <int ACT, int OUT_BF16, int HAS_BIAS>
__global__ __launch_bounds__(256) void gemm_bt128(const u16* __restrict__ A,
                                                  const u16* __restrict__ BT,
                                                  const float* __restrict__ bias,
                                                  void* __restrict__ Cout,
                                                  int M, int N, int K) {
    __shared__ __align__(16) u16 sA[128 * 64];  // 16 KB
    __shared__ __align__(16) u16 sB[128 * 64];  // 16 KB
    const int tid  = threadIdx.x;
    const int wave = tid >> 6, lane = tid & 63;
    const int quad = lane >> 4, lr = lane & 15;
    const int wm = wave & 1, wn = wave >> 1;
    const int m0 = blockIdx.x * 128, n0 = blockIdx.y * 128;
    // staging: lane -> row (lane>>3), col (lane&7)*8; each glds16 covers 8 rows x 64 k
    const int srl = lane >> 3, sc = (lane & 7) * 8;

    floatx4 acc[4][4];
#pragma unroll
    for (int i = 0; i < 4; i++)
#pragma unroll
        for (int j = 0; j < 4; j++)
#pragma unroll
            for (int r = 0; r < 4; r++) acc[i][j][r] = 0.f;

    const u16* apg = A + (size_t)(m0 + wave * 32 + srl) * K + sc;
    const u16* bpg = BT + (size_t)(n0 + wave * 32 + srl) * K + sc;

    for (int k0 = 0; k0 < K; k0 += 64) {
        __syncthreads();   // previous slab's LDS readers done
#pragma unroll
        for (int g = 0; g < 4; ++g) {
            glds16(apg + (size_t)(g * 8) * K + k0, &sA[(wave * 32 + g * 8) * 64]);
            glds16(bpg + (size_t)(g * 8) * K + k0, &sB[(wave * 32 + g * 8) * 64]);
        }
        __syncthreads();   // drain vmcnt -> LDS visible
#pragma unroll
        for (int ks = 0; ks < 2; ++ks) {
            bf16x8 af[4], bfr[4];
#pragma unroll
            for (int i = 0; i < 4; i++)
                af[i] = *(const bf16x8*)&sA[(wm * 64 + i * 16 + lr) * 64 + ks * 32 + quad * 8];
#pragma unroll
            for (int j = 0; j < 4; j++)
                bfr[j] = *(const bf16x8*)&sB[(wn * 64 + j * 16 + lr) * 64 + ks * 32 + quad * 8];
#pragma unroll
            for (int i = 0; i < 4; i++)
#pragma unroll
                for (int j = 0; j < 4; j++)
                    acc[i][j] = __builtin_amdgcn_mfma_f32_16x16x32_bf16(af[i], bfr[j], acc[i][j], 0, 0, 0);
        }
    }
    // C/D layout: col = lane&15, row = quad*4 + reg
#pragma unroll
    for (int j = 0; j < 4; j++) {
        int col = n0 + wn * 64 + j * 16 + lr;
        float bvv = HAS_BIAS ? bias[col] : 0.f;
#pragma unroll
        for (int i = 0; i < 4; i++) {
#pragma unroll
            for (int r = 0; r < 4; r++) {
                int row = m0 + wm * 64 + i * 16 + quad * 4 + r;
                float v = acc[i][j][r] + bvv;
                if (ACT) v = fmaxf(v, 0.f);
                if (OUT_BF16) ((u16*)Cout)[(size_t)row * N + col] = f2bf(v);
                else          ((float*)Cout)[(size_t)row * N + col] = v;
            }
        }
    }
}

// ---------------- bt64: 64x64 bf16 MFMA GEMM, B^T layout, BK=64 glds staging ----------------
template <int ACT, int OUT_BF16>
__global__ __launch_bounds__(256) void gemm_bt64(const u16* __restrict__ A,
                                                 const u16* __restrict__ BT,
                                                 const float* __restrict__ bias,
                                                 void* __restrict__ Cout,
                                                 int M, int N, int K) {
    __shared__ __align__(16) u16 sA[64 * 64];  // 8 KB
    __shared__ __align__(16) u16 sB[64 * 64];
    const int tid  = threadIdx.x;
    const int wave = tid >> 6, lane = tid & 63;
    const int quad = lane >> 4, lr = lane & 15;
    const int m0 = blockIdx.x * 64, n0 = blockIdx.y * 64;
    const int srl = lane >> 3, sc = (lane & 7) * 8;

    floatx4 acc[4];
#pragma unroll
    for (int i = 0; i < 4; i++)
#pragma unroll
        for (int j = 0; j < 4; j++) acc[i][j] = 0.f;

    const u16* apg = A + (size_t)(m0 + wave * 16 + srl) * K + sc;
    const u16* bpg = BT + (size_t)(n0 + wave * 16 + srl) * K + sc;

    for (int k0 = 0; k0 < K; k0 += 64) {
        __syncthreads();
#pragma unroll
        for (int g = 0; g < 2; ++g) {
            glds16(apg + (size_t)(g * 8) * K + k0, &sA[(wave * 16 + g * 8) * 64]);
            glds16(bpg + (size_t)(g * 8) * K + k0, &sB[(wave * 16 + g * 8) * 64]);
        }
        __syncthreads();
#pragma unroll
        for (int ks = 0; ks < 2; ++ks) {
            bf16x8 af = *(const bf16x8*)&sA[(wave * 16 + lr) * 64 + ks * 32 + quad * 8];
#pragma unroll
            for (int nt = 0; nt < 4; nt++) {
                bf16x8 bf = *(const bf16x8*)&sB[(nt * 16 + lr) * 64 + ks * 32 + quad * 8];
                acc[nt] = __builtin_amdgcn_mfma_f32_16x16x32_bf16(af, bf, acc[nt], 0, 0, 0);
            }
        }
    }
#pragma unroll
    for (int nt = 0; nt < 4; nt++) {
        int col = n0 + nt * 16 + lr;
        float bvv = bias ? bias[col] : 0.f;
#pragma unroll
        for (int r = 0; r < 4; r++) {
            int row = m0 + wave * 16 + quad * 4 + r;
            float v = acc[nt][r] + bvv;
            if (ACT) v = fmaxf(v, 0.f);
            if (OUT_BF16) ((u16*)Cout)[(size_t)row * N + col] = f2bf(v);
            else          ((float*)Cout)[(size_t)row * N + col] = v;
        }
    }
}

// ---------------- dt: one row per block ----------------
__global__ __launch_bounds__(256) void dt_kernel(const u16* __restrict__ xb,
                                                 const u16* __restrict__ Wdtb,
                                                 const float* __restrict__ dt_bias,
                                                 const float* __restrict__ A_log,
                                                 float* __restrict__ dtv,
                                                 float* __restrict__ decayv) {
    const int row = blockIdx.x;
    __shared__ __align__(16) u16 xr[D_IN];
    __shared__ float part[256];
    const int tid = threadIdx.x;
    *(uint4*)&xr[tid * 8] = *(const uint4*)(xb + (size_t)row * D_IN + tid * 8);
    __syncthreads();
    const int h = tid & 15, ks = tid >> 4;
    float acc = 0.f;
    const int kb = ks * 128;
    for (int k = 0; k < 128; ++k)
        acc = fmaf(bf2f(xr[kb + k]), bf2f(Wdtb[(size_t)(kb + k) * NHEAD + h]), acc);
    part[tid] = acc;
    __syncthreads();
    if (tid < 16) {
        float s = 0.f;
        for (int k2 = 0; k2 < 16; ++k2) s += part[k2 * 16 + tid];
        float z = s + dt_bias[tid];
        float sp = (z > 20.f) ? z : log1pf(expf(z));
        float a = expf(A_log[tid]);
        dtv[row * NHEAD + tid]    = sp;
        decayv[row * NHEAD + tid] = expf(-a * sp);
    }
}

// ---------------- seg_state: segment-final states as weighted outer-product sum ----------------
__global__ __launch_bounds__(256) void seg_state(const u16* __restrict__ xw,
                                                 const u16* __restrict__ BCm,
                                                 const float* __restrict__ dtv,
                                                 const float* __restrict__ decayv,
                                                 float* __restrict__ Hbuf) {
    const int blk = blockIdx.x;
    const int seg = blk >> 7;
    const int b   = (blk >> 4) & 7;
    const int h   = blk & 15;
    const int tid = threadIdx.x;
    const int pgrp = tid >> 3;
    const int oct  = tid & 7;

    __shared__ __align__(16) u16 sx[SEGT][PDIM];
    __shared__ __align__(16) u16 sbm[SEGT][NSTATE];
    __shared__ float sw[SEGT];
    __shared__ float sdt[SEGT];
    __shared__ float sdec[SEGT];
    __shared__ float sP[32];

    const int t0 = seg * SEGT;

#pragma unroll
    for (int k = 0; k < 8; ++k) {
        int idx = tid + k * 256;
        int t = idx >> 4, c = (idx & 15) * 8;
        int r = (t0 + t) * B_SZ + b;
        *(uint4*)&sx[t][c] = *(const uint4*)(xw + (size_t)r * D_IN + h * PDIM + c);
    }
#pragma unroll
    for (int k = 0; k < 4; ++k) {
        int idx = tid + k * 256;
        int t = idx >> 3, c = (idx & 7) * 8;
        int r = (t0 + t) * B_SZ + b;
        *(uint4*)&sbm[t][c] = *(const uint4*)(BCm + (size_t)r * D_IN + h * NSTATE + c);
    }
    if (tid < SEGT)            sdt[tid] = dtv[((t0 + tid) * B_SZ + b) * NHEAD + h];
    else if (tid < 2 * SEGT)   sdec[tid - SEGT] = decayv[((t0 + tid - SEGT) * B_SZ + b) * NHEAD + h];
    __syncthreads();

    if (tid < 32) {
        float p = 1.f;
        for (int i = 3; i >= 0; --i) {
            int t = tid * 4 + i;
            sw[t] = sdt[t] * p;
            p *= sdec[t];
        }
        sP[tid] = p;
    }
    __syncthreads();
    if (tid == 0) {
        float suf = 1.f;
        for (int q = 31; q >= 0; --q) { float tmp = sP[q]; sP[q] = suf; suf *= tmp; }
    }
    __syncthreads();
    if (tid < 32) {
        float m = sP[tid];
        for (int i = 0; i < 4; ++i) sw[tid * 4 + i] *= m;
    }
    __syncthreads();

    float acc[4][8];
#pragma unroll
    for (int i = 0; i < 4; i++)
#pragma unroll
        for (int j = 0; j < 8; j++) acc[i][j] = 0.f;

    for (int t = 0; t < SEGT; ++t) {
        float w = sw[t];
        const u16* xp = &sx[t][pgrp * 4];
        const u16* bp = &sbm[t][oct * 8];
        float xv[4], bv[8];
#pragma unroll
        for (int i = 0; i < 4; i++) xv[i] = w * bf2f(xp[i]);
#pragma unroll
        for (int j = 0; j < 8; j++) bv[j] = bf2f(bp[j]);
#pragma unroll
        for (int i = 0; i < 4; i++)
#pragma unroll
            for (int j = 0; j < 8; j++)
                acc[i][j] = fmaf(xv[i], bv[j], acc[i][j]);
    }

    float* base = Hbuf + (size_t)seg * SLOT +
                  (((size_t)b * NHEAD + h) * PDIM + pgrp * 4) * NSTATE + oct * 8;
#pragma unroll
    for (int i = 0; i < 4; i++) {
        *(float4*)(base + (size_t)i * NSTATE)     = make_float4(acc[i][0], acc[i][1], acc[i][2], acc[i][3]);
        *(float4*)(base + (size_t)i * NSTATE + 4) = make_float4(acc[i][4], acc[i][5], acc[i][6], acc[i][7]);
    }
}

// ---------------- prefix combine -> bf16 prefix states Hbf ----------------
__global__ __launch_bounds__(256) void seg_prefix(const float* __restrict__ Hbuf,
                                                  const float* __restrict__ decayv,
                                                  u16* __restrict__ Hbf) {
    const int blk = blockIdx.x;
    const int b  = blk >> 6;
    const int h  = (blk >> 2) & 15;
    const int ec = blk & 3;
    const int tid = threadIdx.x;

    __shared__ float sA[NSEG];

    if (tid < 64 * (NSEG - 2)) {
        int s = 1 + (tid >> 6);
        int i = tid & 63;
        int t = s * SEGT + i * 2;
        float p = decayv[(t * B_SZ + b) * NHEAD + h] *
                  decayv[((t + 1) * B_SZ + b) * NHEAD + h];
        p *= __shfl_xor(p, 1);
        p *= __shfl_xor(p, 2);
        p *= __shfl_xor(p, 4);
        p *= __shfl_xor(p, 8);
        p *= __shfl_xor(p, 16);
        p *= __shfl_xor(p, 32);
        if (i == 0) sA[s] = p;
    }
    __syncthreads();

    const size_t base = (((size_t)b * NHEAD + h) * PDIM * NSTATE) + (size_t)ec * 2048 + tid * 8;
    float4 P0 = *(const float4*)(Hbuf + base);
    float4 P1 = *(const float4*)(Hbuf + base + 4);
    u16 pk[8];
    pk[0] = f2bf(P0.x); pk[1] = f2bf(P0.y); pk[2] = f2bf(P0.z); pk[3] = f2bf(P0.w);
    pk[4] = f2bf(P1.x); pk[5] = f2bf(P1.y); pk[6] = f2bf(P1.z); pk[7] = f2bf(P1.w);
    *(uint4*)(Hbf + base) = *(const uint4*)pk;
#pragma unroll
    for (int s = 1; s <= NSEG - 2; ++s) {
        float a = sA[s];
        const float* slot = Hbuf + (size_t)s * SLOT + base;
        float4 h0 = *(const float4*)(slot);
        float4 h1 = *(const float4*)(slot + 4);
        P0.x = fmaf(a, P0.x, h0.x); P0.y = fmaf(a, P0.y, h0.y);
        P0.z = fmaf(a, P0.z, h0.z); P0.w = fmaf(a, P0.w, h0.w);
        P1.x = fmaf(a, P1.x, h1.x); P1.y = fmaf(a, P1.y, h1.y);
        P1.z = fmaf(a, P1.z, h1.z); P1.w = fmaf(a, P1.w, h1.w);
        pk[0] = f2bf(P0.x); pk[1] = f2bf(P0.y); pk[2] = f2bf(P0.z); pk[3] = f2bf(P0.w);
        pk[4] = f2bf(P1.x); pk[5] = f2bf(P1.y); pk[6] = f2bf(P1.z); pk[7] = f2bf(P1.w);
        *(uint4*)(Hbf + (size_t)s * SLOT + base) = *(const uint4*)pk;
    }
}

// ---------------- chunk_scan: fused S' build + Y = exp(L).C@Hp^T + S'@X^T ----------------
__global__ __launch_bounds__(256) void chunk_scan(const u16* __restrict__ BCm,
                                                  const float* __restrict__ dtv,
                                                  const float* __restrict__ decayv,
                                                  const u16* __restrict__ Hbf,
                                                  u16* __restrict__ xb) {
    __shared__ __align__(16) u16 sB_[128][68];   // B [t'][n]
    __shared__ __align__(16) u16 sC_[128][68];   // C [t][n]
    __shared__ __align__(16) u16 sS[128][132];   // S' [t][t']
    __shared__ __align__(16) u16 sXT[128][36];   // X^T [p][k-tile]
    __shared__ float sdt[SEGT], sL[SEGT], sEL[SEGT], stmp[32];

    const int blk = blockIdx.x;
    const int seg = blk >> 7, b = (blk >> 4) & 7, h = blk & 15;
    const int tid = threadIdx.x;
    const int wave = tid >> 6, lane = tid & 63;
    const int quad = lane >> 4, lr = lane & 15;
    const int wm = wave & 1, wn = wave >> 1;
    const int t0 = seg * SEGT;

#pragma unroll
    for (int it = 0; it < 4; ++it) {
        int idx = tid + it * 256;
        int t = idx >> 3, c = (idx & 7) * 8;
        int r = (t0 + t) * B_SZ + b;
        *(uint4*)&sB_[t][c] = *(const uint4*)(BCm + (size_t)r * D_IN + h * NSTATE + c);
        *(uint4*)&sC_[t][c] = *(const uint4*)(BCm + (size_t)r * D_IN + 1024 + h * NSTATE + c);
    }
    if (tid < SEGT) sdt[tid] = dtv[((t0 + tid) * B_SZ + b) * NHEAD + h];
    else if (tid < 2 * SEGT) {
        int t = tid - SEGT;
        sL[t] = __logf(fmaxf(decayv[((t0 + t) * B_SZ + b) * NHEAD + h], 1e-30f));
    }
    __syncthreads();
    if (tid < 32) {
        float s = 0.f, v[4];
#pragma unroll
        for (int i = 0; i < 4; ++i) { s += sL[tid * 4 + i]; v[i] = s; }
        stmp[tid] = s;
#pragma unroll
        for (int i = 0; i < 4; ++i) sL[tid * 4 + i] = v[i];
    }
    __syncthreads();
    if (tid == 0) {
        float run = 0.f;
        for (int q = 0; q < 32; ++q) { float c2 = stmp[q]; stmp[q] = run; run += c2; }
    }
    __syncthreads();
    if (tid < 32) {
        float off = stmp[tid];
#pragma unroll
        for (int i = 0; i < 4; ++i) sL[tid * 4 + i] += off;
    }
    __syncthreads();
    if (tid < SEGT) sEL[tid] = __expf(sL[tid]);

    floatx4 accS[4][4];
#pragma unroll
    for (int i = 0; i < 4; i++)
#pragma unroll
        for (int j = 0; j < 4; j++)
#pragma unroll
            for (int r = 0; r < 4; r++) accS[i][j][r] = 0.f;
#pragma unroll
    for (int k0 = 0; k0 < 64; k0 += 32) {
        bf16x8 af[4], bfr[4];
#pragma unroll
        for (int i = 0; i < 4; i++)
            af[i] = *(const bf16x8*)&sB_[wm * 64 + i * 16 + lr][k0 + quad * 8];
#pragma unroll
        for (int j = 0; j < 4; j++)
            bfr[j] = *(const bf16x8*)&sC_[wn * 64 + j * 16 + lr][k0 + quad * 8];
#pragma unroll
        for (int i = 0; i < 4; i++)
#pragma unroll
            for (int j = 0; j < 4; j++)
                accS[i][j] = __builtin_amdgcn_mfma_f32_16x16x32_bf16(af[i], bfr[j], accS[i][j], 0, 0, 0);
    }
#pragma unroll
    for (int j = 0; j < 4; j++) {
        int tt = wn * 64 + j * 16 + lr;
        float Lt = sL[tt];
#pragma unroll
        for (int i = 0; i < 4; i++) {
#pragma unroll
            for (int r = 0; r < 4; r++) {
                int tp = wm * 64 + i * 16 + quad * 4 + r;
                float v = 0.f;
                if (tp <= tt) v = accS[i][j][r] * sdt[tp] * __expf(Lt - sL[tp]);
                sS[tt][tp] = f2bf(v);
            }
        }
    }

    floatx4 acc[4][4];
#pragma unroll
    for (int i = 0; i < 4; i++)
#pragma unroll
        for (int j = 0; j < 4; j++)
#pragma unroll
            for (int r = 0; r < 4; r++) acc[i][j][r] = 0.f;
    __syncthreads();
    if (seg > 0) {
        const u16* hbase = Hbf + (size_t)(seg - 1) * SLOT + (((size_t)b * NHEAD + h) * PDIM) * NSTATE;
#pragma unroll
        for (int k0 = 0; k0 < 64; k0 += 32) {
            bf16x8 af[4], bfr[4];
#pragma unroll
            for (int i = 0; i < 4; i++)
                af[i] = *(const bf16x8*)&sC_[wm * 64 + i * 16 + lr][k0 + quad * 8];
#pragma unroll
            for (int j = 0; j < 4; j++)
                bfr[j] = *(const bf16x8*)(hbase + (size_t)(wn * 64 + j * 16 + lr) * NSTATE + k0 + quad * 8);
#pragma unroll
            for (int i = 0; i < 4; i++)
#pragma unroll
                for (int j = 0; j < 4; j++)
                    acc[i][j] = __builtin_amdgcn_mfma_f32_16x16x32_bf16(af[i], bfr[j], acc[i][j], 0, 0, 0);
        }
#pragma unroll
        for (int i = 0; i < 4; i++) {
#pragma unroll
            for (int r = 0; r < 4; r++) {
                float el = sEL[wm * 64 + i * 16 + quad * 4 + r];
#pragma unroll
                for (int j = 0; j < 4; j++) acc[i][j][r] *= el;
            }
        }
    }

    const int px = tid & 127, koh = (tid >> 7) * 16;
    for (int kc = 0; kc < 128; kc += 32) {
        u16 xv[16];
#pragma unroll
        for (int j2 = 0; j2 < 16; ++j2) {
            int tp = kc + koh + j2;
            xv[j2] = xb[(size_t)((t0 + tp) * B_SZ + b) * D_IN + h * PDIM + px];
        }
        __syncthreads();
        *(uint4*)&sXT[px][koh]     = *(const uint4*)&xv[0];
        *(uint4*)&sXT[px][koh + 8] = *(const uint4*)&xv[8];
        __syncthreads();
        bf16x8 af[4], bfr[4];
#pragma unroll
        for (int i = 0; i < 4; i++)
            af[i] = *(const bf16x8*)&sS[wm * 64 + i * 16 + lr][kc + quad * 8];
#pragma unroll
        for (int j = 0; j < 4; j++)
            bfr[j] = *(const bf16x8*)&sXT[wn * 64 + j * 16 + lr][quad * 8];
#pragma unroll
        for (int i = 0; i < 4; i++)
#pragma unroll
            for (int j = 0; j < 4; j++)
                acc[i][j] = __builtin_amdgcn_mfma_f32_16x16x32_bf16(af[i], bfr[j], acc[i][j], 0, 0, 0);
    }

#pragma unroll
    for (int j = 0; j < 4; j++) {
        int p = wn * 64 + j * 16 + lr;
#pragma unroll
        for (int i = 0; i < 4; i++) {
#pragma unroll
            for (int r = 0; r < 4; r++) {
                int t = wm * 64 + i * 16 + quad * 4 + r;
                xb[(size_t)((t0 + t) * B_SZ + b) * D_IN + h * PDIM + p] = f2bf(acc[i][j][r]);
            }
        }
    }
}

// ---------------- launch ----------------
extern "C" void kernel_launch(void* const* d_in, const int* in_sizes, int n_in,
                              void* d_out, int out_size, void* d_ws, size_t ws_size,
                              hipStream_t stream) {
    const float* obs     = (const float*)d_in[0];
    const float* W_in    = (const float*)d_in[1];
    const float* b_in    = (const float*)d_in[2];
    const float* A_log   = (const float*)d_in[3];
    const float* dt_bias = (const float*)d_in[4];
    const float* W_dt    = (const float*)d_in[5];
    const float* W_B     = (const float*)d_in[6];
    const float* W_C     = (const float*)d_in[7];
    const float* W_yo    = (const float*)d_in[8];
    const float* b_yo    = (const float*)d_in[9];
    const float* W_head  = (const float*)d_in[10];
    const float* b_head  = (const float*)d_in[11];

    char* ws = (char*)d_ws;
    size_t o = 0;
    u16*   xb     = (u16*)(ws + o);   o += (size_t)ROWS * D_IN * 2;            // 16 MB (x, then y in-place)
    u16*   BCm    = (u16*)(ws + o);   o += (size_t)ROWS * D_IN * 2;            // 16 MB (B | C)
    float* dtv    = (float*)(ws + o); o += (size_t)ROWS * NHEAD * 4;
    float* decayv = (float*)(ws + o); o += (size_t)ROWS * NHEAD * 4;
    u16*   zb     = (u16*)(ws + o);   o += (size_t)ROWS * NUNITS * 2;          // 2 MB
    float* Hseg   = (float*)(ws + o); o += (size_t)(NSEG - 1) * SLOT * 4;      // 12 MB
    u16*   Hbf    = (u16*)(ws + o);   o += (size_t)(NSEG - 1) * SLOT * 2;      // 6 MB
    u16*   obsb   = (u16*)(ws + o);   o += (size_t)ROWS * OBS_D * 2;           // 2 MB
    u16*   WinT   = (u16*)(ws + o);   o += (size_t)D_IN * OBS_D * 2;           // 1 MB
    u16*   WBCT   = (u16*)(ws + o);   o += (size_t)D_IN * D_IN * 2;            // 8 MB
    u16*   WyoT   = (u16*)(ws + o);   o += (size_t)NUNITS * D_IN * 2;          // 1 MB
    u16*   WheadT = (u16*)(ws + o);   o += (size_t)NACT * NUNITS * 2;
    u16*   Wdtb   = (u16*)(ws + o);   o += (size_t)D_IN * NHEAD * 2;

    // zero-work launch of the harness-required symbol (kept referenced; d_out
    // is fully written by the final head GEMM)
    ActorAgent_27625229647898_kernel<<<dim3(1), 256, 0, stream>>>((float*)d_out, 0, 0.f);

    // ---- all weight prep in one launch ----
    prep<<<dim3(160 + 5136), 256, 0, stream>>>(obs, W_dt, W_in, W_B, W_C, W_yo, W_head,
                                               obsb, Wdtb, WinT, WBCT, WyoT, WheadT);

    // ---- x = relu(obs @ W_in + b_in) -> bf16 ----
    gemm_bt128<1, 1, 1><<<dim3(32, 16), 256, 0, stream>>>(obsb, WinT, b_in, xb, ROWS, D_IN, OBS_D);
    // ---- dt/decay ----
    dt_kernel<<<dim3(ROWS), 256, 0, stream>>>(xb, Wdtb, dt_bias, A_log, dtv, decayv);
    // ---- B|C projection ----
    gemm_bt128<0, 1, 0><<<dim3(32, 16), 256, 0, stream>>>(xb, WBCT, (const float*)nullptr, BCm, ROWS, D_IN, D_IN);
    // ---- scan: A) segment-local final states ----
    seg_state<<<dim3((NSEG - 1) * 128), 256, 0, stream>>>(xb, BCm, dtv, decayv, Hseg);
    //          B) prefix combine -> bf16 ----
    seg_prefix<<<dim3(512), 256, 0, stream>>>(Hseg, decayv, Hbf);
    //          C) fused S' + Y, in-place over xb ----
    chunk_scan<<<dim3(NSEG * 128), 256, 0, stream>>>(BCm, dtv, decayv, Hbf, xb);
    // ---- z = relu(y @ W_yo + b_yo) -> bf16 ----
    gemm_bt64<1, 1><<<dim3(64, 4), 256, 0, stream>>>(xb, WyoT, b_yo, zb, ROWS, NUNITS, D_IN);
    // ---- logits = z @ W_head + b_head -> d_out (fp32) ----
    gemm_bt64<0, 0><<<dim3(64, 1), 256, 0, stream>>>(zb, WheadT, b_head, (float*)d_out, ROWS, NACT, NUNITS);
}

// Round 15
// 251.321 us; speedup vs baseline: 3.4257x; 1.0123x over previous
//
#include <hip/hip_runtime.h>
#include <cstdint>
#include <cstddef>

typedef unsigned short u16;
typedef __attribute__((ext_vector_type(8))) __bf16 bf16x8;   // MFMA A/B operand
typedef __attribute__((ext_vector_type(4))) float floatx4;   // MFMA C/D operand

// dims
#define T_DIM   512
#define B_SZ    8
#define ROWS    4096      // T*B
#define OBS_D   256
#define D_IN    2048
#define NHEAD   16
#define NSTATE  64
#define PDIM    128
#define NUNITS  256
#define NACT    64
#define NSEG    4
#define SEGT    128       // T_DIM / NSEG
#define SLOT    (B_SZ * NHEAD * PDIM * NSTATE)   // 1048576 elems per seg-state slot
#define BCSTR   2112      // BCm row stride: B(1024) | C(1024) | dtraw(64)

__host__ __device__ __forceinline__ float bf2f(u16 u) {
    union { uint32_t i; float f; } v; v.i = ((uint32_t)u) << 16; return v.f;
}
__host__ __device__ __forceinline__ u16 f2bf(float f) {
    union { float f; uint32_t i; } v; v.f = f;
    uint32_t r = v.i + 0x7FFFu + ((v.i >> 16) & 1u);
    return (u16)(r >> 16);
}

// async 16B/lane global->LDS (m97 pattern). lds ptr must be wave-uniform.
__device__ __forceinline__ void glds16(const u16* g, u16* l) {
    __builtin_amdgcn_global_load_lds(
        (__attribute__((address_space(1))) void*)g,
        (__attribute__((address_space(3))) void*)l, 16, 0, 0);
}

// ---------------- harness-required symbol (zero-work launch keeps it referenced) ----------------
__global__ __launch_bounds__(256) void ActorAgent_27625229647898_kernel(
        float* __restrict__ out, int n, float v) {
    for (int i = blockIdx.x * 256 + threadIdx.x; i < n; i += gridDim.x * 256)
        out[i] = v;
}

// ---------------- prep: all weight converts + transposes in ONE launch ----------------
// flat section: obs cvt, W_dt^T scatter into WBCT rows 2048..2063, zero rows 2064..2111.
__global__ __launch_bounds__(256) void prep(const float* __restrict__ obs,
                                            const float* __restrict__ W_dt,
                                            const float* __restrict__ W_in,
                                            const float* __restrict__ W_B,
                                            const float* __restrict__ W_C,
                                            const float* __restrict__ W_yo,
                                            const float* __restrict__ W_head,
                                            u16* __restrict__ obsb,
                                            u16* __restrict__ WinT, u16* __restrict__ WBCT,
                                            u16* __restrict__ WyoT, u16* __restrict__ WheadT) {
    int bid = blockIdx.x;
    if (bid < 160) {
        const int NOBS = ROWS * OBS_D;             // 1048576
        const int NDT  = D_IN * NHEAD;             // 32768
        const int NZ   = 48 * D_IN;                // 98304 (zero pad rows 2064..2111)
        for (int i = bid * 256 + threadIdx.x; i < NOBS + NDT + NZ; i += 160 * 256) {
            if (i < NOBS) obsb[i] = f2bf(obs[i]);
            else if (i < NOBS + NDT) {
                int j = i - NOBS;                  // j = k*16 + n
                int k = j >> 4, n = j & 15;
                WBCT[(size_t)(2048 + n) * D_IN + k] = f2bf(W_dt[j]);
            } else {
                WBCT[(size_t)2064 * D_IN + (i - NOBS - NDT)] = 0;
            }
        }
        return;
    }
    bid -= 160;
    const float* src; u16* dst; int R, C, bx, by;
    if (bid < 512)       { src = W_in;   dst = WinT;   R = 256;  C = 2048; bx = bid & 63; by = bid >> 6; }
    else if (bid < 2560) { int i = bid - 512;  src = W_B;  dst = WBCT; R = 2048; C = 1024; bx = i & 31; by = i >> 5; }
    else if (bid < 4608) { int i = bid - 2560; src = W_C;  dst = WBCT + (size_t)1024 * 2048; R = 2048; C = 1024; bx = i & 31; by = i >> 5; }
    else if (bid < 5120) { int i = bid - 4608; src = W_yo; dst = WyoT; R = 2048; C = 256;  bx = i & 7;  by = i >> 3; }
    else                 { int i = bid - 5120; src = W_head; dst = WheadT; R = 256; C = 64; bx = i & 1; by = i >> 1; }
    __shared__ float t[32][33];
    int c0 = bx * 32, r0 = by * 32;
    int tx = threadIdx.x & 31, ty = threadIdx.x >> 5;
#pragma unroll
    for (int i = 0; i < 32; i += 8)
        t[ty + i][tx] = src[(size_t)(r0 + ty + i) * C + c0 + tx];
    __syncthreads();
#pragma unroll
    for (int i = 0; i < 32; i += 8)
        dst[(size_t)(c0 + ty + i) * R + r0 + tx] = f2bf(t[tx][ty + i]);
}

// ---------------- gemm_bt: 128x64 bf16 MFMA GEMM, B^T (N,K), BK=32 glds staging ----------------
// 4 waves in 2x2 (wm over 64m, wn over 32n); 8 MFMA + 3 glds16 per wave-iter.
// 12 KB LDS -> high blocks/CU; grid ~(M/128, N/64) gives 4+ blocks/CU.
template <int ACT, int OUT_BF16, int HAS_BIAS>
__global__ __launch_bounds__(256) void gemm_bt(const u16* __restrict__ A,
                                               const u16* __restrict__ BT,
                                               const float* __restrict__ bias,
                                               void* __restrict__ Cout,
                                               int M, int N, int K) {
    __shared__ __align__(16) u16 sA[128 * 32];  // 8 KB, row stride 32 u16 (16 dw: 2-way ok)
    __shared__ __align__(16) u16 sB[64 * 32];   // 4 KB
    const int tid  = threadIdx.x;
    const int wave = tid >> 6, lane = tid & 63;
    const int quad = lane >> 4, lr = lane & 15;
    const int wm = wave & 1, wn = wave >> 1;
    const int m0 = blockIdx.x * 128, n0 = blockIdx.y * 64;
    const int srl = lane >> 2, sc = (lane & 3) * 8;  // glds: 16 rows x 32 k per call

    floatx4 acc[4][2];
#pragma unroll
    for (int i = 0; i < 4; i++)
#pragma unroll
        for (int j = 0; j < 2; j++)
#pragma unroll
            for (int r = 0; r < 4; r++) acc[i][j][r] = 0.f;

    const u16* apg = A + (size_t)(m0 + wave * 32 + srl) * K + sc;
    const u16* bpg = BT + (size_t)(n0 + wave * 16 + srl) * K + sc;
    u16* lA0 = &sA[(wave * 32) * 32];
    u16* lA1 = &sA[(wave * 32 + 16) * 32];
    u16* lB  = &sB[(wave * 16) * 32];

    for (int k0 = 0; k0 < K; k0 += 32) {
        __syncthreads();   // previous iteration's LDS readers done
        glds16(apg + k0, lA0);
        glds16(apg + (size_t)16 * K + k0, lA1);
        glds16(bpg + k0, lB);
        __syncthreads();   // drain vmcnt -> LDS visible
        bf16x8 af[4], bfr[2];
#pragma unroll
        for (int i = 0; i < 4; i++)
            af[i] = *(const bf16x8*)&sA[(wm * 64 + i * 16 + lr) * 32 + quad * 8];
#pragma unroll
        for (int j = 0; j < 2; j++)
            bfr[j] = *(const bf16x8*)&sB[(wn * 32 + j * 16 + lr) * 32 + quad * 8];
#pragma unroll
        for (int i = 0; i < 4; i++)
#pragma unroll
            for (int j = 0; j < 2; j++)
                acc[i][j] = __builtin_amdgcn_mfma_f32_16x16x32_bf16(af[i], bfr[j], acc[i][j], 0, 0, 0);
    }
    // C/D layout: col = lane&15, row = quad*4 + reg
#pragma unroll
    for (int j = 0; j < 2; j++) {
        int col = n0 + wn * 32 + j * 16 + lr;
        float bvv = HAS_BIAS ? bias[col] : 0.f;
#pragma unroll
        for (int i = 0; i < 4; i++) {
#pragma unroll
            for (int r = 0; r < 4; r++) {
                int row = m0 + wm * 64 + i * 16 + quad * 4 + r;
                float v = acc[i][j][r] + bvv;
                if (ACT) v = fmaxf(v, 0.f);
                if (OUT_BF16) ((u16*)Cout)[(size_t)row * N + col] = f2bf(v);
                else          ((float*)Cout)[(size_t)row * N + col] = v;
            }
        }
    }
}

// ---------------- bt64: 64x64 bf16 MFMA GEMM, B^T layout, BK=64 glds staging ----------------
template <int ACT, int OUT_BF16>
__global__ __launch_bounds__(256) void gemm_bt64(const u16* __restrict__ A,
                                                 const u16* __restrict__ BT,
                                                 const float* __restrict__ bias,
                                                 void* __restrict__ Cout,
                                                 int M, int N, int K) {
    __shared__ __align__(16) u16 sA[64 * 64];  // 8 KB
    __shared__ __align__(16) u16 sB[64 * 64];
    const int tid  = threadIdx.x;
    const int wave = tid >> 6, lane = tid & 63;
    const int quad = lane >> 4, lr = lane & 15;
    const int m0 = blockIdx.x * 64, n0 = blockIdx.y * 64;
    const int srl = lane >> 3, sc = (lane & 7) * 8;

    floatx4 acc[4];
#pragma unroll
    for (int i = 0; i < 4; i++)
#pragma unroll
        for (int j = 0; j < 4; j++) acc[i][j] = 0.f;

    const u16* apg = A + (size_t)(m0 + wave * 16 + srl) * K + sc;
    const u16* bpg = BT + (size_t)(n0 + wave * 16 + srl) * K + sc;

    for (int k0 = 0; k0 < K; k0 += 64) {
        __syncthreads();
#pragma unroll
        for (int g = 0; g < 2; ++g) {
            glds16(apg + (size_t)(g * 8) * K + k0, &sA[(wave * 16 + g * 8) * 64]);
            glds16(bpg + (size_t)(g * 8) * K + k0, &sB[(wave * 16 + g * 8) * 64]);
        }
        __syncthreads();
#pragma unroll
        for (int ks = 0; ks < 2; ++ks) {
            bf16x8 af = *(const bf16x8*)&sA[(wave * 16 + lr) * 64 + ks * 32 + quad * 8];
#pragma unroll
            for (int nt = 0; nt < 4; nt++) {
                bf16x8 bf = *(const bf16x8*)&sB[(nt * 16 + lr) * 64 + ks * 32 + quad * 8];
                acc[nt] = __builtin_amdgcn_mfma_f32_16x16x32_bf16(af, bf, acc[nt], 0, 0, 0);
            }
        }
    }
#pragma unroll
    for (int nt = 0; nt < 4; nt++) {
        int col = n0 + nt * 16 + lr;
        float bvv = bias ? bias[col] : 0.f;
#pragma unroll
        for (int r = 0; r < 4; r++) {
            int row = m0 + wave * 16 + quad * 4 + r;
            float v = acc[nt][r] + bvv;
            if (ACT) v = fmaxf(v, 0.f);
            if (OUT_BF16) ((u16*)Cout)[(size_t)row * N + col] = f2bf(v);
            else          ((float*)Cout)[(size_t)row * N + col] = v;
        }
    }
}

// ---------------- dt_fix: softplus + decay from GEMM-produced dtraw ----------------
__global__ __launch_bounds__(256) void dt_fix(const u16* __restrict__ BCm,
                                              const float* __restrict__ dt_bias,
                                              const float* __restrict__ A_log,
                                              float* __restrict__ dtv,
                                              float* __restrict__ decayv) {
    int i = blockIdx.x * 256 + threadIdx.x;   // grid 256 -> 65536 = ROWS*NHEAD
    int row = i >> 4, h = i & 15;
    float z = bf2f(BCm[(size_t)row * BCSTR + 2048 + h]) + dt_bias[h];
    float sp = (z > 20.f) ? z : log1pf(expf(z));
    dtv[i] = sp;
    decayv[i] = expf(-expf(A_log[h]) * sp);
}

// ---------------- seg_state: segment-final states as weighted outer-product sum ----------------
__global__ __launch_bounds__(256) void seg_state(const u16* __restrict__ xw,
                                                 const u16* __restrict__ BCm,
                                                 const float* __restrict__ dtv,
                                                 const float* __restrict__ decayv,
                                                 float* __restrict__ Hbuf) {
    const int blk = blockIdx.x;
    const int seg = blk >> 7;
    const int b   = (blk >> 4) & 7;
    const int h   = blk & 15;
    const int tid = threadIdx.x;
    const int pgrp = tid >> 3;
    const int oct  = tid & 7;

    __shared__ __align__(16) u16 sx[SEGT][PDIM];
    __shared__ __align__(16) u16 sbm[SEGT][NSTATE];
    __shared__ float sw[SEGT];
    __shared__ float sdt[SEGT];
    __shared__ float sdec[SEGT];
    __shared__ float sP[32];

    const int t0 = seg * SEGT;

#pragma unroll
    for (int k = 0; k < 8; ++k) {
        int idx = tid + k * 256;
        int t = idx >> 4, c = (idx & 15) * 8;
        int r = (t0 + t) * B_SZ + b;
        *(uint4*)&sx[t][c] = *(const uint4*)(xw + (size_t)r * D_IN + h * PDIM + c);
    }
#pragma unroll
    for (int k = 0; k < 4; ++k) {
        int idx = tid + k * 256;
        int t = idx >> 3, c = (idx & 7) * 8;
        int r = (t0 + t) * B_SZ + b;
        *(uint4*)&sbm[t][c] = *(const uint4*)(BCm + (size_t)r * BCSTR + h * NSTATE + c);
    }
    if (tid < SEGT)            sdt[tid] = dtv[((t0 + tid) * B_SZ + b) * NHEAD + h];
    else if (tid < 2 * SEGT)   sdec[tid - SEGT] = decayv[((t0 + tid - SEGT) * B_SZ + b) * NHEAD + h];
    __syncthreads();

    if (tid < 32) {
        float p = 1.f;
        for (int i = 3; i >= 0; --i) {
            int t = tid * 4 + i;
            sw[t] = sdt[t] * p;
            p *= sdec[t];
        }
        sP[tid] = p;
    }
    __syncthreads();
    if (tid == 0) {
        float suf = 1.f;
        for (int q = 31; q >= 0; --q) { float tmp = sP[q]; sP[q] = suf; suf *= tmp; }
    }
    __syncthreads();
    if (tid < 32) {
        float m = sP[tid];
        for (int i = 0; i < 4; ++i) sw[tid * 4 + i] *= m;
    }
    __syncthreads();

    float acc[4][8];
#pragma unroll
    for (int i = 0; i < 4; i++)
#pragma unroll
        for (int j = 0; j < 8; j++) acc[i][j] = 0.f;

    for (int t = 0; t < SEGT; ++t) {
        float w = sw[t];
        const u16* xp = &sx[t][pgrp * 4];
        const u16* bp = &sbm[t][oct * 8];
        float xv[4], bv[8];
#pragma unroll
        for (int i = 0; i < 4; i++) xv[i] = w * bf2f(xp[i]);
#pragma unroll
        for (int j = 0; j < 8; j++) bv[j] = bf2f(bp[j]);
#pragma unroll
        for (int i = 0; i < 4; i++)
#pragma unroll
            for (int j = 0; j < 8; j++)
                acc[i][j] = fmaf(xv[i], bv[j], acc[i][j]);
    }

    float* base = Hbuf + (size_t)seg * SLOT +
                  (((size_t)b * NHEAD + h) * PDIM + pgrp * 4) * NSTATE + oct * 8;
#pragma unroll
    for (int i = 0; i < 4; i++) {
        *(float4*)(base + (size_t)i * NSTATE)     = make_float4(acc[i][0], acc[i][1], acc[i][2], acc[i][3]);
        *(float4*)(base + (size_t)i * NSTATE + 4) = make_float4(acc[i][4], acc[i][5], acc[i][6], acc[i][7]);
    }
}

// ---------------- prefix combine -> bf16 prefix states Hbf ----------------
__global__ __launch_bounds__(256) void seg_prefix(const float* __restrict__ Hbuf,
                                                  const float* __restrict__ decayv,
                                                  u16* __restrict__ Hbf) {
    const int blk = blockIdx.x;
    const int b  = blk >> 6;
    const int h  = (blk >> 2) & 15;
    const int ec = blk & 3;
    const int tid = threadIdx.x;

    __shared__ float sA[NSEG];

    if (tid < 64 * (NSEG - 2)) {
        int s = 1 + (tid >> 6);
        int i = tid & 63;
        int t = s * SEGT + i * 2;
        float p = decayv[(t * B_SZ + b) * NHEAD + h] *
                  decayv[((t + 1) * B_SZ + b) * NHEAD + h];
        p *= __shfl_xor(p, 1);
        p *= __shfl_xor(p, 2);
        p *= __shfl_xor(p, 4);
        p *= __shfl_xor(p, 8);
        p *= __shfl_xor(p, 16);
        p *= __shfl_xor(p, 32);
        if (i == 0) sA[s] = p;
    }
    __syncthreads();

    const size_t base = (((size_t)b * NHEAD + h) * PDIM * NSTATE) + (size_t)ec * 2048 + tid * 8;
    float4 P0 = *(const float4*)(Hbuf + base);
    float4 P1 = *(const float4*)(Hbuf + base + 4);
    u16 pk[8];
    pk[0] = f2bf(P0.x); pk[1] = f2bf(P0.y); pk[2] = f2bf(P0.z); pk[3] = f2bf(P0.w);
    pk[4] = f2bf(P1.x); pk[5] = f2bf(P1.y); pk[6] = f2bf(P1.z); pk[7] = f2bf(P1.w);
    *(uint4*)(Hbf + base) = *(const uint4*)pk;
#pragma unroll
    for (int s = 1; s <= NSEG - 2; ++s) {
        float a = sA[s];
        const float* slot = Hbuf + (size_t)s * SLOT + base;
        float4 h0 = *(const float4*)(slot);
        float4 h1 = *(const float4*)(slot + 4);
        P0.x = fmaf(a, P0.x, h0.x); P0.y = fmaf(a, P0.y, h0.y);
        P0.z = fmaf(a, P0.z, h0.z); P0.w = fmaf(a, P0.w, h0.w);
        P1.x = fmaf(a, P1.x, h1.x); P1.y = fmaf(a, P1.y, h1.y);
        P1.z = fmaf(a, P1.z, h1.z); P1.w = fmaf(a, P1.w, h1.w);
        pk[0] = f2bf(P0.x); pk[1] = f2bf(P0.y); pk[2] = f2bf(P0.z); pk[3] = f2bf(P0.w);
        pk[4] = f2bf(P1.x); pk[5] = f2bf(P1.y); pk[6] = f2bf(P1.z); pk[7] = f2bf(P1.w);
        *(uint4*)(Hbf + (size_t)s * SLOT + base) = *(const uint4*)pk;
    }
}

// ---------------- chunk_scan: fused S' build + Y = exp(L).C@Hp^T + S'@X^T ----------------
__global__ __launch_bounds__(256) void chunk_scan(const u16* __restrict__ BCm,
                                                  const float* __restrict__ dtv,
                                                  const float* __restrict__ decayv,
                                                  const u16* __restrict__ Hbf,
                                                  u16* __restrict__ xb) {
    __shared__ __align__(16) u16 sB_[128][68];   // B [t'][n]
    __shared__ __align__(16) u16 sC_[128][68];   // C [t][n]
    __shared__ __align__(16) u16 sS[128][132];   // S' [t][t']
    __shared__ __align__(16) u16 sXT[128][36];   // X^T [p][k-tile]
    __shared__ float sdt[SEGT], sL[SEGT], sEL[SEGT], stmp[32];

    const int blk = blockIdx.x;
    const int seg = blk >> 7, b = (blk >> 4) & 7, h = blk & 15;
    const int tid = threadIdx.x;
    const int wave = tid >> 6, lane = tid & 63;
    const int quad = lane >> 4, lr = lane & 15;
    const int wm = wave & 1, wn = wave >> 1;
    const int t0 = seg * SEGT;

#pragma unroll
    for (int it = 0; it < 4; ++it) {
        int idx = tid + it * 256;
        int t = idx >> 3, c = (idx & 7) * 8;
        int r = (t0 + t) * B_SZ + b;
        *(uint4*)&sB_[t][c] = *(const uint4*)(BCm + (size_t)r * BCSTR + h * NSTATE + c);
        *(uint4*)&sC_[t][c] = *(const uint4*)(BCm + (size_t)r * BCSTR + 1024 + h * NSTATE + c);
    }
    if (tid < SEGT) sdt[tid] = dtv[((t0 + tid) * B_SZ + b) * NHEAD + h];
    else if (tid < 2 * SEGT) {
        int t = tid - SEGT;
        sL[t] = __logf(fmaxf(decayv[((t0 + t) * B_SZ + b) * NHEAD + h], 1e-30f));
    }
    __syncthreads();
    if (tid < 32) {
        float s = 0.f, v[4];
#pragma unroll
        for (int i = 0; i < 4; ++i) { s += sL[tid * 4 + i]; v[i] = s; }
        stmp[tid] = s;
#pragma unroll
        for (int i = 0; i < 4; ++i) sL[tid * 4 + i] = v[i];
    }
    __syncthreads();
    if (tid == 0) {
        float run = 0.f;
        for (int q = 0; q < 32; ++q) { float c2 = stmp[q]; stmp[q] = run; run += c2; }
    }
    __syncthreads();
    if (tid < 32) {
        float off = stmp[tid];
#pragma unroll
        for (int i = 0; i < 4; ++i) sL[tid * 4 + i] += off;
    }
    __syncthreads();
    if (tid < SEGT) sEL[tid] = __expf(sL[tid]);

    floatx4 accS[4][4];
#pragma unroll
    for (int i = 0; i < 4; i++)
#pragma unroll
        for (int j = 0; j < 4; j++)
#pragma unroll
            for (int r = 0; r < 4; r++) accS[i][j][r] = 0.f;
#pragma unroll
    for (int k0 = 0; k0 < 64; k0 += 32) {
        bf16x8 af[4], bfr[4];
#pragma unroll
        for (int i = 0; i < 4; i++)
            af[i] = *(const bf16x8*)&sB_[wm * 64 + i * 16 + lr][k0 + quad * 8];
#pragma unroll
        for (int j = 0; j < 4; j++)
            bfr[j] = *(const bf16x8*)&sC_[wn * 64 + j * 16 + lr][k0 + quad * 8];
#pragma unroll
        for (int i = 0; i < 4; i++)
#pragma unroll
            for (int j = 0; j < 4; j++)
                accS[i][j] = __builtin_amdgcn_mfma_f32_16x16x32_bf16(af[i], bfr[j], accS[i][j], 0, 0, 0);
    }
#pragma unroll
    for (int j = 0; j < 4; j++) {
        int tt = wn * 64 + j * 16 + lr;
        float Lt = sL[tt];
#pragma unroll
        for (int i = 0; i < 4; i++) {
#pragma unroll
            for (int r = 0; r < 4; r++) {
                int tp = wm * 64 + i * 16 + quad * 4 + r;
                float v = 0.f;
                if (tp <= tt) v = accS[i][j][r] * sdt[tp] * __expf(Lt - sL[tp]);
                sS[tt][tp] = f2bf(v);
            }
        }
    }

    floatx4 acc[4][4];
#pragma unroll
    for (int i = 0; i < 4; i++)
#pragma unroll
        for (int j = 0; j < 4; j++)
#pragma unroll
            for (int r = 0; r < 4; r++) acc[i][j][r] = 0.f;
    __syncthreads();
    if (seg > 0) {
        const u16* hbase = Hbf + (size_t)(seg - 1) * SLOT + (((size_t)b * NHEAD + h) * PDIM) * NSTATE;
#pragma unroll
        for (int k0 = 0; k0 < 64; k0 += 32) {
            bf16x8 af[4], bfr[4];
#pragma unroll
            for (int i = 0; i < 4; i++)
                af[i] = *(const bf16x8*)&sC_[wm * 64 + i * 16 + lr][k0 + quad * 8];
#pragma unroll
            for (int j = 0; j < 4; j++)
                bfr[j] = *(const bf16x8*)(hbase + (size_t)(wn * 64 + j * 16 + lr) * NSTATE + k0 + quad * 8);
#pragma unroll
            for (int i = 0; i < 4; i++)
#pragma unroll
                for (int j = 0; j < 4; j++)
                    acc[i][j] = __builtin_amdgcn_mfma_f32_16x16x32_bf16(af[i], bfr[j], acc[i][j], 0, 0, 0);
        }
#pragma unroll
        for (int i = 0; i < 4; i++) {
#pragma unroll
            for (int r = 0; r < 4; r++) {
                float el = sEL[wm * 64 + i * 16 + quad * 4 + r];
#pragma unroll
                for (int j = 0; j < 4; j++) acc[i][j][r] *= el;
            }
        }
    }

    const int px = tid & 127, koh = (tid >> 7) * 16;
    for (int kc = 0; kc < 128; kc += 32) {
        u16 xv[16];
#pragma unroll
        for (int j2 = 0; j2 < 16; ++j2) {
            int tp = kc + koh + j2;
            xv[j2] = xb[(size_t)((t0 + tp) * B_SZ + b) * D_IN + h * PDIM + px];
        }
        __syncthreads();
        *(uint4*)&sXT[px][koh]     = *(const uint4*)&xv[0];
        *(uint4*)&sXT[px][koh + 8] = *(const uint4*)&xv[8];
        __syncthreads();
        bf16x8 af[4], bfr[4];
#pragma unroll
        for (int i = 0; i < 4; i++)
            af[i] = *(const bf16x8*)&sS[wm * 64 + i * 16 + lr][kc + quad * 8];
#pragma unroll
        for (int j = 0; j < 4; j++)
            bfr[j] = *(const bf16x8*)&sXT[wn * 64 + j * 16 + lr][quad * 8];
#pragma unroll
        for (int i = 0; i < 4; i++)
#pragma unroll
            for (int j = 0; j < 4; j++)
                acc[i][j] = __builtin_amdgcn_mfma_f32_16x16x32_bf16(af[i], bfr[j], acc[i][j], 0, 0, 0);
    }

#pragma unroll
    for (int j = 0; j < 4; j++) {
        int p = wn * 64 + j * 16 + lr;
#pragma unroll
        for (int i = 0; i < 4; i++) {
#pragma unroll
            for (int r = 0; r < 4; r++) {
                int t = wm * 64 + i * 16 + quad * 4 + r;
                xb[(size_t)((t0 + t) * B_SZ + b) * D_IN + h * PDIM + p] = f2bf(acc[i][j][r]);
            }
        }
    }
}

// ---------------- launch ----------------
extern "C" void kernel_launch(void* const* d_in, const int* in_sizes, int n_in,
                              void* d_out, int out_size, void* d_ws, size_t ws_size,
                              hipStream_t stream) {
    const float* obs     = (const float*)d_in[0];
    const float* W_in    = (const float*)d_in[1];
    const float* b_in    = (const float*)d_in[2];
    const float* A_log   = (const float*)d_in[3];
    const float* dt_bias = (const float*)d_in[4];
    const float* W_dt    = (const float*)d_in[5];
    const float* W_B     = (const float*)d_in[6];
    const float* W_C     = (const float*)d_in[7];
    const float* W_yo    = (const float*)d_in[8];
    const float* b_yo    = (const float*)d_in[9];
    const float* W_head  = (const float*)d_in[10];
    const float* b_head  = (const float*)d_in[11];

    char* ws = (char*)d_ws;
    size_t o = 0;
    u16*   xb     = (u16*)(ws + o);   o += (size_t)ROWS * D_IN * 2;            // 16 MB (x, then y in-place)
    u16*   BCm    = (u16*)(ws + o);   o += (size_t)ROWS * BCSTR * 2;           // 17.3 MB (B | C | dtraw)
    float* dtv    = (float*)(ws + o); o += (size_t)ROWS * NHEAD * 4;
    float* decayv = (float*)(ws + o); o += (size_t)ROWS * NHEAD * 4;
    u16*   zb     = (u16*)(ws + o);   o += (size_t)ROWS * NUNITS * 2;          // 2 MB
    float* Hseg   = (float*)(ws + o); o += (size_t)(NSEG - 1) * SLOT * 4;      // 12 MB
    u16*   Hbf    = (u16*)(ws + o);   o += (size_t)(NSEG - 1) * SLOT * 2;      // 6 MB
    u16*   obsb   = (u16*)(ws + o);   o += (size_t)ROWS * OBS_D * 2;           // 2 MB
    u16*   WinT   = (u16*)(ws + o);   o += (size_t)D_IN * OBS_D * 2;           // 1 MB
    u16*   WBCT   = (u16*)(ws + o);   o += (size_t)BCSTR * D_IN * 2;           // 8.6 MB
    u16*   WyoT   = (u16*)(ws + o);   o += (size_t)NUNITS * D_IN * 2;          // 1 MB
    u16*   WheadT = (u16*)(ws + o);   o += (size_t)NACT * NUNITS * 2;

    // zero-work launch of the harness-required symbol (kept referenced)
    ActorAgent_27625229647898_kernel<<<dim3(1), 256, 0, stream>>>((float*)d_out, 0, 0.f);

    // ---- all weight prep in one launch ----
    prep<<<dim3(160 + 5136), 256, 0, stream>>>(obs, W_dt, W_in, W_B, W_C, W_yo, W_head,
                                               obsb, WinT, WBCT, WyoT, WheadT);

    // ---- x = relu(obs @ W_in + b_in) -> bf16 ----
    gemm_bt<1, 1, 1><<<dim3(32, 32), 256, 0, stream>>>(obsb, WinT, b_in, xb, ROWS, D_IN, OBS_D);
    // ---- B|C|dtraw projection (N = 2112) ----
    gemm_bt<0, 1, 0><<<dim3(32, 33), 256, 0, stream>>>(xb, WBCT, (const float*)nullptr, BCm, ROWS, BCSTR, D_IN);
    // ---- dt = softplus(dtraw + dt_bias); decay = exp(-exp(A_log)*dt) ----
    dt_fix<<<dim3(256), 256, 0, stream>>>(BCm, dt_bias, A_log, dtv, decayv);
    // ---- scan: A) segment-local final states ----
    seg_state<<<dim3((NSEG - 1) * 128), 256, 0, stream>>>(xb, BCm, dtv, decayv, Hseg);
    //          B) prefix combine -> bf16 ----
    seg_prefix<<<dim3(512), 256, 0, stream>>>(Hseg, decayv, Hbf);
    //          C) fused S' + Y, in-place over xb ----
    chunk_scan<<<dim3(NSEG * 128), 256, 0, stream>>>(BCm, dtv, decayv, Hbf, xb);
    // ---- z = relu(y @ W_yo + b_yo) -> bf16 ----
    gemm_bt64<1, 1><<<dim3(64, 4), 256, 0, stream>>>(xb, WyoT, b_yo, zb, ROWS, NUNITS, D_IN);
    // ---- logits = z @ W_head + b_head -> d_out (fp32) ----
    gemm_bt64<0, 0><<<dim3(64, 1), 256, 0, stream>>>(zb, WheadT, b_head, (float*)d_out, ROWS, NACT, NUNITS);
}

// Round 16
// 249.055 us; speedup vs baseline: 3.4569x; 1.0091x over previous
//
#include <hip/hip_runtime.h>
#include <cstdint>
#include <cstddef>

typedef unsigned short u16;
typedef __attribute__((ext_vector_type(8))) __bf16 bf16x8;   // MFMA A/B operand
typedef __attribute__((ext_vector_type(4))) float floatx4;   // MFMA C/D operand

// dims
#define T_DIM   512
#define B_SZ    8
#define ROWS    4096      // T*B
#define OBS_D   256
#define D_IN    2048
#define NHEAD   16
#define NSTATE  64
#define PDIM    128
#define NUNITS  256
#define NACT    64
#define NSEG    4
#define SEGT    128       // T_DIM / NSEG
#define SLOT    (B_SZ * NHEAD * PDIM * NSTATE)   // 1048576 elems per seg-state slot
#define BCSTR   2176      // BCm row stride: B(1024) | C(1024) | dtraw(16) | pad(112) = 17 x 128

__host__ __device__ __forceinline__ float bf2f(u16 u) {
    union { uint32_t i; float f; } v; v.i = ((uint32_t)u) << 16; return v.f;
}
__host__ __device__ __forceinline__ u16 f2bf(float f) {
    union { float f; uint32_t i; } v; v.f = f;
    uint32_t r = v.i + 0x7FFFu + ((v.i >> 16) & 1u);
    return (u16)(r >> 16);
}

// async 16B/lane global->LDS (m97 pattern). lds ptr must be wave-uniform.
__device__ __forceinline__ void glds16(const u16* g, u16* l) {
    __builtin_amdgcn_global_load_lds(
        (__attribute__((address_space(1))) void*)g,
        (__attribute__((address_space(3))) void*)l, 16, 0, 0);
}

// ---------------- harness-required symbol (zero-work launch keeps it referenced) ----------------
__global__ __launch_bounds__(256) void ActorAgent_27625229647898_kernel(
        float* __restrict__ out, int n, float v) {
    for (int i = blockIdx.x * 256 + threadIdx.x; i < n; i += gridDim.x * 256)
        out[i] = v;
}

// ---------------- prep: all weight converts + transposes in ONE launch ----------------
// flat section: obs cvt, W_dt^T scatter into WBCT rows 2048..2063, zero rows 2064..2175.
__global__ __launch_bounds__(256) void prep(const float* __restrict__ obs,
                                            const float* __restrict__ W_dt,
                                            const float* __restrict__ W_in,
                                            const float* __restrict__ W_B,
                                            const float* __restrict__ W_C,
                                            const float* __restrict__ W_yo,
                                            const float* __restrict__ W_head,
                                            u16* __restrict__ obsb,
                                            u16* __restrict__ WinT, u16* __restrict__ WBCT,
                                            u16* __restrict__ WyoT, u16* __restrict__ WheadT) {
    int bid = blockIdx.x;
    if (bid < 160) {
        const int NOBS = ROWS * OBS_D;             // 1048576
        const int NDT  = D_IN * NHEAD;             // 32768
        const int NZ   = 112 * D_IN;               // 229376 (zero pad rows 2064..2175)
        for (int i = bid * 256 + threadIdx.x; i < NOBS + NDT + NZ; i += 160 * 256) {
            if (i < NOBS) obsb[i] = f2bf(obs[i]);
            else if (i < NOBS + NDT) {
                int j = i - NOBS;                  // j = k*16 + n
                int k = j >> 4, n = j & 15;
                WBCT[(size_t)(2048 + n) * D_IN + k] = f2bf(W_dt[j]);
            } else {
                WBCT[(size_t)2064 * D_IN + (i - NOBS - NDT)] = 0;
            }
        }
        return;
    }
    bid -= 160;
    const float* src; u16* dst; int R, C, bx, by;
    if (bid < 512)       { src = W_in;   dst = WinT;   R = 256;  C = 2048; bx = bid & 63; by = bid >> 6; }
    else if (bid < 2560) { int i = bid - 512;  src = W_B;  dst = WBCT; R = 2048; C = 1024; bx = i & 31; by = i >> 5; }
    else if (bid < 4608) { int i = bid - 2560; src = W_C;  dst = WBCT + (size_t)1024 * 2048; R = 2048; C = 1024; bx = i & 31; by = i >> 5; }
    else if (bid < 5120) { int i = bid - 4608; src = W_yo; dst = WyoT; R = 2048; C = 256;  bx = i & 7;  by = i >> 3; }
    else                 { int i = bid - 5120; src = W_head; dst = WheadT; R = 256; C = 64; bx = i & 1; by = i >> 1; }
    __shared__ float t[32][33];
    int c0 = bx * 32, r0 = by * 32;
    int tx = threadIdx.x & 31, ty = threadIdx.x >> 5;
#pragma unroll
    for (int i = 0; i < 32; i += 8)
        t[ty + i][tx] = src[(size_t)(r0 + ty + i) * C + c0 + tx];
    __syncthreads();
#pragma unroll
    for (int i = 0; i < 32; i += 8)
        dst[(size_t)(c0 + ty + i) * R + r0 + tx] = f2bf(t[tx][ty + i]);
}

// ---------------- bt128: 128x128 bf16 MFMA GEMM, B^T (N,K), BK=32 glds staging ----------------
// Proven round-13 structure: unpadded [row][32] LDS, 4 glds16/thread-group/iter,
// 16 MFMA per wave-iter, 2 barriers/iter. Best measured variant (59.5 us on BC).
template <int ACT, int OUT_BF16, int HAS_BIAS>
__global__ __launch_bounds__(256) void gemm_bt128(const u16* __restrict__ A,
                                                  const u16* __restrict__ BT,
                                                  const float* __restrict__ bias,
                                                  void* __restrict__ Cout,
                                                  int M, int N, int K) {
    __shared__ __align__(16) u16 sA[128 * 32];
    __shared__ __align__(16) u16 sB[128 * 32];
    const int tid  = threadIdx.x;
    const int wave = tid >> 6, lane = tid & 63;
    const int quad = lane >> 4, lr = lane & 15;
    const int wm = wave & 1, wn = wave >> 1;
    const int m0 = blockIdx.x * 128, n0 = blockIdx.y * 128;
    const int r0 = wave * 32 + (lane >> 2);   // staged row per lane
    const int kel = (lane & 3) * 8;           // k offset (u16) per lane

    floatx4 acc[4][4];
#pragma unroll
    for (int i = 0; i < 4; i++)
#pragma unroll
        for (int j = 0; j < 4; j++)
#pragma unroll
            for (int r = 0; r < 4; r++) acc[i][j][r] = 0.f;

    const u16* apg = A + (size_t)(m0 + r0) * K + kel;
    const u16* bpg = BT + (size_t)(n0 + r0) * K + kel;
    u16* lA0 = &sA[(wave * 32) * 32];
    u16* lA1 = &sA[(wave * 32 + 16) * 32];
    u16* lB0 = &sB[(wave * 32) * 32];
    u16* lB1 = &sB[(wave * 32 + 16) * 32];

    for (int k0 = 0; k0 < K; k0 += 32) {
        __syncthreads();   // previous iteration's LDS readers done
        glds16(apg + k0, lA0);
        glds16(apg + (size_t)16 * K + k0, lA1);
        glds16(bpg + k0, lB0);
        glds16(bpg + (size_t)16 * K + k0, lB1);
        __syncthreads();   // drain vmcnt -> LDS visible
        bf16x8 af[4], bfr[4];
#pragma unroll
        for (int i = 0; i < 4; i++)
            af[i] = *(const bf16x8*)&sA[(wm * 64 + i * 16 + lr) * 32 + quad * 8];
#pragma unroll
        for (int j = 0; j < 4; j++)
            bfr[j] = *(const bf16x8*)&sB[(wn * 64 + j * 16 + lr) * 32 + quad * 8];
#pragma unroll
        for (int i = 0; i < 4; i++)
#pragma unroll
            for (int j = 0; j < 4; j++)
                acc[i][j] = __builtin_amdgcn_mfma_f32_16x16x32_bf16(af[i], bfr[j], acc[i][j], 0, 0, 0);
    }
    // C/D layout: col = lane&15, row = quad*4 + reg
#pragma unroll
    for (int j = 0; j < 4; j++) {
        int col = n0 + wn * 64 + j * 16 + lr;
        float bvv = HAS_BIAS ? bias[col] : 0.f;
#pragma unroll
        for (int i = 0; i < 4; i++) {
#pragma unroll
            for (int r = 0; r < 4; r++) {
                int row = m0 + wm * 64 + i * 16 + quad * 4 + r;
                float v = acc[i][j][r] + bvv;
                if (ACT) v = fmaxf(v, 0.f);
                if (OUT_BF16) ((u16*)Cout)[(size_t)row * N + col] = f2bf(v);
                else          ((float*)Cout)[(size_t)row * N + col] = v;
            }
        }
    }
}

// ---------------- bt64: 64x64 bf16 MFMA GEMM, B^T layout, BK=64 glds staging ----------------
template <int ACT, int OUT_BF16>
__global__ __launch_bounds__(256) void gemm_bt64(const u16* __restrict__ A,
                                                 const u16* __restrict__ BT,
                                                 const float* __restrict__ bias,
                                                 void* __restrict__ Cout,
                                                 int M, int N, int K) {
    __shared__ __align__(16) u16 sA[64 * 64];  // 8 KB
    __shared__ __align__(16) u16 sB[64 * 64];
    const int tid  = threadIdx.x;
    const int wave = tid >> 6, lane = tid & 63;
    const int quad = lane >> 4, lr = lane & 15;
    const int m0 = blockIdx.x * 64, n0 = blockIdx.y * 64;
    const int srl = lane >> 3, sc = (lane & 7) * 8;

    floatx4 acc[4];
#pragma unroll
    for (int i = 0; i < 4; i++)
#pragma unroll
        for (int j = 0; j < 4; j++) acc[i][j] = 0.f;

    const u16* apg = A + (size_t)(m0 + wave * 16 + srl) * K + sc;
    const u16* bpg = BT + (size_t)(n0 + wave * 16 + srl) * K + sc;

    for (int k0 = 0; k0 < K; k0 += 64) {
        __syncthreads();
#pragma unroll
        for (int g = 0; g < 2; ++g) {
            glds16(apg + (size_t)(g * 8) * K + k0, &sA[(wave * 16 + g * 8) * 64]);
            glds16(bpg + (size_t)(g * 8) * K + k0, &sB[(wave * 16 + g * 8) * 64]);
        }
        __syncthreads();
#pragma unroll
        for (int ks = 0; ks < 2; ++ks) {
            bf16x8 af = *(const bf16x8*)&sA[(wave * 16 + lr) * 64 + ks * 32 + quad * 8];
#pragma unroll
            for (int nt = 0; nt < 4; nt++) {
                bf16x8 bf = *(const bf16x8*)&sB[(nt * 16 + lr) * 64 + ks * 32 + quad * 8];
                acc[nt] = __builtin_amdgcn_mfma_f32_16x16x32_bf16(af, bf, acc[nt], 0, 0, 0);
            }
        }
    }
#pragma unroll
    for (int nt = 0; nt < 4; nt++) {
        int col = n0 + nt * 16 + lr;
        float bvv = bias ? bias[col] : 0.f;
#pragma unroll
        for (int r = 0; r < 4; r++) {
            int row = m0 + wave * 16 + quad * 4 + r;
            float v = acc[nt][r] + bvv;
            if (ACT) v = fmaxf(v, 0.f);
            if (OUT_BF16) ((u16*)Cout)[(size_t)row * N + col] = f2bf(v);
            else          ((float*)Cout)[(size_t)row * N + col] = v;
        }
    }
}

// ---------------- dt_fix: softplus + decay from GEMM-produced dtraw ----------------
__global__ __launch_bounds__(256) void dt_fix(const u16* __restrict__ BCm,
                                              const float* __restrict__ dt_bias,
                                              const float* __restrict__ A_log,
                                              float* __restrict__ dtv,
                                              float* __restrict__ decayv) {
    int i = blockIdx.x * 256 + threadIdx.x;   // grid 256 -> 65536 = ROWS*NHEAD
    int row = i >> 4, h = i & 15;
    float z = bf2f(BCm[(size_t)row * BCSTR + 2048 + h]) + dt_bias[h];
    float sp = (z > 20.f) ? z : log1pf(expf(z));
    dtv[i] = sp;
    decayv[i] = expf(-expf(A_log[h]) * sp);
}

// ---------------- seg_state: segment-final states as weighted outer-product sum ----------------
__global__ __launch_bounds__(256) void seg_state(const u16* __restrict__ xw,
                                                 const u16* __restrict__ BCm,
                                                 const float* __restrict__ dtv,
                                                 const float* __restrict__ decayv,
                                                 float* __restrict__ Hbuf) {
    const int blk = blockIdx.x;
    const int seg = blk >> 7;
    const int b   = (blk >> 4) & 7;
    const int h   = blk & 15;
    const int tid = threadIdx.x;
    const int pgrp = tid >> 3;
    const int oct  = tid & 7;

    __shared__ __align__(16) u16 sx[SEGT][PDIM];
    __shared__ __align__(16) u16 sbm[SEGT][NSTATE];
    __shared__ float sw[SEGT];
    __shared__ float sdt[SEGT];
    __shared__ float sdec[SEGT];
    __shared__ float sP[32];

    const int t0 = seg * SEGT;

#pragma unroll
    for (int k = 0; k < 8; ++k) {
        int idx = tid + k * 256;
        int t = idx >> 4, c = (idx & 15) * 8;
        int r = (t0 + t) * B_SZ + b;
        *(uint4*)&sx[t][c] = *(const uint4*)(xw + (size_t)r * D_IN + h * PDIM + c);
    }
#pragma unroll
    for (int k = 0; k < 4; ++k) {
        int idx = tid + k * 256;
        int t = idx >> 3, c = (idx & 7) * 8;
        int r = (t0 + t) * B_SZ + b;
        *(uint4*)&sbm[t][c] = *(const uint4*)(BCm + (size_t)r * BCSTR + h * NSTATE + c);
    }
    if (tid < SEGT)            sdt[tid] = dtv[((t0 + tid) * B_SZ + b) * NHEAD + h];
    else if (tid < 2 * SEGT)   sdec[tid - SEGT] = decayv[((t0 + tid - SEGT) * B_SZ + b) * NHEAD + h];
    __syncthreads();

    if (tid < 32) {
        float p = 1.f;
        for (int i = 3; i >= 0; --i) {
            int t = tid * 4 + i;
            sw[t] = sdt[t] * p;
            p *= sdec[t];
        }
        sP[tid] = p;
    }
    __syncthreads();
    if (tid == 0) {
        float suf = 1.f;
        for (int q = 31; q >= 0; --q) { float tmp = sP[q]; sP[q] = suf; suf *= tmp; }
    }
    __syncthreads();
    if (tid < 32) {
        float m = sP[tid];
        for (int i = 0; i < 4; ++i) sw[tid * 4 + i] *= m;
    }
    __syncthreads();

    float acc[4][8];
#pragma unroll
    for (int i = 0; i < 4; i++)
#pragma unroll
        for (int j = 0; j < 8; j++) acc[i][j] = 0.f;

    for (int t = 0; t < SEGT; ++t) {
        float w = sw[t];
        const u16* xp = &sx[t][pgrp * 4];
        const u16* bp = &sbm[t][oct * 8];
        float xv[4], bv[8];
#pragma unroll
        for (int i = 0; i < 4; i++) xv[i] = w * bf2f(xp[i]);
#pragma unroll
        for (int j = 0; j < 8; j++) bv[j] = bf2f(bp[j]);
#pragma unroll
        for (int i = 0; i < 4; i++)
#pragma unroll
            for (int j = 0; j < 8; j++)
                acc[i][j] = fmaf(xv[i], bv[j], acc[i][j]);
    }

    float* base = Hbuf + (size_t)seg * SLOT +
                  (((size_t)b * NHEAD + h) * PDIM + pgrp * 4) * NSTATE + oct * 8;
#pragma unroll
    for (int i = 0; i < 4; i++) {
        *(float4*)(base + (size_t)i * NSTATE)     = make_float4(acc[i][0], acc[i][1], acc[i][2], acc[i][3]);
        *(float4*)(base + (size_t)i * NSTATE + 4) = make_float4(acc[i][4], acc[i][5], acc[i][6], acc[i][7]);
    }
}

// ---------------- prefix combine -> bf16 prefix states Hbf ----------------
__global__ __launch_bounds__(256) void seg_prefix(const float* __restrict__ Hbuf,
                                                  const float* __restrict__ decayv,
                                                  u16* __restrict__ Hbf) {
    const int blk = blockIdx.x;
    const int b  = blk >> 6;
    const int h  = (blk >> 2) & 15;
    const int ec = blk & 3;
    const int tid = threadIdx.x;

    __shared__ float sA[NSEG];

    if (tid < 64 * (NSEG - 2)) {
        int s = 1 + (tid >> 6);
        int i = tid & 63;
        int t = s * SEGT + i * 2;
        float p = decayv[(t * B_SZ + b) * NHEAD + h] *
                  decayv[((t + 1) * B_SZ + b) * NHEAD + h];
        p *= __shfl_xor(p, 1);
        p *= __shfl_xor(p, 2);
        p *= __shfl_xor(p, 4);
        p *= __shfl_xor(p, 8);
        p *= __shfl_xor(p, 16);
        p *= __shfl_xor(p, 32);
        if (i == 0) sA[s] = p;
    }
    __syncthreads();

    const size_t base = (((size_t)b * NHEAD + h) * PDIM * NSTATE) + (size_t)ec * 2048 + tid * 8;
    float4 P0 = *(const float4*)(Hbuf + base);
    float4 P1 = *(const float4*)(Hbuf + base + 4);
    u16 pk[8];
    pk[0] = f2bf(P0.x); pk[1] = f2bf(P0.y); pk[2] = f2bf(P0.z); pk[3] = f2bf(P0.w);
    pk[4] = f2bf(P1.x); pk[5] = f2bf(P1.y); pk[6] = f2bf(P1.z); pk[7] = f2bf(P1.w);
    *(uint4*)(Hbf + base) = *(const uint4*)pk;
#pragma unroll
    for (int s = 1; s <= NSEG - 2; ++s) {
        float a = sA[s];
        const float* slot = Hbuf + (size_t)s * SLOT + base;
        float4 h0 = *(const float4*)(slot);
        float4 h1 = *(const float4*)(slot + 4);
        P0.x = fmaf(a, P0.x, h0.x); P0.y = fmaf(a, P0.y, h0.y);
        P0.z = fmaf(a, P0.z, h0.z); P0.w = fmaf(a, P0.w, h0.w);
        P1.x = fmaf(a, P1.x, h1.x); P1.y = fmaf(a, P1.y, h1.y);
        P1.z = fmaf(a, P1.z, h1.z); P1.w = fmaf(a, P1.w, h1.w);
        pk[0] = f2bf(P0.x); pk[1] = f2bf(P0.y); pk[2] = f2bf(P0.z); pk[3] = f2bf(P0.w);
        pk[4] = f2bf(P1.x); pk[5] = f2bf(P1.y); pk[6] = f2bf(P1.z); pk[7] = f2bf(P1.w);
        *(uint4*)(Hbf + (size_t)s * SLOT + base) = *(const uint4*)pk;
    }
}

// ---------------- chunk_scan: fused S' build + Y = exp(L).C@Hp^T + S'@X^T ----------------
__global__ __launch_bounds__(256) void chunk_scan(const u16* __restrict__ BCm,
                                                  const float* __restrict__ dtv,
                                                  const float* __restrict__ decayv,
                                                  const u16* __restrict__ Hbf,
                                                  u16* __restrict__ xb) {
    __shared__ __align__(16) u16 sB_[128][68];   // B [t'][n]
    __shared__ __align__(16) u16 sC_[128][68];   // C [t][n]
    __shared__ __align__(16) u16 sS[128][132];   // S' [t][t']
    __shared__ __align__(16) u16 sXT[128][36];   // X^T [p][k-tile]
    __shared__ float sdt[SEGT], sL[SEGT], sEL[SEGT], stmp[32];

    const int blk = blockIdx.x;
    const int seg = blk >> 7, b = (blk >> 4) & 7, h = blk & 15;
    const int tid = threadIdx.x;
    const int wave = tid >> 6, lane = tid & 63;
    const int quad = lane >> 4, lr = lane & 15;
    const int wm = wave & 1, wn = wave >> 1;
    const int t0 = seg * SEGT;

#pragma unroll
    for (int it = 0; it < 4; ++it) {
        int idx = tid + it * 256;
        int t = idx >> 3, c = (idx & 7) * 8;
        int r = (t0 + t) * B_SZ + b;
        *(uint4*)&sB_[t][c] = *(const uint4*)(BCm + (size_t)r * BCSTR + h * NSTATE + c);
        *(uint4*)&sC_[t][c] = *(const uint4*)(BCm + (size_t)r * BCSTR + 1024 + h * NSTATE + c);
    }
    if (tid < SEGT) sdt[tid] = dtv[((t0 + tid) * B_SZ + b) * NHEAD + h];
    else if (tid < 2 * SEGT) {
        int t = tid - SEGT;
        sL[t] = __logf(fmaxf(decayv[((t0 + t) * B_SZ + b) * NHEAD + h], 1e-30f));
    }
    __syncthreads();
    if (tid < 32) {
        float s = 0.f, v[4];
#pragma unroll
        for (int i = 0; i < 4; ++i) { s += sL[tid * 4 + i]; v[i] = s; }
        stmp[tid] = s;
#pragma unroll
        for (int i = 0; i < 4; ++i) sL[tid * 4 + i] = v[i];
    }
    __syncthreads();
    if (tid == 0) {
        float run = 0.f;
        for (int q = 0; q < 32; ++q) { float c2 = stmp[q]; stmp[q] = run; run += c2; }
    }
    __syncthreads();
    if (tid < 32) {
        float off = stmp[tid];
#pragma unroll
        for (int i = 0; i < 4; ++i) sL[tid * 4 + i] += off;
    }
    __syncthreads();
    if (tid < SEGT) sEL[tid] = __expf(sL[tid]);

    floatx4 accS[4][4];
#pragma unroll
    for (int i = 0; i < 4; i++)
#pragma unroll
        for (int j = 0; j < 4; j++)
#pragma unroll
            for (int r = 0; r < 4; r++) accS[i][j][r] = 0.f;
#pragma unroll
    for (int k0 = 0; k0 < 64; k0 += 32) {
        bf16x8 af[4], bfr[4];
#pragma unroll
        for (int i = 0; i < 4; i++)
            af[i] = *(const bf16x8*)&sB_[wm * 64 + i * 16 + lr][k0 + quad * 8];
#pragma unroll
        for (int j = 0; j < 4; j++)
            bfr[j] = *(const bf16x8*)&sC_[wn * 64 + j * 16 + lr][k0 + quad * 8];
#pragma unroll
        for (int i = 0; i < 4; i++)
#pragma unroll
            for (int j = 0; j < 4; j++)
                accS[i][j] = __builtin_amdgcn_mfma_f32_16x16x32_bf16(af[i], bfr[j], accS[i][j], 0, 0, 0);
    }
#pragma unroll
    for (int j = 0; j < 4; j++) {
        int tt = wn * 64 + j * 16 + lr;
        float Lt = sL[tt];
#pragma unroll
        for (int i = 0; i < 4; i++) {
#pragma unroll
            for (int r = 0; r < 4; r++) {
                int tp = wm * 64 + i * 16 + quad * 4 + r;
                float v = 0.f;
                if (tp <= tt) v = accS[i][j][r] * sdt[tp] * __expf(Lt - sL[tp]);
                sS[tt][tp] = f2bf(v);
            }
        }
    }

    floatx4 acc[4][4];
#pragma unroll
    for (int i = 0; i < 4; i++)
#pragma unroll
        for (int j = 0; j < 4; j++)
#pragma unroll
            for (int r = 0; r < 4; r++) acc[i][j][r] = 0.f;
    __syncthreads();
    if (seg > 0) {
        const u16* hbase = Hbf + (size_t)(seg - 1) * SLOT + (((size_t)b * NHEAD + h) * PDIM) * NSTATE;
#pragma unroll
        for (int k0 = 0; k0 < 64; k0 += 32) {
            bf16x8 af[4], bfr[4];
#pragma unroll
            for (int i = 0; i < 4; i++)
                af[i] = *(const bf16x8*)&sC_[wm * 64 + i * 16 + lr][k0 + quad * 8];
#pragma unroll
            for (int j = 0; j < 4; j++)
                bfr[j] = *(const bf16x8*)(hbase + (size_t)(wn * 64 + j * 16 + lr) * NSTATE + k0 + quad * 8);
#pragma unroll
            for (int i = 0; i < 4; i++)
#pragma unroll
                for (int j = 0; j < 4; j++)
                    acc[i][j] = __builtin_amdgcn_mfma_f32_16x16x32_bf16(af[i], bfr[j], acc[i][j], 0, 0, 0);
        }
#pragma unroll
        for (int i = 0; i < 4; i++) {
#pragma unroll
            for (int r = 0; r < 4; r++) {
                float el = sEL[wm * 64 + i * 16 + quad * 4 + r];
#pragma unroll
                for (int j = 0; j < 4; j++) acc[i][j][r] *= el;
            }
        }
    }

    const int px = tid & 127, koh = (tid >> 7) * 16;
    for (int kc = 0; kc < 128; kc += 32) {
        u16 xv[16];
#pragma unroll
        for (int j2 = 0; j2 < 16; ++j2) {
            int tp = kc + koh + j2;
            xv[j2] = xb[(size_t)((t0 + tp) * B_SZ + b) * D_IN + h * PDIM + px];
        }
        __syncthreads();
        *(uint4*)&sXT[px][koh]     = *(const uint4*)&xv[0];
        *(uint4*)&sXT[px][koh + 8] = *(const uint4*)&xv[8];
        __syncthreads();
        bf16x8 af[4], bfr[4];
#pragma unroll
        for (int i = 0; i < 4; i++)
            af[i] = *(const bf16x8*)&sS[wm * 64 + i * 16 + lr][kc + quad * 8];
#pragma unroll
        for (int j = 0; j < 4; j++)
            bfr[j] = *(const bf16x8*)&sXT[wn * 64 + j * 16 + lr][quad * 8];
#pragma unroll
        for (int i = 0; i < 4; i++)
#pragma unroll
            for (int j = 0; j < 4; j++)
                acc[i][j] = __builtin_amdgcn_mfma_f32_16x16x32_bf16(af[i], bfr[j], acc[i][j], 0, 0, 0);
    }

#pragma unroll
    for (int j = 0; j < 4; j++) {
        int p = wn * 64 + j * 16 + lr;
#pragma unroll
        for (int i = 0; i < 4; i++) {
#pragma unroll
            for (int r = 0; r < 4; r++) {
                int t = wm * 64 + i * 16 + quad * 4 + r;
                xb[(size_t)((t0 + t) * B_SZ + b) * D_IN + h * PDIM + p] = f2bf(acc[i][j][r]);
            }
        }
    }
}

// ---------------- launch ----------------
extern "C" void kernel_launch(void* const* d_in, const int* in_sizes, int n_in,
                              void* d_out, int out_size, void* d_ws, size_t ws_size,
                              hipStream_t stream) {
    const float* obs     = (const float*)d_in[0];
    const float* W_in    = (const float*)d_in[1];
    const float* b_in    = (const float*)d_in[2];
    const float* A_log   = (const float*)d_in[3];
    const float* dt_bias = (const float*)d_in[4];
    const float* W_dt    = (const float*)d_in[5];
    const float* W_B     = (const float*)d_in[6];
    const float* W_C     = (const float*)d_in[7];
    const float* W_yo    = (const float*)d_in[8];
    const float* b_yo    = (const float*)d_in[9];
    const float* W_head  = (const float*)d_in[10];
    const float* b_head  = (const float*)d_in[11];

    char* ws = (char*)d_ws;
    size_t o = 0;
    u16*   xb     = (u16*)(ws + o);   o += (size_t)ROWS * D_IN * 2;            // 16 MB (x, then y in-place)
    u16*   BCm    = (u16*)(ws + o);   o += (size_t)ROWS * BCSTR * 2;           // 17.8 MB (B | C | dtraw | pad)
    float* dtv    = (float*)(ws + o); o += (size_t)ROWS * NHEAD * 4;
    float* decayv = (float*)(ws + o); o += (size_t)ROWS * NHEAD * 4;
    u16*   zb     = (u16*)(ws + o);   o += (size_t)ROWS * NUNITS * 2;          // 2 MB
    float* Hseg   = (float*)(ws + o); o += (size_t)(NSEG - 1) * SLOT * 4;      // 12 MB
    u16*   Hbf    = (u16*)(ws + o);   o += (size_t)(NSEG - 1) * SLOT * 2;      // 6 MB
    u16*   obsb   = (u16*)(ws + o);   o += (size_t)ROWS * OBS_D * 2;           // 2 MB
    u16*   WinT   = (u16*)(ws + o);   o += (size_t)D_IN * OBS_D * 2;           // 1 MB
    u16*   WBCT   = (u16*)(ws + o);   o += (size_t)BCSTR * D_IN * 2;           // 8.9 MB
    u16*   WyoT   = (u16*)(ws + o);   o += (size_t)NUNITS * D_IN * 2;          // 1 MB
    u16*   WheadT = (u16*)(ws + o);   o += (size_t)NACT * NUNITS * 2;

    // zero-work launch of the harness-required symbol (kept referenced)
    ActorAgent_27625229647898_kernel<<<dim3(1), 256, 0, stream>>>((float*)d_out, 0, 0.f);

    // ---- all weight prep in one launch ----
    prep<<<dim3(160 + 5136), 256, 0, stream>>>(obs, W_dt, W_in, W_B, W_C, W_yo, W_head,
                                               obsb, WinT, WBCT, WyoT, WheadT);

    // ---- x = relu(obs @ W_in + b_in) -> bf16 ----
    gemm_bt128<1, 1, 1><<<dim3(32, 16), 256, 0, stream>>>(obsb, WinT, b_in, xb, ROWS, D_IN, OBS_D);
    // ---- B|C|dtraw projection (N = 2176, exactly 17 tiles) ----
    gemm_bt128<0, 1, 0><<<dim3(32, 17), 256, 0, stream>>>(xb, WBCT, (const float*)nullptr, BCm, ROWS, BCSTR, D_IN);
    // ---- dt = softplus(dtraw + dt_bias); decay = exp(-exp(A_log)*dt) ----
    dt_fix<<<dim3(256), 256, 0, stream>>>(BCm, dt_bias, A_log, dtv, decayv);
    // ---- scan: A) segment-local final states ----
    seg_state<<<dim3((NSEG - 1) * 128), 256, 0, stream>>>(xb, BCm, dtv, decayv, Hseg);
    //          B) prefix combine -> bf16 ----
    seg_prefix<<<dim3(512), 256, 0, stream>>>(Hseg, decayv, Hbf);
    //          C) fused S' + Y, in-place over xb ----
    chunk_scan<<<dim3(NSEG * 128), 256, 0, stream>>>(BCm, dtv, decayv, Hbf, xb);
    // ---- z = relu(y @ W_yo + b_yo) -> bf16 ----
    gemm_bt64<1, 1><<<dim3(64, 4), 256, 0, stream>>>(xb, WyoT, b_yo, zb, ROWS, NUNITS, D_IN);
    // ---- logits = z @ W_head + b_head -> d_out (fp32) ----
    gemm_bt64<0, 0><<<dim3(64, 1), 256, 0, stream>>>(zb, WheadT, b_head, (float*)d_out, ROWS, NACT, NUNITS);
}